// Round 15
// baseline (780.368 us; speedup 1.0000x reference)
//
#include <hip/hip_runtime.h>
#include <stdint.h>

typedef unsigned short u16;
typedef __attribute__((ext_vector_type(8))) short short8;
typedef __attribute__((ext_vector_type(4))) float f32x4;

__device__ __forceinline__ float bf2f(u16 u) {
  union { float f; uint32_t i; } v; v.i = ((uint32_t)u) << 16; return v.f;
}
__device__ __forceinline__ u16 f2bf(float f) {
  union { float f; uint32_t i; } v; v.f = f;
  uint32_t r = v.i + 0x7FFFu + ((v.i >> 16) & 1u);
  return (u16)(r >> 16);
}
__device__ __forceinline__ uint32_t pk2(float a, float b) {
  return (uint32_t)f2bf(a) | ((uint32_t)f2bf(b) << 16);
}
// async global->LDS, 16B per lane; LDS dest is wave-uniform base + lane*16
__device__ __forceinline__ void gload16(const u16* g, u16* l) {
  __builtin_amdgcn_global_load_lds(
      (const __attribute__((address_space(1))) unsigned int*)g,
      (__attribute__((address_space(3))) unsigned int*)l, 16, 0, 0);
}

__device__ __forceinline__ float block_sum256(float v) {
  __shared__ float red[4];
  #pragma unroll
  for (int o = 1; o < 64; o <<= 1) v += __shfl_xor(v, o, 64);
  int lane = threadIdx.x & 63, w = threadIdx.x >> 6;
  __syncthreads();
  if (lane == 0) red[w] = v;
  __syncthreads();
  return red[0] + red[1] + red[2] + red[3];
}

// ---------- W[K][N] f32 -> Wt[Npad][K] bf16 (zero-pad rows >= N) ----------
__global__ void k_tcast(const float* __restrict__ W, u16* __restrict__ Wt,
                        int K, int N, int Npad) {
  __shared__ float tile[32][33];
  int n0 = blockIdx.x * 32, k0 = blockIdx.y * 32;
  int tx = threadIdx.x, ty0 = threadIdx.y;
  #pragma unroll
  for (int i = 0; i < 4; i++) {
    int ty = ty0 + i * 8;
    int k = k0 + ty, n = n0 + tx;
    tile[ty][tx] = (k < K && n < N) ? W[(size_t)k * N + n] : 0.f;
  }
  __syncthreads();
  #pragma unroll
  for (int i = 0; i < 4; i++) {
    int ty = ty0 + i * 8;
    int n = n0 + ty, k = k0 + tx;
    if (n < Npad && k < K) Wt[(size_t)n * K + k] = f2bf(tile[tx][ty]);
  }
}

// ---------- f32 -> bf16 elementwise (x4) ----------
__global__ void k_cast(const float* __restrict__ in, u16* __restrict__ out, int n4) {
  int i = blockIdx.x * 256 + threadIdx.x;
  if (i >= n4) return;
  float4 v = ((const float4*)in)[i];
  uint2 o;
  o.x = pk2(v.x, v.y);
  o.y = pk2(v.z, v.w);
  ((uint2*)out)[i] = o;
}

// ---------- 128x128 bf16 MFMA GEMM (dbuf global_load_lds), general ----------
// flags: 1=bf16 out, 2=accumulate Cf, 4=flip row, 8=fuse u2 (v *= silu(hp))
__launch_bounds__(256)
__global__ void k_gemm(const u16* __restrict__ A, const u16* __restrict__ Bt,
                       float* __restrict__ Cf, u16* __restrict__ Cb,
                       const u16* __restrict__ hp,
                       int M, int N, int K, int ldc, int flags) {
  __shared__ u16 lA[2][128 * 64];
  __shared__ u16 lB[2][128 * 64];
  const int tid = threadIdx.x;
  const int lane = tid & 63;
  const int wave = tid >> 6;
  const int bm = blockIdx.x, bn = blockIdx.y;
  const int wr = wave >> 1, wc = wave & 1;
  const int fr = lane & 15, fq = lane >> 4;

  const int srow = wave * 32 + (lane >> 3);
  const int scol = ((lane & 7) ^ (srow & 7)) * 8;   // inverse-swizzled source col
  const u16* gA = A + (size_t)(bm * 128 + srow) * K + scol;
  const u16* gB = Bt + (size_t)(bn * 128 + srow) * K + scol;
  const int lofs = wave * 2048;

  f32x4 acc[4][4] = {};

  #pragma unroll
  for (int i = 0; i < 4; i++) {
    gload16(gA + (size_t)(i * 8) * K, &lA[0][lofs + i * 512]);
    gload16(gB + (size_t)(i * 8) * K, &lB[0][lofs + i * 512]);
  }
  __syncthreads();

  const int NT = K >> 6;
  for (int t = 0; t < NT; ++t) {
    const int cur = t & 1;
    if (t + 1 < NT) {
      const int kt = (t + 1) << 6;
      #pragma unroll
      for (int i = 0; i < 4; i++) {
        gload16(gA + (size_t)(i * 8) * K + kt, &lA[cur ^ 1][lofs + i * 512]);
        gload16(gB + (size_t)(i * 8) * K + kt, &lB[cur ^ 1][lofs + i * 512]);
      }
    }
    #pragma unroll
    for (int kk = 0; kk < 2; kk++) {
      short8 af[4], bfr[4];
      #pragma unroll
      for (int m = 0; m < 4; m++) {
        int row = wr * 64 + m * 16 + fr;
        int sl = (kk * 4 + fq) ^ (row & 7);
        af[m] = *(const short8*)(&lA[cur][row * 64 + sl * 8]);
      }
      #pragma unroll
      for (int n = 0; n < 4; n++) {
        int row = wc * 64 + n * 16 + fr;
        int sl = (kk * 4 + fq) ^ (row & 7);
        bfr[n] = *(const short8*)(&lB[cur][row * 64 + sl * 8]);
      }
      #pragma unroll
      for (int m = 0; m < 4; m++)
        #pragma unroll
        for (int n = 0; n < 4; n++)
          acc[m][n] = __builtin_amdgcn_mfma_f32_16x16x32_bf16(af[m], bfr[n], acc[m][n], 0, 0, 0);
    }
    __syncthreads();   // drains next-tile loads (latency hidden under compute above)
  }

  const bool bf16out = flags & 1, accum = flags & 2, flip = flags & 4, fuse = flags & 8;
  #pragma unroll
  for (int m = 0; m < 4; m++) {
    #pragma unroll
    for (int q = 0; q < 4; q++) {
      int rr = bm * 128 + wr * 64 + m * 16 + fq * 4 + q;
      int orow = flip ? (rr ^ 4095) : rr;
      size_t rb = (size_t)orow * ldc;
      #pragma unroll
      for (int n = 0; n < 4; n++) {
        int cc = bn * 128 + wc * 64 + n * 16 + fr;
        float v = acc[m][n][q];
        if (accum) v += Cf[rb + cc];
        if (fuse) {
          float h = bf2f(hp[rb + cc]);
          v = v * (h / (1.f + __expf(-h)));
        }
        if (bf16out) Cb[rb + cc] = f2bf(v);
        else Cf[rb + cc] = v;
      }
    }
  }
}

// ---------- 256x256 bf16 GEMM, win projection: BK=32, 64 KiB LDS, 2 blocks/CU ----------
// 8 waves (2Mx4N), per-wave 128x64, dbuf + counted vmcnt(4), 2-deep prefetch.
// Row-pair LDS layout: byte(row,slot) = (row>>1)*128 + (row&1)*64 +
// ((slot ^ ((row>>1)&3))*16 -> 16-lane fragment reads hit 8 distinct 16B
// positions (2-way = free). gload dest linear: lane l's byte l*16 decodes to
// row=2(l>>3)+((l>>2)&1), slot=(l&3)^((l>>3)&3); global source pre-permuted.
// XCD-swizzled block order (576 = 8 x 72, bijective).
// Fixed: M=8192, K=1024, N=4480 (18 N-tiles; ragged: B-row clamp + C guard).
__launch_bounds__(512)
__global__ void k_gemm256(const u16* __restrict__ A, const u16* __restrict__ Bt,
                          u16* __restrict__ Cb) {
  constexpr int K = 1024, N = 4480, NT = 32;   // BK = 32
  __shared__ u16 lA[2][256 * 32];
  __shared__ u16 lB[2][256 * 32];
  const int tid = threadIdx.x;
  const int lane = tid & 63;
  const int wid = tid >> 6;
  // XCD-aware bijective swizzle of the 32x18 grid
  const int wgid = blockIdx.y * 32 + blockIdx.x;
  const int nid = (wgid & 7) * 72 + (wgid >> 3);
  const int bm = nid & 31, bn = nid >> 5;
  const int wr = wid >> 2, wc = wid & 3;       // 2 x 4 waves
  const int fr = lane & 15, fq = lane >> 4;

  // staging: lane l -> row 2*(l>>3)+((l>>2)&1), pre-permuted col slot
  const int srow = 2 * (tid >> 3) + ((tid >> 2) & 1);   // 0..127
  const int scol = ((tid & 3) ^ ((tid >> 3) & 3)) * 8;
  const u16* gA0 = A + (size_t)(bm * 256 + srow) * K + scol;
  const u16* gA1 = gA0 + (size_t)128 * K;
  int br0 = bn * 256 + srow;       if (br0 > N - 1) br0 = N - 1;
  int br1 = bn * 256 + 128 + srow; if (br1 > N - 1) br1 = N - 1;
  const u16* gB0 = Bt + (size_t)br0 * K + scol;
  const u16* gB1 = Bt + (size_t)br1 * K + scol;

  f32x4 acc[8][4] = {};

  auto stage = [&](int u) {
    const int buf = u & 1, kt = u << 5;
    gload16(gA0 + kt, &lA[buf][tid * 8]);
    gload16(gA1 + kt, &lA[buf][4096 + tid * 8]);
    gload16(gB0 + kt, &lB[buf][tid * 8]);
    gload16(gB1 + kt, &lB[buf][4096 + tid * 8]);
  };

  // prologue: tiles 0,1 in flight; wait tile 0 only (4 newest stay pending)
  stage(0);
  stage(1);
  asm volatile("s_waitcnt vmcnt(4)" ::: "memory");
  __builtin_amdgcn_s_barrier();

  for (int t = 0; t < NT; ++t) {
    const u16* bufA = &lA[t & 1][0];
    const u16* bufB = &lB[t & 1][0];
    short8 af[8], bfm[4];
    #pragma unroll
    for (int m = 0; m < 8; m++) {
      int row = wr * 128 + m * 16 + fr;
      int off = ((row >> 1) << 6) + ((row & 1) << 5) + ((fq ^ ((row >> 1) & 3)) << 3);
      af[m] = *(const short8*)(&bufA[off]);
    }
    #pragma unroll
    for (int n = 0; n < 4; n++) {
      int row = wc * 64 + n * 16 + fr;
      int off = ((row >> 1) << 6) + ((row & 1) << 5) + ((fq ^ ((row >> 1) & 3)) << 3);
      bfm[n] = *(const short8*)(&bufB[off]);
    }
    #pragma unroll
    for (int m = 0; m < 8; m++)
      #pragma unroll
      for (int n = 0; n < 4; n++)
        acc[m][n] = __builtin_amdgcn_mfma_f32_16x16x32_bf16(af[m], bfm[n], acc[m][n], 0, 0, 0);
    // boundary: buf[t&1] dead -> stage t+2 there; counted wait: t+1 landed,
    // t+2's 4 loads stay in flight (never drain to 0 mid-loop)
    __builtin_amdgcn_s_barrier();
    if (t + 2 < NT) {
      stage(t + 2);
      asm volatile("s_waitcnt vmcnt(4)" ::: "memory");
    } else {
      asm volatile("s_waitcnt vmcnt(0)" ::: "memory");
    }
    __builtin_amdgcn_s_barrier();
  }

  #pragma unroll
  for (int m = 0; m < 8; m++) {
    #pragma unroll
    for (int q = 0; q < 4; q++) {
      size_t rb = (size_t)(bm * 256 + wr * 128 + m * 16 + fq * 4 + q) * N;
      #pragma unroll
      for (int n = 0; n < 4; n++) {
        int cc = bn * 256 + wc * 64 + n * 16 + fr;
        if (cc < N) Cb[rb + cc] = f2bf(acc[m][n][q]);
      }
    }
  }
}

// ---------- pre-LN ----------
__global__ void k_preln(const float* __restrict__ t, const float* __restrict__ bias,
                        const float* __restrict__ g, const float* __restrict__ bb,
                        u16* __restrict__ out) {
  const int row = blockIdx.x, tid = threadIdx.x;
  float4 v = ((const float4*)(t + (size_t)row * 1024))[tid];
  float4 bi = ((const float4*)bias)[tid];
  float v0 = v.x + bi.x, v1 = v.y + bi.y, v2 = v.z + bi.z, v3 = v.w + bi.w;
  float mean = block_sum256(v0 + v1 + v2 + v3) * (1.f / 1024.f);
  float d0 = v0 - mean, d1 = v1 - mean, d2 = v2 - mean, d3 = v3 - mean;
  float var = block_sum256(d0 * d0 + d1 * d1 + d2 * d2 + d3 * d3) * (1.f / 1024.f);
  float rs = rsqrtf(var + 1e-5f);
  float4 gg = ((const float4*)g)[tid];
  float4 bv = ((const float4*)bb)[tid];
  uint2 o;
  o.x = pk2(d0 * rs * gg.x + bv.x, d1 * rs * gg.y + bv.y);
  o.y = pk2(d2 * rs * gg.z + bv.z, d3 * rs * gg.w + bv.w);
  ((uint2*)(out + (size_t)row * 1024))[tid] = o;
}

// ---------- dt/dec in [b][h][t] (flipped-domain) layout ----------
__global__ void k_dt2(const u16* __restrict__ zx, const float* __restrict__ dtb,
                      const float* __restrict__ Alog, float* __restrict__ DTt,
                      float* __restrict__ DECt, int flip) {
  int t = blockIdx.x * 256 + threadIdx.x;
  int h = blockIdx.y, b = blockIdx.z;
  int ts = flip ? 4095 - t : t;
  float raw = bf2f(zx[(size_t)((b << 12) + ts) * 4480 + 4352 + h]) + dtb[h];
  float d = (raw > 20.f) ? raw : log1pf(__expf(raw));
  size_t o = (size_t)(b * 32 + h) * 4096 + t;
  DTt[o] = d;
  DECt[o] = __expf(-__expf(Alog[h]) * d);
}

// ---------- conv(K=4)+silu; vectorized I/O; outputs XT [b][2048][4096],
// ---------- BCtok [m][256] bf16, BCT [b][256][4096] (flipped-domain) ----------
__global__ void k_conv2(const u16* __restrict__ zx, const float* __restrict__ cw,
                        const float* __restrict__ cb, u16* __restrict__ XT,
                        u16* __restrict__ BCtok, u16* __restrict__ BCT, int flip) {
  const int ct = blockIdx.x;           // 0..35 channel tile (64)
  const int tt = blockIdx.y;           // 0..63 token tile (64)
  const int b = blockIdx.z;
  const int tid = threadIdx.x;         // 256
  __shared__ float sin_[67][64];
  __shared__ float sout[64][65];
  const int ch0 = ct * 64, t0 = tt * 64;

  // staging: uint2 = 4 ch/thread; 67 rows x 16 quads
  for (int i = tid; i < 67 * 16; i += 256) {
    int r = i >> 4, c4 = (i & 15) << 2;
    int tok = t0 - 3 + r;
    float f0 = 0.f, f1 = 0.f, f2 = 0.f, f3 = 0.f;
    if (tok >= 0) {
      int src = (b << 12) + (flip ? 4095 - tok : tok);
      uint2 v = *(const uint2*)(zx + (size_t)src * 4480 + 2048 + ch0 + c4);
      f0 = bf2f((u16)(v.x & 0xFFFF)); f1 = bf2f((u16)(v.x >> 16));
      f2 = bf2f((u16)(v.y & 0xFFFF)); f3 = bf2f((u16)(v.y >> 16));
    }
    sin_[r][c4] = f0; sin_[r][c4 + 1] = f1; sin_[r][c4 + 2] = f2; sin_[r][c4 + 3] = f3;
  }
  __syncthreads();

  const int ch = tid & 63, g = tid >> 6;
  const int chg = ch0 + ch;
  float4 wv = *(const float4*)(cw + (size_t)chg * 4);
  float bias = cb[chg];
  #pragma unroll
  for (int i = 0; i < 16; i++) {
    int tl = g * 16 + i;
    float a = bias + wv.x * sin_[tl][ch] + wv.y * sin_[tl + 1][ch]
                   + wv.z * sin_[tl + 2][ch] + wv.w * sin_[tl + 3][ch];
    sout[tl][ch] = a / (1.f + __expf(-a));
  }
  __syncthreads();

  if (ch0 < 2048) {
    for (int i = tid; i < 64 * 16; i += 256) {
      int chw = i >> 4, t4 = (i & 15) << 2;
      uint2 o;
      o.x = pk2(sout[t4][chw], sout[t4 + 1][chw]);
      o.y = pk2(sout[t4 + 2][chw], sout[t4 + 3][chw]);
      *(uint2*)(XT + ((size_t)(b * 2048 + ch0 + chw)) * 4096 + t0 + t4) = o;
    }
  } else {
    int c2b = (ct - 32) * 64;
    for (int i = tid; i < 64 * 16; i += 256) {
      int chw = i >> 4, t4 = (i & 15) << 2;
      uint2 o;
      o.x = pk2(sout[t4][chw], sout[t4 + 1][chw]);
      o.y = pk2(sout[t4 + 2][chw], sout[t4 + 3][chw]);
      *(uint2*)(BCT + ((size_t)(b * 256 + c2b + chw)) * 4096 + t0 + t4) = o;
    }
    for (int i = tid; i < 64 * 8; i += 256) {
      int r = i >> 3, c8 = (i & 7) << 3;
      uint4 o;
      o.x = pk2(sout[r][c8], sout[r][c8 + 1]);
      o.y = pk2(sout[r][c8 + 2], sout[r][c8 + 3]);
      o.z = pk2(sout[r][c8 + 4], sout[r][c8 + 5]);
      o.w = pk2(sout[r][c8 + 6], sout[r][c8 + 7]);
      *(uint4*)(BCtok + ((size_t)(b * 4096 + t0 + r)) * 256 + c2b + c8) = o;
    }
  }
}

// ================= SSD chunked scan, Q=256, NCH=16 =================
#define NCH 16
#define SWZ(row, oct, msk) (((oct) ^ ((row) & (msk))) << 4)

// inclusive cumsum helper over 256 threads (first 4 waves), returns L for tid<256
__device__ __forceinline__ void cumsum256(int tid, int lane, float adt, float dtv,
                                          float* sL, float* sdt, float* spart) {
  float v = adt;
  if (tid < 256) {
    #pragma unroll
    for (int o = 1; o < 64; o <<= 1) {
      float t = __shfl_up(v, o, 64);
      if (lane >= o) v += t;
    }
    if (lane == 63) spart[tid >> 6] = v;
  }
  __syncthreads();
  if (tid < 256) {
    int w = tid >> 6;
    float off = 0.f;
    #pragma unroll
    for (int j = 0; j < 3; j++) if (j < w) off += spart[j];
    sL[tid] = v + off;
    sdt[tid] = dtv;
  }
}

// pass A: H_localT[p][n] = sum_tau w_tau * X[tau][p] * B[tau][n], PR = exp(Lend)
__launch_bounds__(512, 1)
__global__ void k_ssd_a(const u16* __restrict__ XT, const u16* __restrict__ BCT,
                        const float* __restrict__ DTt, const float* __restrict__ Alog,
                        float* __restrict__ HB, float* __restrict__ PR) {
  const int c = blockIdx.x, h = blockIdx.y, b = blockIdx.z;
  const int tid = threadIdx.x;
  const int lane = tid & 63, w = tid >> 6;
  const int fr = lane & 15, fq = lane >> 4;
  const int bh = b * 32 + h;

  __shared__ u16 sX[64 * 256];      // [p][tau], 32 oct/row, swz ^(p&15)
  __shared__ u16 sBW[128 * 256];    // [n][tau], 32 oct/row, swz ^(n&15)
  __shared__ float sL[256], sdt[256], sw_[256], spart[4];

  float dtv = 0.f;
  if (tid < 256) dtv = DTt[(size_t)bh * 4096 + c * 256 + tid];
  float expA = __expf(Alog[h]);
  cumsum256(tid, lane, -expA * dtv, dtv, sL, sdt, spart);
  __syncthreads();
  if (tid < 256) sw_[tid] = __expf(sL[255] - sL[tid]) * sdt[tid];
  for (int i = tid; i < 2048; i += 512) {
    int p = i >> 5, oct = i & 31;
    uint4 v = *(const uint4*)(XT + ((size_t)(b * 2048 + h * 64 + p) << 12) + c * 256 + oct * 8);
    *(uint4*)((char*)sX + p * 512 + SWZ(p, oct, 15)) = v;
  }
  __syncthreads();
  for (int i = tid; i < 4096; i += 512) {
    int n = i >> 5, oct = i & 31;
    uint4 v = *(const uint4*)(BCT + ((size_t)(b * 256 + n) << 12) + c * 256 + oct * 8);
    const float* swp = sw_ + oct * 8;
    float f0 = bf2f((u16)(v.x & 0xFFFF)) * swp[0];
    float f1 = bf2f((u16)(v.x >> 16)) * swp[1];
    float f2 = bf2f((u16)(v.y & 0xFFFF)) * swp[2];
    float f3 = bf2f((u16)(v.y >> 16)) * swp[3];
    float f4 = bf2f((u16)(v.z & 0xFFFF)) * swp[4];
    float f5 = bf2f((u16)(v.z >> 16)) * swp[5];
    float f6 = bf2f((u16)(v.w & 0xFFFF)) * swp[6];
    float f7 = bf2f((u16)(v.w >> 16)) * swp[7];
    uint4 o;
    o.x = pk2(f0, f1); o.y = pk2(f2, f3); o.z = pk2(f4, f5); o.w = pk2(f6, f7);
    *(uint4*)((char*)sBW + n * 512 + SWZ(n, oct, 15)) = o;
  }
  __syncthreads();

  const int pb = w >> 1, nh = w & 1;
  f32x4 acc[4] = {};
  #pragma unroll
  for (int ks = 0; ks < 8; ks++) {
    int p = pb * 16 + fr;
    short8 af = *(const short8*)((char*)sX + p * 512 + SWZ(p, ks * 4 + fq, 15));
    #pragma unroll
    for (int nb = 0; nb < 4; nb++) {
      int n = nh * 64 + nb * 16 + fr;
      short8 bfm = *(const short8*)((char*)sBW + n * 512 + SWZ(n, ks * 4 + fq, 15));
      acc[nb] = __builtin_amdgcn_mfma_f32_16x16x32_bf16(af, bfm, acc[nb], 0, 0, 0);
    }
  }
  float* hb = HB + (size_t)(bh * NCH + c) * 8192;
  #pragma unroll
  for (int nb = 0; nb < 4; nb++)
    #pragma unroll
    for (int q = 0; q < 4; q++) {
      int p = pb * 16 + fq * 4 + q;
      int n = nh * 64 + nb * 16 + fr;
      hb[p * 128 + n] = acc[nb][q];
    }
  if (tid == 0) PR[bh * NCH + c] = __expf(sL[255]);
}

// pass B: sequential combine over chunk boundaries
__global__ void k_scan_b(float* __restrict__ HB, const float* __restrict__ PR) {
  const int eb = blockIdx.x, h = blockIdx.y, b = blockIdx.z;
  const int e = eb * 256 + threadIdx.x;
  const int bh = b * 32 + h;
  float* base = HB + (size_t)bh * NCH * 8192 + e;
  const float* pr = PR + bh * NCH;
  float carry = 0.f;
  #pragma unroll 4
  for (int c = 0; c < NCH; ++c) {
    float v = base[(size_t)c * 8192];
    base[(size_t)c * 8192] = carry;
    carry = pr[c] * carry + v;
  }
}

// pass C: y = (M.(C B^T)) X + exp(L_t) (C Hin) ; D-term added to P diag AFTER *G
__launch_bounds__(512, 1)
__global__ void k_ssd_c(const u16* __restrict__ BCtok, const u16* __restrict__ XT,
                        const float* __restrict__ DTt, const float* __restrict__ HB,
                        const float* __restrict__ Alog, const float* __restrict__ Dp,
                        u16* __restrict__ Y) {
  const int c = blockIdx.x, h = blockIdx.y, b = blockIdx.z;
  const int tid = threadIdx.x;
  const int lane = tid & 63, w = tid >> 6;
  const int fr = lane & 15, fq = lane >> 4;
  const int bh = b * 32 + h;
  const size_t m0 = (size_t)b * 4096 + c * 256;

  __shared__ u16 sB[256 * 128];     // [tau][n], 16 oct/row, swz ^(tau&15)
  __shared__ u16 sX[64 * 256];      // [p][tau], 32 oct/row, swz ^(p&15)
  __shared__ u16 sH[64 * 128];      // [p][n],  16 oct/row, swz ^(p&15)
  __shared__ u16 sP[8 * 32 * 64];   // per-wave [32t][64tau], 8 oct/row, swz ^(t&7)
  __shared__ float sL[256], sdt[256], spart[4];

  float dtv = 0.f;
  if (tid < 256) dtv = DTt[(size_t)bh * 4096 + c * 256 + tid];
  float expA = __expf(Alog[h]);
  cumsum256(tid, lane, -expA * dtv, dtv, sL, sdt, spart);

  for (int i = tid; i < 4096; i += 512) {
    int tr = i >> 4, oct = i & 15;
    uint4 v = *(const uint4*)(BCtok + ((m0 + tr) << 8) + oct * 8);
    *(uint4*)((char*)sB + tr * 256 + SWZ(tr, oct, 15)) = v;
  }
  for (int i = tid; i < 2048; i += 512) {
    int p = i >> 5, oct = i & 31;
    uint4 v = *(const uint4*)(XT + ((size_t)(b * 2048 + h * 64 + p) << 12) + c * 256 + oct * 8);
    *(uint4*)((char*)sX + p * 512 + SWZ(p, oct, 15)) = v;
  }
  for (int i = tid; i < 1024; i += 512) {
    int p = i >> 4, oct = i & 15;
    const float* src = HB + (size_t)(bh * NCH + c) * 8192 + p * 128 + oct * 8;
    float4 a = *(const float4*)src;
    float4 bb4 = *(const float4*)(src + 4);
    uint4 o;
    o.x = pk2(a.x, a.y); o.y = pk2(a.z, a.w); o.z = pk2(bb4.x, bb4.y); o.w = pk2(bb4.z, bb4.w);
    *(uint4*)((char*)sH + p * 256 + SWZ(p, oct, 15)) = o;
  }
  // C A-fragments (reused by G and Yoff): rows t = w*32+m*16+fr, ch 128+k
  short8 cf[2][4];
  #pragma unroll
  for (int m = 0; m < 2; m++)
    #pragma unroll
    for (int ks = 0; ks < 4; ks++)
      cf[m][ks] = *(const short8*)(BCtok + ((m0 + w * 32 + m * 16 + fr) << 8) + 128 + ks * 32 + fq * 8);
  __syncthreads();

  float Lt[2][4], eLt[2][4];
  #pragma unroll
  for (int m = 0; m < 2; m++)
    #pragma unroll
    for (int q = 0; q < 4; q++) {
      Lt[m][q] = sL[w * 32 + m * 16 + fq * 4 + q];
      eLt[m][q] = __expf(Lt[m][q]);
    }
  const float Dh = Dp[h];

  f32x4 accY[2][4] = {};
  u16* pw = sP + w * 2048;
  const int ntl = (w >> 1) + 1;
  for (int tt = 0; tt < ntl; tt++) {
    const int t0 = tt * 64;
    f32x4 g[2][4] = {};
    #pragma unroll
    for (int ks = 0; ks < 4; ks++) {
      short8 bfm[4];
      #pragma unroll
      for (int nb = 0; nb < 4; nb++) {
        int tr = t0 + nb * 16 + fr;
        bfm[nb] = *(const short8*)((char*)sB + tr * 256 + SWZ(tr, ks * 4 + fq, 15));
      }
      #pragma unroll
      for (int m = 0; m < 2; m++)
        #pragma unroll
        for (int nb = 0; nb < 4; nb++)
          g[m][nb] = __builtin_amdgcn_mfma_f32_16x16x32_bf16(cf[m][ks], bfm[nb], g[m][nb], 0, 0, 0);
    }
    // mask * G -> P (bf16, per-wave LDS); D added to diag AFTER multiplying by G
    #pragma unroll
    for (int nb = 0; nb < 4; nb++) {
      int tau = t0 + nb * 16 + fr;
      float Ltau = sL[tau], dtau = sdt[tau];
      #pragma unroll
      for (int m = 0; m < 2; m++) {
        #pragma unroll
        for (int q = 0; q < 4; q++) {
          int t = w * 32 + m * 16 + fq * 4 + q;
          float mask = (tau > t) ? 0.f : __expf(Lt[m][q] - Ltau) * dtau;
          float pv = mask * g[m][nb][q];
          pv = (tau == t) ? pv + Dh : pv;
          int tl = m * 16 + fq * 4 + q, taul = nb * 16 + fr;
          *(u16*)((char*)pw + tl * 128 + ((((taul) >> 3) ^ (tl & 7)) << 4) + (taul & 7) * 2) = f2bf(pv);
        }
      }
    }
    // P @ X
    #pragma unroll
    for (int ks = 0; ks < 2; ks++) {
      short8 pf[2], xf[4];
      #pragma unroll
      for (int m = 0; m < 2; m++) {
        int tl = m * 16 + fr;
        pf[m] = *(const short8*)((char*)pw + tl * 128 + (((ks * 4 + fq) ^ (tl & 7)) << 4));
      }
      #pragma unroll
      for (int pb = 0; pb < 4; pb++) {
        int p = pb * 16 + fr;
        int oct = (t0 >> 3) + ks * 4 + fq;
        xf[pb] = *(const short8*)((char*)sX + p * 512 + SWZ(p, oct, 15));
      }
      #pragma unroll
      for (int m = 0; m < 2; m++)
        #pragma unroll
        for (int pb = 0; pb < 4; pb++)
          accY[m][pb] = __builtin_amdgcn_mfma_f32_16x16x32_bf16(pf[m], xf[pb], accY[m][pb], 0, 0, 0);
    }
  }
  // Yoff = C @ HinT
  f32x4 accO[2][4] = {};
  #pragma unroll
  for (int ks = 0; ks < 4; ks++) {
    short8 hf[4];
    #pragma unroll
    for (int pb = 0; pb < 4; pb++) {
      int p = pb * 16 + fr;
      hf[pb] = *(const short8*)((char*)sH + p * 256 + SWZ(p, ks * 4 + fq, 15));
    }
    #pragma unroll
    for (int m = 0; m < 2; m++)
      #pragma unroll
      for (int pb = 0; pb < 4; pb++)
        accO[m][pb] = __builtin_amdgcn_mfma_f32_16x16x32_bf16(cf[m][ks], hf[pb], accO[m][pb], 0, 0, 0);
  }
  #pragma unroll
  for (int m = 0; m < 2; m++)
    #pragma unroll
    for (int pb = 0; pb < 4; pb++)
      #pragma unroll
      for (int q = 0; q < 4; q++) {
        int t = w * 32 + m * 16 + fq * 4 + q;
        float val = accY[m][pb][q] + eLt[m][q] * accO[m][pb][q];
        Y[(m0 + t) * 2048 + h * 64 + pb * 16 + fr] = f2bf(val);
      }
}

// ---------- fallback: sequential scan on new layouts ----------
__launch_bounds__(256)
__global__ void k_scan(const u16* __restrict__ XT, const u16* __restrict__ BCtok,
                       const float* __restrict__ DTt, const float* __restrict__ DECt,
                       const float* __restrict__ Dp, u16* __restrict__ y) {
  const int ps = blockIdx.x, h = blockIdx.y, b = blockIdx.z;
  const int tid = threadIdx.x;
  const int tsub = tid & 15, pl = tid >> 4;
  const int p = ps * 16 + pl;
  const u16* xp = XT + ((size_t)(b * 2048 + h * 64 + p)) * 4096;
  const float* dth = DTt + (size_t)(b * 32 + h) * 4096;
  const float* dch = DECt + (size_t)(b * 32 + h) * 4096;
  u16* yp = y + (size_t)b * 4096 * 2048 + h * 64 + p;
  const float Dh = Dp[h];
  float s0 = 0, s1 = 0, s2 = 0, s3 = 0, s4 = 0, s5 = 0, s6 = 0, s7 = 0;
  for (int tau = 0; tau < 4096; ++tau) {
    const u16* bcr = BCtok + ((size_t)(b * 4096 + tau)) * 256;
    uint4 vB = *(const uint4*)(bcr + tsub * 8);
    uint4 vC = *(const uint4*)(bcr + 128 + tsub * 8);
    float xv = bf2f(xp[tau]);
    float a = dth[tau] * xv;
    float dcv = dch[tau];
    s0 = s0 * dcv + a * bf2f((u16)(vB.x & 0xFFFF)); s1 = s1 * dcv + a * bf2f((u16)(vB.x >> 16));
    s2 = s2 * dcv + a * bf2f((u16)(vB.y & 0xFFFF)); s3 = s3 * dcv + a * bf2f((u16)(vB.y >> 16));
    s4 = s4 * dcv + a * bf2f((u16)(vB.z & 0xFFFF)); s5 = s5 * dcv + a * bf2f((u16)(vB.z >> 16));
    s6 = s6 * dcv + a * bf2f((u16)(vB.w & 0xFFFF)); s7 = s7 * dcv + a * bf2f((u16)(vB.w >> 16));
    float sum = s0 * bf2f((u16)(vC.x & 0xFFFF)) + s1 * bf2f((u16)(vC.x >> 16))
              + s2 * bf2f((u16)(vC.y & 0xFFFF)) + s3 * bf2f((u16)(vC.y >> 16))
              + s4 * bf2f((u16)(vC.z & 0xFFFF)) + s5 * bf2f((u16)(vC.z >> 16))
              + s6 * bf2f((u16)(vC.w & 0xFFFF)) + s7 * bf2f((u16)(vC.w >> 16));
    sum += __shfl_xor(sum, 1, 64);
    sum += __shfl_xor(sum, 2, 64);
    sum += __shfl_xor(sum, 4, 64);
    sum += __shfl_xor(sum, 8, 64);
    if (tsub == 0) yp[(size_t)tau * 2048] = f2bf(sum + Dh * xv);
  }
}

// ---------- gated RMSNorm (vectorized: uint4 loads, thread owns 8 channels) ----------
__global__ void k_gate(const u16* __restrict__ y, const u16* __restrict__ zx,
                       const float* __restrict__ normw, u16* __restrict__ u, int flip) {
  const int m = blockIdx.x, tid = threadIdx.x;
  const int ms = flip ? (m ^ 4095) : m;
  uint4 yv = *(const uint4*)(y + (size_t)m * 2048 + tid * 8);
  uint4 zv = *(const uint4*)(zx + (size_t)ms * 4480 + tid * 8);
  const u16* yp = (const u16*)&yv;
  const u16* zp = (const u16*)&zv;
  float vals[8];
  float ss = 0.f;
  #pragma unroll
  for (int i = 0; i < 8; i++) {
    float zf = bf2f(zp[i]);
    float wv = bf2f(yp[i]) * (zf / (1.f + __expf(-zf)));
    vals[i] = wv;
    ss += wv * wv;
  }
  float rs = rsqrtf(block_sum256(ss) * (1.f / 2048.f) + 1e-5f);
  float4 n0 = *(const float4*)(normw + tid * 8);
  float4 n1 = *(const float4*)(normw + tid * 8 + 4);
  uint4 o;
  o.x = pk2(vals[0] * rs * n0.x, vals[1] * rs * n0.y);
  o.y = pk2(vals[2] * rs * n0.z, vals[3] * rs * n0.w);
  o.z = pk2(vals[4] * rs * n1.x, vals[5] * rs * n1.y);
  o.w = pk2(vals[6] * rs * n1.z, vals[7] * rs * n1.w);
  *(uint4*)(u + (size_t)m * 2048 + tid * 8) = o;
}

// ---------- final LN + residual ----------
__global__ void k_final(const float* __restrict__ t2, const float* __restrict__ bias,
                        const float* __restrict__ g, const float* __restrict__ bb,
                        const float* __restrict__ x, float* __restrict__ out) {
  const int row = blockIdx.x, tid = threadIdx.x;
  float2 v = ((const float2*)(t2 + (size_t)row * 512))[tid];
  float v0 = v.x + bias[tid * 2], v1 = v.y + bias[tid * 2 + 1];
  float mean = block_sum256(v0 + v1) * (1.f / 512.f);
  float d0 = v0 - mean, d1 = v1 - mean;
  float var = block_sum256(d0 * d0 + d1 * d1) * (1.f / 512.f);
  float rs = rsqrtf(var + 1e-5f);
  float2 xr = ((const float2*)(x + (size_t)row * 512))[tid];
  float2 o;
  o.x = d0 * rs * g[tid * 2] + bb[tid * 2] + xr.x;
  o.y = d1 * rs * g[tid * 2 + 1] + bb[tid * 2 + 1] + xr.y;
  ((float2*)(out + (size_t)row * 512))[tid] = o;
}

extern "C" void kernel_launch(void* const* d_in, const int* in_sizes, int n_in,
                              void* d_out, int out_size, void* d_ws, size_t ws_size,
                              hipStream_t stream) {
  const float* x      = (const float*)d_in[0];
  const float* pre_w  = (const float*)d_in[1];
  const float* pre_b  = (const float*)d_in[2];
  const float* pre_g  = (const float*)d_in[3];
  const float* pre_bb = (const float*)d_in[4];
  const float* post_w = (const float*)d_in[5];
  const float* post_b = (const float*)d_in[6];
  const float* post_g = (const float*)d_in[7];
  const float* post_bb= (const float*)d_in[8];
  const float* win_[2]   = {(const float*)d_in[9],  (const float*)d_in[17]};
  const float* convw_[2] = {(const float*)d_in[10], (const float*)d_in[18]};
  const float* convb_[2] = {(const float*)d_in[11], (const float*)d_in[19]};
  const float* dtb_[2]   = {(const float*)d_in[12], (const float*)d_in[20]};
  const float* Alog_[2]  = {(const float*)d_in[13], (const float*)d_in[21]};
  const float* Dp_[2]    = {(const float*)d_in[14], (const float*)d_in[22]};
  const float* normw_[2] = {(const float*)d_in[15], (const float*)d_in[23]};
  const float* wout_[2]  = {(const float*)d_in[16], (const float*)d_in[24]};

  char* ws = (char*)d_ws;
  constexpr size_t OFF_WT_PRE  = 0;                         // 1 MB (PR aliases later)
  constexpr size_t OFF_WT_WINF = OFF_WT_PRE  + 1048576;
  constexpr size_t OFF_WT_WINB = OFF_WT_WINF + 9175040;
  constexpr size_t OFF_WT_WOF  = OFF_WT_WINB + 9175040;
  constexpr size_t OFF_WT_WOB  = OFF_WT_WOF  + 4194304;
  constexpr size_t OFF_WT_POST = OFF_WT_WOB  + 4194304;
  constexpr size_t OFF_HPRE    = OFF_WT_POST + 1048576;     // 16 MB
  constexpr size_t OFF_ZX      = OFF_HPRE + 16777216;       // 70 MB
  constexpr size_t OFF_XT      = OFF_ZX + 73400320;         // 32 MB: XT [2][2048][4096] bf16
  constexpr size_t OFF_BC      = OFF_XT + 33554432;         // 4 MB BCtok + 4 MB BCT
  constexpr size_t OFF_DT      = OFF_BC + 8388608;          // 1 MB DT_T
  constexpr size_t OFF_DEC     = OFF_DT + 1048576;          // 1 MB DEC_T
  constexpr size_t OFF_Y       = OFF_DEC + 1048576;         // 16 MB bf16 y
  constexpr size_t OFF_S       = OFF_Y + 33554432;          // 32 MB
  constexpr size_t OFF_HB      = OFF_S + 33554432;          // 32 MB
  constexpr size_t ARENA_END   = OFF_HB + 33554432;         // == 263716864

  u16* WtPre    = (u16*)(ws + OFF_WT_PRE);
  u16* WtWin[2] = {(u16*)(ws + OFF_WT_WINF), (u16*)(ws + OFF_WT_WINB)};
  u16* WtWo[2]  = {(u16*)(ws + OFF_WT_WOF),  (u16*)(ws + OFF_WT_WOB)};
  u16* WtPost   = (u16*)(ws + OFF_WT_POST);
  u16* HPRE = (u16*)(ws + OFF_HPRE);
  u16* ZX   = (u16*)(ws + OFF_ZX);
  u16* XT   = (u16*)(ws + OFF_XT);
  u16* BCtok= (u16*)(ws + OFF_BC);
  u16* BCT  = (u16*)(ws + OFF_BC + 4194304);
  float* DTt = (float*)(ws + OFF_DT);
  float* DECt= (float*)(ws + OFF_DEC);
  u16*  Y   = (u16*)(ws + OFF_Y);
  float* S  = (float*)(ws + OFF_S);
  float* HB = (float*)(ws + OFF_HB);
  // aliases
  float* PRb  = (float*)(ws + OFF_WT_PRE); // 4 KB (WtPre dead after pre-GEMM)
  u16*   XBF  = (u16*)(ws + OFF_Y);        // bf16 x for pre-GEMM
  float* TMP  = S;                         // pre-GEMM f32 out
  u16*   U    = (u16*)(ws + OFF_XT);       // gated y bf16 (XT dead after ssd_c)
  u16*   U2   = ZX;                        // final gated sum (ZX dead)
  float* TMP2 = (float*)(ws + OFF_XT);     // post-GEMM f32 out (U dead)

  const bool chunked = (ws_size >= ARENA_END);

  dim3 tb(32, 8);
  k_tcast<<<dim3(32, 16),  tb, 0, stream>>>(pre_w,   WtPre,    512, 1024, 1024);
  k_tcast<<<dim3(140, 32), tb, 0, stream>>>(win_[0], WtWin[0], 1024, 4384, 4480);
  k_tcast<<<dim3(140, 32), tb, 0, stream>>>(win_[1], WtWin[1], 1024, 4384, 4480);
  k_tcast<<<dim3(32, 64),  tb, 0, stream>>>(wout_[0], WtWo[0], 2048, 1024, 1024);
  k_tcast<<<dim3(32, 64),  tb, 0, stream>>>(wout_[1], WtWo[1], 2048, 1024, 1024);
  k_tcast<<<dim3(16, 32),  tb, 0, stream>>>(post_w,  WtPost,   1024,  512,  512);
  k_cast<<<4096, 256, 0, stream>>>(x, XBF, 1048576);
  k_gemm<<<dim3(64, 8), 256, 0, stream>>>(XBF, WtPre, TMP, nullptr, nullptr,
                                          8192, 1024, 512, 1024, 0);
  k_preln<<<8192, 256, 0, stream>>>(TMP, pre_b, pre_g, pre_bb, HPRE);

  for (int d = 0; d < 2; d++) {
    int flip = d;
    k_gemm256<<<dim3(32, 18), 512, 0, stream>>>(HPRE, WtWin[d], ZX);
    k_dt2<<<dim3(16, 32, 2), 256, 0, stream>>>(ZX, dtb_[d], Alog_[d], DTt, DECt, flip);
    k_conv2<<<dim3(36, 64, 2), 256, 0, stream>>>(ZX, convw_[d], convb_[d], XT, BCtok, BCT, flip);
    if (chunked) {
      k_ssd_a<<<dim3(NCH, 32, 2), 512, 0, stream>>>(XT, BCT, DTt, Alog_[d], HB, PRb);
      k_scan_b<<<dim3(32, 32, 2), 256, 0, stream>>>(HB, PRb);
      k_ssd_c<<<dim3(NCH, 32, 2), 512, 0, stream>>>(BCtok, XT, DTt, HB, Alog_[d], Dp_[d], Y);
    } else {
      k_scan<<<dim3(4, 32, 2), 256, 0, stream>>>(XT, BCtok, DTt, DECt, Dp_[d], Y);
    }
    k_gate<<<8192, 256, 0, stream>>>(Y, ZX, normw_[d], U, flip);
    // d=0: plain f32 out to S. d=1: accumulate S + fused u2 (silu(HPRE)) -> bf16 U2.
    if (d == 0) {
      k_gemm<<<dim3(64, 8), 256, 0, stream>>>(U, WtWo[d], S, nullptr, nullptr,
                                              8192, 1024, 2048, 1024, 0);
    } else {
      k_gemm<<<dim3(64, 8), 256, 0, stream>>>(U, WtWo[d], S, U2, HPRE,
                                              8192, 1024, 2048, 1024, 1 | 2 | 4 | 8);
    }
  }

  k_gemm<<<dim3(64, 4), 256, 0, stream>>>(U2, WtPost, TMP2, nullptr, nullptr,
                                          8192, 512, 1024, 512, 0);
  k_final<<<8192, 256, 0, stream>>>(TMP2, post_b, post_g, post_bb, x, (float*)d_out);
}

// Round 16
// 723.845 us; speedup vs baseline: 1.0781x; 1.0781x over previous
//
#include <hip/hip_runtime.h>
#include <stdint.h>

typedef unsigned short u16;
typedef __attribute__((ext_vector_type(8))) short short8;
typedef __attribute__((ext_vector_type(4))) float f32x4;

__device__ __forceinline__ float bf2f(u16 u) {
  union { float f; uint32_t i; } v; v.i = ((uint32_t)u) << 16; return v.f;
}
__device__ __forceinline__ u16 f2bf(float f) {
  union { float f; uint32_t i; } v; v.f = f;
  uint32_t r = v.i + 0x7FFFu + ((v.i >> 16) & 1u);
  return (u16)(r >> 16);
}
__device__ __forceinline__ uint32_t pk2(float a, float b) {
  return (uint32_t)f2bf(a) | ((uint32_t)f2bf(b) << 16);
}
// async global->LDS, 16B per lane; LDS dest is wave-uniform base + lane*16
__device__ __forceinline__ void gload16(const u16* g, u16* l) {
  __builtin_amdgcn_global_load_lds(
      (const __attribute__((address_space(1))) unsigned int*)g,
      (__attribute__((address_space(3))) unsigned int*)l, 16, 0, 0);
}

__device__ __forceinline__ float block_sum256(float v) {
  __shared__ float red[4];
  #pragma unroll
  for (int o = 1; o < 64; o <<= 1) v += __shfl_xor(v, o, 64);
  int lane = threadIdx.x & 63, w = threadIdx.x >> 6;
  __syncthreads();
  if (lane == 0) red[w] = v;
  __syncthreads();
  return red[0] + red[1] + red[2] + red[3];
}

// ---------- W[K][N] f32 -> Wt[Npad][K] bf16 (zero-pad rows >= N) ----------
__global__ void k_tcast(const float* __restrict__ W, u16* __restrict__ Wt,
                        int K, int N, int Npad) {
  __shared__ float tile[32][33];
  int n0 = blockIdx.x * 32, k0 = blockIdx.y * 32;
  int tx = threadIdx.x, ty0 = threadIdx.y;
  #pragma unroll
  for (int i = 0; i < 4; i++) {
    int ty = ty0 + i * 8;
    int k = k0 + ty, n = n0 + tx;
    tile[ty][tx] = (k < K && n < N) ? W[(size_t)k * N + n] : 0.f;
  }
  __syncthreads();
  #pragma unroll
  for (int i = 0; i < 4; i++) {
    int ty = ty0 + i * 8;
    int n = n0 + ty, k = k0 + tx;
    if (n < Npad && k < K) Wt[(size_t)n * K + k] = f2bf(tile[tx][ty]);
  }
}

// ---------- f32 -> bf16 elementwise (x4) ----------
__global__ void k_cast(const float* __restrict__ in, u16* __restrict__ out, int n4) {
  int i = blockIdx.x * 256 + threadIdx.x;
  if (i >= n4) return;
  float4 v = ((const float4*)in)[i];
  uint2 o;
  o.x = pk2(v.x, v.y);
  o.y = pk2(v.z, v.w);
  ((uint2*)out)[i] = o;
}

// ---------- 128x128 bf16 MFMA GEMM (dbuf global_load_lds), general ----------
// flags: 1=bf16 out, 2=accumulate Cf, 4=flip row, 8=fuse u2 (v *= silu(hp))
__launch_bounds__(256)
__global__ void k_gemm(const u16* __restrict__ A, const u16* __restrict__ Bt,
                       float* __restrict__ Cf, u16* __restrict__ Cb,
                       const u16* __restrict__ hp,
                       int M, int N, int K, int ldc, int flags) {
  __shared__ u16 lA[2][128 * 64];
  __shared__ u16 lB[2][128 * 64];
  const int tid = threadIdx.x;
  const int lane = tid & 63;
  const int wave = tid >> 6;
  const int bm = blockIdx.x, bn = blockIdx.y;
  const int wr = wave >> 1, wc = wave & 1;
  const int fr = lane & 15, fq = lane >> 4;

  const int srow = wave * 32 + (lane >> 3);
  const int scol = ((lane & 7) ^ (srow & 7)) * 8;   // inverse-swizzled source col
  const u16* gA = A + (size_t)(bm * 128 + srow) * K + scol;
  const u16* gB = Bt + (size_t)(bn * 128 + srow) * K + scol;
  const int lofs = wave * 2048;

  f32x4 acc[4][4] = {};

  #pragma unroll
  for (int i = 0; i < 4; i++) {
    gload16(gA + (size_t)(i * 8) * K, &lA[0][lofs + i * 512]);
    gload16(gB + (size_t)(i * 8) * K, &lB[0][lofs + i * 512]);
  }
  __syncthreads();

  const int NT = K >> 6;
  for (int t = 0; t < NT; ++t) {
    const int cur = t & 1;
    if (t + 1 < NT) {
      const int kt = (t + 1) << 6;
      #pragma unroll
      for (int i = 0; i < 4; i++) {
        gload16(gA + (size_t)(i * 8) * K + kt, &lA[cur ^ 1][lofs + i * 512]);
        gload16(gB + (size_t)(i * 8) * K + kt, &lB[cur ^ 1][lofs + i * 512]);
      }
    }
    #pragma unroll
    for (int kk = 0; kk < 2; kk++) {
      short8 af[4], bfr[4];
      #pragma unroll
      for (int m = 0; m < 4; m++) {
        int row = wr * 64 + m * 16 + fr;
        int sl = (kk * 4 + fq) ^ (row & 7);
        af[m] = *(const short8*)(&lA[cur][row * 64 + sl * 8]);
      }
      #pragma unroll
      for (int n = 0; n < 4; n++) {
        int row = wc * 64 + n * 16 + fr;
        int sl = (kk * 4 + fq) ^ (row & 7);
        bfr[n] = *(const short8*)(&lB[cur][row * 64 + sl * 8]);
      }
      #pragma unroll
      for (int m = 0; m < 4; m++)
        #pragma unroll
        for (int n = 0; n < 4; n++)
          acc[m][n] = __builtin_amdgcn_mfma_f32_16x16x32_bf16(af[m], bfr[n], acc[m][n], 0, 0, 0);
    }
    __syncthreads();   // drains next-tile loads (latency hidden under compute above)
  }

  const bool bf16out = flags & 1, accum = flags & 2, flip = flags & 4, fuse = flags & 8;
  #pragma unroll
  for (int m = 0; m < 4; m++) {
    #pragma unroll
    for (int q = 0; q < 4; q++) {
      int rr = bm * 128 + wr * 64 + m * 16 + fq * 4 + q;
      int orow = flip ? (rr ^ 4095) : rr;
      size_t rb = (size_t)orow * ldc;
      #pragma unroll
      for (int n = 0; n < 4; n++) {
        int cc = bn * 128 + wc * 64 + n * 16 + fr;
        float v = acc[m][n][q];
        if (accum) v += Cf[rb + cc];
        if (fuse) {
          float h = bf2f(hp[rb + cc]);
          v = v * (h / (1.f + __expf(-h)));
        }
        if (bf16out) Cb[rb + cc] = f2bf(v);
        else Cf[rb + cc] = v;
      }
    }
  }
}

// ---------- 256x256 bf16 MFMA GEMM for the win projection (r11 proven) ----------
// 8 waves (2Mx4N), per-wave 128x64, BK=64, 128 KiB LDS dbuf, 2-barrier
// structure, counted vmcnt(8) at tile boundaries (never drain mid-loop).
// Fixed shape: M=8192, K=1024, N=4480 (18 N-tiles; ragged: B-row clamp + C guard).
__launch_bounds__(512)
__global__ void k_gemm256(const u16* __restrict__ A, const u16* __restrict__ Bt,
                          u16* __restrict__ Cb) {
  constexpr int K = 1024, N = 4480, NT = 16;
  __shared__ u16 lA[2][256 * 64];
  __shared__ u16 lB[2][256 * 64];
  const int tid = threadIdx.x;
  const int lane = tid & 63;
  const int wid = tid >> 6;
  const int bm = blockIdx.x, bn = blockIdx.y;
  const int wr = wid >> 2, wc = wid & 3;       // 2 x 4 waves
  const int fr = lane & 15, fq = lane >> 4;

  const int srow = tid >> 3;                    // 0..63
  const int scol = ((tid & 7) ^ (srow & 7)) * 8;
  const u16* gA[4];
  const u16* gB[4];
  #pragma unroll
  for (int i = 0; i < 4; i++) {
    int arow = bm * 256 + i * 64 + srow;
    gA[i] = A + (size_t)arow * K + scol;
    int brow = bn * 256 + i * 64 + srow;
    if (brow > N - 1) brow = N - 1;             // ragged-N clamp (cols guarded at C)
    gB[i] = Bt + (size_t)brow * K + scol;
  }

  f32x4 acc[8][4] = {};

  auto stage = [&](int u) {
    const int buf = u & 1, kt = u << 6;
    #pragma unroll
    for (int i = 0; i < 4; i++)
      gload16(gA[i] + kt, &lA[buf][i * 4096 + tid * 8]);
    #pragma unroll
    for (int i = 0; i < 4; i++)
      gload16(gB[i] + kt, &lB[buf][i * 4096 + tid * 8]);
  };

  // prologue: tiles 0,1 in flight; wait tile 0 only (8 newest stay pending)
  stage(0);
  stage(1);
  asm volatile("s_waitcnt vmcnt(8)" ::: "memory");
  __builtin_amdgcn_s_barrier();

  for (int t = 0; t < NT; ++t) {
    const u16* bufA = &lA[t & 1][0];
    const u16* bufB = &lB[t & 1][0];
    #pragma unroll
    for (int kk = 0; kk < 2; kk++) {
      short8 af[8], bfm[4];
      #pragma unroll
      for (int m = 0; m < 8; m++) {
        int row = wr * 128 + m * 16 + fr;
        int sl = (kk * 4 + fq) ^ (row & 7);
        af[m] = *(const short8*)(&bufA[row * 64 + sl * 8]);
      }
      #pragma unroll
      for (int n = 0; n < 4; n++) {
        int row = wc * 64 + n * 16 + fr;
        int sl = (kk * 4 + fq) ^ (row & 7);
        bfm[n] = *(const short8*)(&bufB[row * 64 + sl * 8]);
      }
      #pragma unroll
      for (int m = 0; m < 8; m++)
        #pragma unroll
        for (int n = 0; n < 4; n++)
          acc[m][n] = __builtin_amdgcn_mfma_f32_16x16x32_bf16(af[m], bfm[n], acc[m][n], 0, 0, 0);
    }
    // boundary: buf[t&1] dead -> stage t+2 there; counted wait: t+1 landed,
    // t+2's 8 loads stay in flight (never drain to 0 mid-loop)
    __builtin_amdgcn_s_barrier();
    if (t + 2 < NT) {
      stage(t + 2);
      asm volatile("s_waitcnt vmcnt(8)" ::: "memory");
    } else {
      asm volatile("s_waitcnt vmcnt(0)" ::: "memory");
    }
    __builtin_amdgcn_s_barrier();
  }

  #pragma unroll
  for (int m = 0; m < 8; m++) {
    #pragma unroll
    for (int q = 0; q < 4; q++) {
      size_t rb = (size_t)(bm * 256 + wr * 128 + m * 16 + fq * 4 + q) * N;
      #pragma unroll
      for (int n = 0; n < 4; n++) {
        int cc = bn * 256 + wc * 64 + n * 16 + fr;
        if (cc < N) Cb[rb + cc] = f2bf(acc[m][n][q]);
      }
    }
  }
}

// ---------- pre-LN ----------
__global__ void k_preln(const float* __restrict__ t, const float* __restrict__ bias,
                        const float* __restrict__ g, const float* __restrict__ bb,
                        u16* __restrict__ out) {
  const int row = blockIdx.x, tid = threadIdx.x;
  float4 v = ((const float4*)(t + (size_t)row * 1024))[tid];
  float4 bi = ((const float4*)bias)[tid];
  float v0 = v.x + bi.x, v1 = v.y + bi.y, v2 = v.z + bi.z, v3 = v.w + bi.w;
  float mean = block_sum256(v0 + v1 + v2 + v3) * (1.f / 1024.f);
  float d0 = v0 - mean, d1 = v1 - mean, d2 = v2 - mean, d3 = v3 - mean;
  float var = block_sum256(d0 * d0 + d1 * d1 + d2 * d2 + d3 * d3) * (1.f / 1024.f);
  float rs = rsqrtf(var + 1e-5f);
  float4 gg = ((const float4*)g)[tid];
  float4 bv = ((const float4*)bb)[tid];
  uint2 o;
  o.x = pk2(d0 * rs * gg.x + bv.x, d1 * rs * gg.y + bv.y);
  o.y = pk2(d2 * rs * gg.z + bv.z, d3 * rs * gg.w + bv.w);
  ((uint2*)(out + (size_t)row * 1024))[tid] = o;
}

// ---------- dt/dec in [b][h][t] (flipped-domain) layout ----------
__global__ void k_dt2(const u16* __restrict__ zx, const float* __restrict__ dtb,
                      const float* __restrict__ Alog, float* __restrict__ DTt,
                      float* __restrict__ DECt, int flip) {
  int t = blockIdx.x * 256 + threadIdx.x;
  int h = blockIdx.y, b = blockIdx.z;
  int ts = flip ? 4095 - t : t;
  float raw = bf2f(zx[(size_t)((b << 12) + ts) * 4480 + 4352 + h]) + dtb[h];
  float d = (raw > 20.f) ? raw : log1pf(__expf(raw));
  size_t o = (size_t)(b * 32 + h) * 4096 + t;
  DTt[o] = d;
  DECt[o] = __expf(-__expf(Alog[h]) * d);
}

// ---------- conv(K=4)+silu; vectorized I/O; outputs XT [b][2048][4096],
// ---------- BCtok [m][256] bf16, BCT [b][256][4096] (flipped-domain) ----------
__global__ void k_conv2(const u16* __restrict__ zx, const float* __restrict__ cw,
                        const float* __restrict__ cb, u16* __restrict__ XT,
                        u16* __restrict__ BCtok, u16* __restrict__ BCT, int flip) {
  const int ct = blockIdx.x;           // 0..35 channel tile (64)
  const int tt = blockIdx.y;           // 0..63 token tile (64)
  const int b = blockIdx.z;
  const int tid = threadIdx.x;         // 256
  __shared__ float sin_[67][64];
  __shared__ float sout[64][65];
  const int ch0 = ct * 64, t0 = tt * 64;

  // staging: uint2 = 4 ch/thread; 67 rows x 16 quads
  for (int i = tid; i < 67 * 16; i += 256) {
    int r = i >> 4, c4 = (i & 15) << 2;
    int tok = t0 - 3 + r;
    float f0 = 0.f, f1 = 0.f, f2 = 0.f, f3 = 0.f;
    if (tok >= 0) {
      int src = (b << 12) + (flip ? 4095 - tok : tok);
      uint2 v = *(const uint2*)(zx + (size_t)src * 4480 + 2048 + ch0 + c4);
      f0 = bf2f((u16)(v.x & 0xFFFF)); f1 = bf2f((u16)(v.x >> 16));
      f2 = bf2f((u16)(v.y & 0xFFFF)); f3 = bf2f((u16)(v.y >> 16));
    }
    sin_[r][c4] = f0; sin_[r][c4 + 1] = f1; sin_[r][c4 + 2] = f2; sin_[r][c4 + 3] = f3;
  }
  __syncthreads();

  const int ch = tid & 63, g = tid >> 6;
  const int chg = ch0 + ch;
  float4 wv = *(const float4*)(cw + (size_t)chg * 4);
  float bias = cb[chg];
  #pragma unroll
  for (int i = 0; i < 16; i++) {
    int tl = g * 16 + i;
    float a = bias + wv.x * sin_[tl][ch] + wv.y * sin_[tl + 1][ch]
                   + wv.z * sin_[tl + 2][ch] + wv.w * sin_[tl + 3][ch];
    sout[tl][ch] = a / (1.f + __expf(-a));
  }
  __syncthreads();

  if (ch0 < 2048) {
    for (int i = tid; i < 64 * 16; i += 256) {
      int chw = i >> 4, t4 = (i & 15) << 2;
      uint2 o;
      o.x = pk2(sout[t4][chw], sout[t4 + 1][chw]);
      o.y = pk2(sout[t4 + 2][chw], sout[t4 + 3][chw]);
      *(uint2*)(XT + ((size_t)(b * 2048 + ch0 + chw)) * 4096 + t0 + t4) = o;
    }
  } else {
    int c2b = (ct - 32) * 64;
    for (int i = tid; i < 64 * 16; i += 256) {
      int chw = i >> 4, t4 = (i & 15) << 2;
      uint2 o;
      o.x = pk2(sout[t4][chw], sout[t4 + 1][chw]);
      o.y = pk2(sout[t4 + 2][chw], sout[t4 + 3][chw]);
      *(uint2*)(BCT + ((size_t)(b * 256 + c2b + chw)) * 4096 + t0 + t4) = o;
    }
    for (int i = tid; i < 64 * 8; i += 256) {
      int r = i >> 3, c8 = (i & 7) << 3;
      uint4 o;
      o.x = pk2(sout[r][c8], sout[r][c8 + 1]);
      o.y = pk2(sout[r][c8 + 2], sout[r][c8 + 3]);
      o.z = pk2(sout[r][c8 + 4], sout[r][c8 + 5]);
      o.w = pk2(sout[r][c8 + 6], sout[r][c8 + 7]);
      *(uint4*)(BCtok + ((size_t)(b * 4096 + t0 + r)) * 256 + c2b + c8) = o;
    }
  }
}

// ================= SSD chunked scan, Q=256, NCH=16 =================
#define NCH 16
#define SWZ(row, oct, msk) (((oct) ^ ((row) & (msk))) << 4)

// inclusive cumsum helper over 256 threads (first 4 waves), returns L for tid<256
__device__ __forceinline__ void cumsum256(int tid, int lane, float adt, float dtv,
                                          float* sL, float* sdt, float* spart) {
  float v = adt;
  if (tid < 256) {
    #pragma unroll
    for (int o = 1; o < 64; o <<= 1) {
      float t = __shfl_up(v, o, 64);
      if (lane >= o) v += t;
    }
    if (lane == 63) spart[tid >> 6] = v;
  }
  __syncthreads();
  if (tid < 256) {
    int w = tid >> 6;
    float off = 0.f;
    #pragma unroll
    for (int j = 0; j < 3; j++) if (j < w) off += spart[j];
    sL[tid] = v + off;
    sdt[tid] = dtv;
  }
}

// pass A: H_localT[p][n] = sum_tau w_tau * X[tau][p] * B[tau][n], PR = exp(Lend)
__launch_bounds__(512, 1)
__global__ void k_ssd_a(const u16* __restrict__ XT, const u16* __restrict__ BCT,
                        const float* __restrict__ DTt, const float* __restrict__ Alog,
                        float* __restrict__ HB, float* __restrict__ PR) {
  const int c = blockIdx.x, h = blockIdx.y, b = blockIdx.z;
  const int tid = threadIdx.x;
  const int lane = tid & 63, w = tid >> 6;
  const int fr = lane & 15, fq = lane >> 4;
  const int bh = b * 32 + h;

  __shared__ u16 sX[64 * 256];      // [p][tau], 32 oct/row, swz ^(p&15)
  __shared__ u16 sBW[128 * 256];    // [n][tau], 32 oct/row, swz ^(n&15)
  __shared__ float sL[256], sdt[256], sw_[256], spart[4];

  float dtv = 0.f;
  if (tid < 256) dtv = DTt[(size_t)bh * 4096 + c * 256 + tid];
  float expA = __expf(Alog[h]);
  cumsum256(tid, lane, -expA * dtv, dtv, sL, sdt, spart);
  __syncthreads();
  if (tid < 256) sw_[tid] = __expf(sL[255] - sL[tid]) * sdt[tid];
  for (int i = tid; i < 2048; i += 512) {
    int p = i >> 5, oct = i & 31;
    uint4 v = *(const uint4*)(XT + ((size_t)(b * 2048 + h * 64 + p) << 12) + c * 256 + oct * 8);
    *(uint4*)((char*)sX + p * 512 + SWZ(p, oct, 15)) = v;
  }
  __syncthreads();
  for (int i = tid; i < 4096; i += 512) {
    int n = i >> 5, oct = i & 31;
    uint4 v = *(const uint4*)(BCT + ((size_t)(b * 256 + n) << 12) + c * 256 + oct * 8);
    const float* swp = sw_ + oct * 8;
    float f0 = bf2f((u16)(v.x & 0xFFFF)) * swp[0];
    float f1 = bf2f((u16)(v.x >> 16)) * swp[1];
    float f2 = bf2f((u16)(v.y & 0xFFFF)) * swp[2];
    float f3 = bf2f((u16)(v.y >> 16)) * swp[3];
    float f4 = bf2f((u16)(v.z & 0xFFFF)) * swp[4];
    float f5 = bf2f((u16)(v.z >> 16)) * swp[5];
    float f6 = bf2f((u16)(v.w & 0xFFFF)) * swp[6];
    float f7 = bf2f((u16)(v.w >> 16)) * swp[7];
    uint4 o;
    o.x = pk2(f0, f1); o.y = pk2(f2, f3); o.z = pk2(f4, f5); o.w = pk2(f6, f7);
    *(uint4*)((char*)sBW + n * 512 + SWZ(n, oct, 15)) = o;
  }
  __syncthreads();

  const int pb = w >> 1, nh = w & 1;
  f32x4 acc[4] = {};
  #pragma unroll
  for (int ks = 0; ks < 8; ks++) {
    int p = pb * 16 + fr;
    short8 af = *(const short8*)((char*)sX + p * 512 + SWZ(p, ks * 4 + fq, 15));
    #pragma unroll
    for (int nb = 0; nb < 4; nb++) {
      int n = nh * 64 + nb * 16 + fr;
      short8 bfm = *(const short8*)((char*)sBW + n * 512 + SWZ(n, ks * 4 + fq, 15));
      acc[nb] = __builtin_amdgcn_mfma_f32_16x16x32_bf16(af, bfm, acc[nb], 0, 0, 0);
    }
  }
  float* hb = HB + (size_t)(bh * NCH + c) * 8192;
  #pragma unroll
  for (int nb = 0; nb < 4; nb++)
    #pragma unroll
    for (int q = 0; q < 4; q++) {
      int p = pb * 16 + fq * 4 + q;
      int n = nh * 64 + nb * 16 + fr;
      hb[p * 128 + n] = acc[nb][q];
    }
  if (tid == 0) PR[bh * NCH + c] = __expf(sL[255]);
}

// pass B: sequential combine over chunk boundaries
__global__ void k_scan_b(float* __restrict__ HB, const float* __restrict__ PR) {
  const int eb = blockIdx.x, h = blockIdx.y, b = blockIdx.z;
  const int e = eb * 256 + threadIdx.x;
  const int bh = b * 32 + h;
  float* base = HB + (size_t)bh * NCH * 8192 + e;
  const float* pr = PR + bh * NCH;
  float carry = 0.f;
  #pragma unroll 4
  for (int c = 0; c < NCH; ++c) {
    float v = base[(size_t)c * 8192];
    base[(size_t)c * 8192] = carry;
    carry = pr[c] * carry + v;
  }
}

// pass C: y = (M.(C B^T)) X + exp(L_t) (C Hin) ; D-term added to P diag AFTER *G
__launch_bounds__(512, 1)
__global__ void k_ssd_c(const u16* __restrict__ BCtok, const u16* __restrict__ XT,
                        const float* __restrict__ DTt, const float* __restrict__ HB,
                        const float* __restrict__ Alog, const float* __restrict__ Dp,
                        u16* __restrict__ Y) {
  const int c = blockIdx.x, h = blockIdx.y, b = blockIdx.z;
  const int tid = threadIdx.x;
  const int lane = tid & 63, w = tid >> 6;
  const int fr = lane & 15, fq = lane >> 4;
  const int bh = b * 32 + h;
  const size_t m0 = (size_t)b * 4096 + c * 256;

  __shared__ u16 sB[256 * 128];     // [tau][n], 16 oct/row, swz ^(tau&15)
  __shared__ u16 sX[64 * 256];      // [p][tau], 32 oct/row, swz ^(p&15)
  __shared__ u16 sH[64 * 128];      // [p][n],  16 oct/row, swz ^(p&15)
  __shared__ u16 sP[8 * 32 * 64];   // per-wave [32t][64tau], 8 oct/row, swz ^(t&7)
  __shared__ float sL[256], sdt[256], spart[4];

  float dtv = 0.f;
  if (tid < 256) dtv = DTt[(size_t)bh * 4096 + c * 256 + tid];
  float expA = __expf(Alog[h]);
  cumsum256(tid, lane, -expA * dtv, dtv, sL, sdt, spart);

  for (int i = tid; i < 4096; i += 512) {
    int tr = i >> 4, oct = i & 15;
    uint4 v = *(const uint4*)(BCtok + ((m0 + tr) << 8) + oct * 8);
    *(uint4*)((char*)sB + tr * 256 + SWZ(tr, oct, 15)) = v;
  }
  for (int i = tid; i < 2048; i += 512) {
    int p = i >> 5, oct = i & 31;
    uint4 v = *(const uint4*)(XT + ((size_t)(b * 2048 + h * 64 + p) << 12) + c * 256 + oct * 8);
    *(uint4*)((char*)sX + p * 512 + SWZ(p, oct, 15)) = v;
  }
  for (int i = tid; i < 1024; i += 512) {
    int p = i >> 4, oct = i & 15;
    const float* src = HB + (size_t)(bh * NCH + c) * 8192 + p * 128 + oct * 8;
    float4 a = *(const float4*)src;
    float4 bb4 = *(const float4*)(src + 4);
    uint4 o;
    o.x = pk2(a.x, a.y); o.y = pk2(a.z, a.w); o.z = pk2(bb4.x, bb4.y); o.w = pk2(bb4.z, bb4.w);
    *(uint4*)((char*)sH + p * 256 + SWZ(p, oct, 15)) = o;
  }
  // C A-fragments (reused by G and Yoff): rows t = w*32+m*16+fr, ch 128+k
  short8 cf[2][4];
  #pragma unroll
  for (int m = 0; m < 2; m++)
    #pragma unroll
    for (int ks = 0; ks < 4; ks++)
      cf[m][ks] = *(const short8*)(BCtok + ((m0 + w * 32 + m * 16 + fr) << 8) + 128 + ks * 32 + fq * 8);
  __syncthreads();

  float Lt[2][4], eLt[2][4];
  #pragma unroll
  for (int m = 0; m < 2; m++)
    #pragma unroll
    for (int q = 0; q < 4; q++) {
      Lt[m][q] = sL[w * 32 + m * 16 + fq * 4 + q];
      eLt[m][q] = __expf(Lt[m][q]);
    }
  const float Dh = Dp[h];

  f32x4 accY[2][4] = {};
  u16* pw = sP + w * 2048;
  const int ntl = (w >> 1) + 1;
  for (int tt = 0; tt < ntl; tt++) {
    const int t0 = tt * 64;
    f32x4 g[2][4] = {};
    #pragma unroll
    for (int ks = 0; ks < 4; ks++) {
      short8 bfm[4];
      #pragma unroll
      for (int nb = 0; nb < 4; nb++) {
        int tr = t0 + nb * 16 + fr;
        bfm[nb] = *(const short8*)((char*)sB + tr * 256 + SWZ(tr, ks * 4 + fq, 15));
      }
      #pragma unroll
      for (int m = 0; m < 2; m++)
        #pragma unroll
        for (int nb = 0; nb < 4; nb++)
          g[m][nb] = __builtin_amdgcn_mfma_f32_16x16x32_bf16(cf[m][ks], bfm[nb], g[m][nb], 0, 0, 0);
    }
    // mask * G -> P (bf16, per-wave LDS); D added to diag AFTER multiplying by G
    #pragma unroll
    for (int nb = 0; nb < 4; nb++) {
      int tau = t0 + nb * 16 + fr;
      float Ltau = sL[tau], dtau = sdt[tau];
      #pragma unroll
      for (int m = 0; m < 2; m++) {
        #pragma unroll
        for (int q = 0; q < 4; q++) {
          int t = w * 32 + m * 16 + fq * 4 + q;
          float mask = (tau > t) ? 0.f : __expf(Lt[m][q] - Ltau) * dtau;
          float pv = mask * g[m][nb][q];
          pv = (tau == t) ? pv + Dh : pv;
          int tl = m * 16 + fq * 4 + q, taul = nb * 16 + fr;
          *(u16*)((char*)pw + tl * 128 + ((((taul) >> 3) ^ (tl & 7)) << 4) + (taul & 7) * 2) = f2bf(pv);
        }
      }
    }
    // P @ X
    #pragma unroll
    for (int ks = 0; ks < 2; ks++) {
      short8 pf[2], xf[4];
      #pragma unroll
      for (int m = 0; m < 2; m++) {
        int tl = m * 16 + fr;
        pf[m] = *(const short8*)((char*)pw + tl * 128 + (((ks * 4 + fq) ^ (tl & 7)) << 4));
      }
      #pragma unroll
      for (int pb = 0; pb < 4; pb++) {
        int p = pb * 16 + fr;
        int oct = (t0 >> 3) + ks * 4 + fq;
        xf[pb] = *(const short8*)((char*)sX + p * 512 + SWZ(p, oct, 15));
      }
      #pragma unroll
      for (int m = 0; m < 2; m++)
        #pragma unroll
        for (int pb = 0; pb < 4; pb++)
          accY[m][pb] = __builtin_amdgcn_mfma_f32_16x16x32_bf16(pf[m], xf[pb], accY[m][pb], 0, 0, 0);
    }
  }
  // Yoff = C @ HinT
  f32x4 accO[2][4] = {};
  #pragma unroll
  for (int ks = 0; ks < 4; ks++) {
    short8 hf[4];
    #pragma unroll
    for (int pb = 0; pb < 4; pb++) {
      int p = pb * 16 + fr;
      hf[pb] = *(const short8*)((char*)sH + p * 256 + SWZ(p, ks * 4 + fq, 15));
    }
    #pragma unroll
    for (int m = 0; m < 2; m++)
      #pragma unroll
      for (int pb = 0; pb < 4; pb++)
        accO[m][pb] = __builtin_amdgcn_mfma_f32_16x16x32_bf16(cf[m][ks], hf[pb], accO[m][pb], 0, 0, 0);
  }
  #pragma unroll
  for (int m = 0; m < 2; m++)
    #pragma unroll
    for (int pb = 0; pb < 4; pb++)
      #pragma unroll
      for (int q = 0; q < 4; q++) {
        int t = w * 32 + m * 16 + fq * 4 + q;
        float val = accY[m][pb][q] + eLt[m][q] * accO[m][pb][q];
        Y[(m0 + t) * 2048 + h * 64 + pb * 16 + fr] = f2bf(val);
      }
}

// ---------- fallback: sequential scan on new layouts ----------
__launch_bounds__(256)
__global__ void k_scan(const u16* __restrict__ XT, const u16* __restrict__ BCtok,
                       const float* __restrict__ DTt, const float* __restrict__ DECt,
                       const float* __restrict__ Dp, u16* __restrict__ y) {
  const int ps = blockIdx.x, h = blockIdx.y, b = blockIdx.z;
  const int tid = threadIdx.x;
  const int tsub = tid & 15, pl = tid >> 4;
  const int p = ps * 16 + pl;
  const u16* xp = XT + ((size_t)(b * 2048 + h * 64 + p)) * 4096;
  const float* dth = DTt + (size_t)(b * 32 + h) * 4096;
  const float* dch = DECt + (size_t)(b * 32 + h) * 4096;
  u16* yp = y + (size_t)b * 4096 * 2048 + h * 64 + p;
  const float Dh = Dp[h];
  float s0 = 0, s1 = 0, s2 = 0, s3 = 0, s4 = 0, s5 = 0, s6 = 0, s7 = 0;
  for (int tau = 0; tau < 4096; ++tau) {
    const u16* bcr = BCtok + ((size_t)(b * 4096 + tau)) * 256;
    uint4 vB = *(const uint4*)(bcr + tsub * 8);
    uint4 vC = *(const uint4*)(bcr + 128 + tsub * 8);
    float xv = bf2f(xp[tau]);
    float a = dth[tau] * xv;
    float dcv = dch[tau];
    s0 = s0 * dcv + a * bf2f((u16)(vB.x & 0xFFFF)); s1 = s1 * dcv + a * bf2f((u16)(vB.x >> 16));
    s2 = s2 * dcv + a * bf2f((u16)(vB.y & 0xFFFF)); s3 = s3 * dcv + a * bf2f((u16)(vB.y >> 16));
    s4 = s4 * dcv + a * bf2f((u16)(vB.z & 0xFFFF)); s5 = s5 * dcv + a * bf2f((u16)(vB.z >> 16));
    s6 = s6 * dcv + a * bf2f((u16)(vB.w & 0xFFFF)); s7 = s7 * dcv + a * bf2f((u16)(vB.w >> 16));
    float sum = s0 * bf2f((u16)(vC.x & 0xFFFF)) + s1 * bf2f((u16)(vC.x >> 16))
              + s2 * bf2f((u16)(vC.y & 0xFFFF)) + s3 * bf2f((u16)(vC.y >> 16))
              + s4 * bf2f((u16)(vC.z & 0xFFFF)) + s5 * bf2f((u16)(vC.z >> 16))
              + s6 * bf2f((u16)(vC.w & 0xFFFF)) + s7 * bf2f((u16)(vC.w >> 16));
    sum += __shfl_xor(sum, 1, 64);
    sum += __shfl_xor(sum, 2, 64);
    sum += __shfl_xor(sum, 4, 64);
    sum += __shfl_xor(sum, 8, 64);
    if (tsub == 0) yp[(size_t)tau * 2048] = f2bf(sum + Dh * xv);
  }
}

// ---------- gated RMSNorm (vectorized: uint4 loads, thread owns 8 channels) ----------
__global__ void k_gate(const u16* __restrict__ y, const u16* __restrict__ zx,
                       const float* __restrict__ normw, u16* __restrict__ u, int flip) {
  const int m = blockIdx.x, tid = threadIdx.x;
  const int ms = flip ? (m ^ 4095) : m;
  uint4 yv = *(const uint4*)(y + (size_t)m * 2048 + tid * 8);
  uint4 zv = *(const uint4*)(zx + (size_t)ms * 4480 + tid * 8);
  const u16* yp = (const u16*)&yv;
  const u16* zp = (const u16*)&zv;
  float vals[8];
  float ss = 0.f;
  #pragma unroll
  for (int i = 0; i < 8; i++) {
    float zf = bf2f(zp[i]);
    float wv = bf2f(yp[i]) * (zf / (1.f + __expf(-zf)));
    vals[i] = wv;
    ss += wv * wv;
  }
  float rs = rsqrtf(block_sum256(ss) * (1.f / 2048.f) + 1e-5f);
  float4 n0 = *(const float4*)(normw + tid * 8);
  float4 n1 = *(const float4*)(normw + tid * 8 + 4);
  uint4 o;
  o.x = pk2(vals[0] * rs * n0.x, vals[1] * rs * n0.y);
  o.y = pk2(vals[2] * rs * n0.z, vals[3] * rs * n0.w);
  o.z = pk2(vals[4] * rs * n1.x, vals[5] * rs * n1.y);
  o.w = pk2(vals[6] * rs * n1.z, vals[7] * rs * n1.w);
  *(uint4*)(u + (size_t)m * 2048 + tid * 8) = o;
}

// ---------- final LN + residual ----------
__global__ void k_final(const float* __restrict__ t2, const float* __restrict__ bias,
                        const float* __restrict__ g, const float* __restrict__ bb,
                        const float* __restrict__ x, float* __restrict__ out) {
  const int row = blockIdx.x, tid = threadIdx.x;
  float2 v = ((const float2*)(t2 + (size_t)row * 512))[tid];
  float v0 = v.x + bias[tid * 2], v1 = v.y + bias[tid * 2 + 1];
  float mean = block_sum256(v0 + v1) * (1.f / 512.f);
  float d0 = v0 - mean, d1 = v1 - mean;
  float var = block_sum256(d0 * d0 + d1 * d1) * (1.f / 512.f);
  float rs = rsqrtf(var + 1e-5f);
  float2 xr = ((const float2*)(x + (size_t)row * 512))[tid];
  float2 o;
  o.x = d0 * rs * g[tid * 2] + bb[tid * 2] + xr.x;
  o.y = d1 * rs * g[tid * 2 + 1] + bb[tid * 2 + 1] + xr.y;
  ((float2*)(out + (size_t)row * 512))[tid] = o;
}

extern "C" void kernel_launch(void* const* d_in, const int* in_sizes, int n_in,
                              void* d_out, int out_size, void* d_ws, size_t ws_size,
                              hipStream_t stream) {
  const float* x      = (const float*)d_in[0];
  const float* pre_w  = (const float*)d_in[1];
  const float* pre_b  = (const float*)d_in[2];
  const float* pre_g  = (const float*)d_in[3];
  const float* pre_bb = (const float*)d_in[4];
  const float* post_w = (const float*)d_in[5];
  const float* post_b = (const float*)d_in[6];
  const float* post_g = (const float*)d_in[7];
  const float* post_bb= (const float*)d_in[8];
  const float* win_[2]   = {(const float*)d_in[9],  (const float*)d_in[17]};
  const float* convw_[2] = {(const float*)d_in[10], (const float*)d_in[18]};
  const float* convb_[2] = {(const float*)d_in[11], (const float*)d_in[19]};
  const float* dtb_[2]   = {(const float*)d_in[12], (const float*)d_in[20]};
  const float* Alog_[2]  = {(const float*)d_in[13], (const float*)d_in[21]};
  const float* Dp_[2]    = {(const float*)d_in[14], (const float*)d_in[22]};
  const float* normw_[2] = {(const float*)d_in[15], (const float*)d_in[23]};
  const float* wout_[2]  = {(const float*)d_in[16], (const float*)d_in[24]};

  char* ws = (char*)d_ws;
  constexpr size_t OFF_WT_PRE  = 0;                         // 1 MB (PR aliases later)
  constexpr size_t OFF_WT_WINF = OFF_WT_PRE  + 1048576;
  constexpr size_t OFF_WT_WINB = OFF_WT_WINF + 9175040;
  constexpr size_t OFF_WT_WOF  = OFF_WT_WINB + 9175040;
  constexpr size_t OFF_WT_WOB  = OFF_WT_WOF  + 4194304;
  constexpr size_t OFF_WT_POST = OFF_WT_WOB  + 4194304;
  constexpr size_t OFF_HPRE    = OFF_WT_POST + 1048576;     // 16 MB
  constexpr size_t OFF_ZX      = OFF_HPRE + 16777216;       // 70 MB
  constexpr size_t OFF_XT      = OFF_ZX + 73400320;         // 32 MB: XT [2][2048][4096] bf16
  constexpr size_t OFF_BC      = OFF_XT + 33554432;         // 4 MB BCtok + 4 MB BCT
  constexpr size_t OFF_DT      = OFF_BC + 8388608;          // 1 MB DT_T
  constexpr size_t OFF_DEC     = OFF_DT + 1048576;          // 1 MB DEC_T
  constexpr size_t OFF_Y       = OFF_DEC + 1048576;         // 16 MB bf16 y
  constexpr size_t OFF_S       = OFF_Y + 33554432;          // 32 MB
  constexpr size_t OFF_HB      = OFF_S + 33554432;          // 32 MB
  constexpr size_t ARENA_END   = OFF_HB + 33554432;         // == 263716864

  u16* WtPre    = (u16*)(ws + OFF_WT_PRE);
  u16* WtWin[2] = {(u16*)(ws + OFF_WT_WINF), (u16*)(ws + OFF_WT_WINB)};
  u16* WtWo[2]  = {(u16*)(ws + OFF_WT_WOF),  (u16*)(ws + OFF_WT_WOB)};
  u16* WtPost   = (u16*)(ws + OFF_WT_POST);
  u16* HPRE = (u16*)(ws + OFF_HPRE);
  u16* ZX   = (u16*)(ws + OFF_ZX);
  u16* XT   = (u16*)(ws + OFF_XT);
  u16* BCtok= (u16*)(ws + OFF_BC);
  u16* BCT  = (u16*)(ws + OFF_BC + 4194304);
  float* DTt = (float*)(ws + OFF_DT);
  float* DECt= (float*)(ws + OFF_DEC);
  u16*  Y   = (u16*)(ws + OFF_Y);
  float* S  = (float*)(ws + OFF_S);
  float* HB = (float*)(ws + OFF_HB);
  // aliases
  float* PRb  = (float*)(ws + OFF_WT_PRE); // 4 KB (WtPre dead after pre-GEMM)
  u16*   XBF  = (u16*)(ws + OFF_Y);        // bf16 x for pre-GEMM
  float* TMP  = S;                         // pre-GEMM f32 out
  u16*   U    = (u16*)(ws + OFF_XT);       // gated y bf16 (XT dead after ssd_c)
  u16*   U2   = ZX;                        // final gated sum (ZX dead)
  float* TMP2 = (float*)(ws + OFF_XT);     // post-GEMM f32 out (U dead)

  const bool chunked = (ws_size >= ARENA_END);

  dim3 tb(32, 8);
  k_tcast<<<dim3(32, 16),  tb, 0, stream>>>(pre_w,   WtPre,    512, 1024, 1024);
  k_tcast<<<dim3(140, 32), tb, 0, stream>>>(win_[0], WtWin[0], 1024, 4384, 4480);
  k_tcast<<<dim3(140, 32), tb, 0, stream>>>(win_[1], WtWin[1], 1024, 4384, 4480);
  k_tcast<<<dim3(32, 64),  tb, 0, stream>>>(wout_[0], WtWo[0], 2048, 1024, 1024);
  k_tcast<<<dim3(32, 64),  tb, 0, stream>>>(wout_[1], WtWo[1], 2048, 1024, 1024);
  k_tcast<<<dim3(16, 32),  tb, 0, stream>>>(post_w,  WtPost,   1024,  512,  512);
  k_cast<<<4096, 256, 0, stream>>>(x, XBF, 1048576);
  k_gemm<<<dim3(64, 8), 256, 0, stream>>>(XBF, WtPre, TMP, nullptr, nullptr,
                                          8192, 1024, 512, 1024, 0);
  k_preln<<<8192, 256, 0, stream>>>(TMP, pre_b, pre_g, pre_bb, HPRE);

  for (int d = 0; d < 2; d++) {
    int flip = d;
    k_gemm256<<<dim3(32, 18), 512, 0, stream>>>(HPRE, WtWin[d], ZX);
    k_dt2<<<dim3(16, 32, 2), 256, 0, stream>>>(ZX, dtb_[d], Alog_[d], DTt, DECt, flip);
    k_conv2<<<dim3(36, 64, 2), 256, 0, stream>>>(ZX, convw_[d], convb_[d], XT, BCtok, BCT, flip);
    if (chunked) {
      k_ssd_a<<<dim3(NCH, 32, 2), 512, 0, stream>>>(XT, BCT, DTt, Alog_[d], HB, PRb);
      k_scan_b<<<dim3(32, 32, 2), 256, 0, stream>>>(HB, PRb);
      k_ssd_c<<<dim3(NCH, 32, 2), 512, 0, stream>>>(BCtok, XT, DTt, HB, Alog_[d], Dp_[d], Y);
    } else {
      k_scan<<<dim3(4, 32, 2), 256, 0, stream>>>(XT, BCtok, DTt, DECt, Dp_[d], Y);
    }
    k_gate<<<8192, 256, 0, stream>>>(Y, ZX, normw_[d], U, flip);
    // d=0: plain f32 out to S. d=1: accumulate S + fused u2 (silu(HPRE)) -> bf16 U2.
    if (d == 0) {
      k_gemm<<<dim3(64, 8), 256, 0, stream>>>(U, WtWo[d], S, nullptr, nullptr,
                                              8192, 1024, 2048, 1024, 0);
    } else {
      k_gemm<<<dim3(64, 8), 256, 0, stream>>>(U, WtWo[d], S, U2, HPRE,
                                              8192, 1024, 2048, 1024, 1 | 2 | 4 | 8);
    }
  }

  k_gemm<<<dim3(64, 4), 256, 0, stream>>>(U2, WtPost, TMP2, nullptr, nullptr,
                                          8192, 512, 1024, 512, 0);
  k_final<<<8192, 256, 0, stream>>>(TMP2, post_b, post_g, post_bb, x, (float*)d_out);
}

// Round 17
// 706.031 us; speedup vs baseline: 1.1053x; 1.0252x over previous
//
#include <hip/hip_runtime.h>
#include <stdint.h>

typedef unsigned short u16;
typedef __attribute__((ext_vector_type(8))) short short8;
typedef __attribute__((ext_vector_type(4))) float f32x4;

__device__ __forceinline__ float bf2f(u16 u) {
  union { float f; uint32_t i; } v; v.i = ((uint32_t)u) << 16; return v.f;
}
__device__ __forceinline__ u16 f2bf(float f) {
  union { float f; uint32_t i; } v; v.f = f;
  uint32_t r = v.i + 0x7FFFu + ((v.i >> 16) & 1u);
  return (u16)(r >> 16);
}
__device__ __forceinline__ uint32_t pk2(float a, float b) {
  return (uint32_t)f2bf(a) | ((uint32_t)f2bf(b) << 16);
}
// async global->LDS, 16B per lane; LDS dest is wave-uniform base + lane*16
__device__ __forceinline__ void gload16(const u16* g, u16* l) {
  __builtin_amdgcn_global_load_lds(
      (const __attribute__((address_space(1))) unsigned int*)g,
      (__attribute__((address_space(3))) unsigned int*)l, 16, 0, 0);
}

__device__ __forceinline__ float block_sum256(float v) {
  __shared__ float red[4];
  #pragma unroll
  for (int o = 1; o < 64; o <<= 1) v += __shfl_xor(v, o, 64);
  int lane = threadIdx.x & 63, w = threadIdx.x >> 6;
  __syncthreads();
  if (lane == 0) red[w] = v;
  __syncthreads();
  return red[0] + red[1] + red[2] + red[3];
}

// ---------- W[K][N] f32 -> Wt[Npad][K] bf16 (zero-pad rows >= N) ----------
__global__ void k_tcast(const float* __restrict__ W, u16* __restrict__ Wt,
                        int K, int N, int Npad) {
  __shared__ float tile[32][33];
  int n0 = blockIdx.x * 32, k0 = blockIdx.y * 32;
  int tx = threadIdx.x, ty0 = threadIdx.y;
  #pragma unroll
  for (int i = 0; i < 4; i++) {
    int ty = ty0 + i * 8;
    int k = k0 + ty, n = n0 + tx;
    tile[ty][tx] = (k < K && n < N) ? W[(size_t)k * N + n] : 0.f;
  }
  __syncthreads();
  #pragma unroll
  for (int i = 0; i < 4; i++) {
    int ty = ty0 + i * 8;
    int n = n0 + ty, k = k0 + tx;
    if (n < Npad && k < K) Wt[(size_t)n * K + k] = f2bf(tile[tx][ty]);
  }
}

// ---------- f32 -> bf16 elementwise (x4) ----------
__global__ void k_cast(const float* __restrict__ in, u16* __restrict__ out, int n4) {
  int i = blockIdx.x * 256 + threadIdx.x;
  if (i >= n4) return;
  float4 v = ((const float4*)in)[i];
  uint2 o;
  o.x = pk2(v.x, v.y);
  o.y = pk2(v.z, v.w);
  ((uint2*)out)[i] = o;
}

// ---------- 128x128 bf16 MFMA GEMM (dbuf global_load_lds), general ----------
// flags: 1=bf16 out, 2=accum f32 Cf, 4=flip row, 8=fuse u2 (v *= silu(hp)),
//        16=accum bf16 ab
__launch_bounds__(256)
__global__ void k_gemm(const u16* __restrict__ A, const u16* __restrict__ Bt,
                       float* __restrict__ Cf, u16* __restrict__ Cb,
                       const u16* __restrict__ hp, const u16* __restrict__ ab,
                       int M, int N, int K, int ldc, int flags) {
  __shared__ u16 lA[2][128 * 64];
  __shared__ u16 lB[2][128 * 64];
  const int tid = threadIdx.x;
  const int lane = tid & 63;
  const int wave = tid >> 6;
  const int bm = blockIdx.x, bn = blockIdx.y;
  const int wr = wave >> 1, wc = wave & 1;
  const int fr = lane & 15, fq = lane >> 4;

  const int srow = wave * 32 + (lane >> 3);
  const int scol = ((lane & 7) ^ (srow & 7)) * 8;   // inverse-swizzled source col
  const u16* gA = A + (size_t)(bm * 128 + srow) * K + scol;
  const u16* gB = Bt + (size_t)(bn * 128 + srow) * K + scol;
  const int lofs = wave * 2048;

  f32x4 acc[4][4] = {};

  #pragma unroll
  for (int i = 0; i < 4; i++) {
    gload16(gA + (size_t)(i * 8) * K, &lA[0][lofs + i * 512]);
    gload16(gB + (size_t)(i * 8) * K, &lB[0][lofs + i * 512]);
  }
  __syncthreads();

  const int NT = K >> 6;
  for (int t = 0; t < NT; ++t) {
    const int cur = t & 1;
    if (t + 1 < NT) {
      const int kt = (t + 1) << 6;
      #pragma unroll
      for (int i = 0; i < 4; i++) {
        gload16(gA + (size_t)(i * 8) * K + kt, &lA[cur ^ 1][lofs + i * 512]);
        gload16(gB + (size_t)(i * 8) * K + kt, &lB[cur ^ 1][lofs + i * 512]);
      }
    }
    #pragma unroll
    for (int kk = 0; kk < 2; kk++) {
      short8 af[4], bfr[4];
      #pragma unroll
      for (int m = 0; m < 4; m++) {
        int row = wr * 64 + m * 16 + fr;
        int sl = (kk * 4 + fq) ^ (row & 7);
        af[m] = *(const short8*)(&lA[cur][row * 64 + sl * 8]);
      }
      #pragma unroll
      for (int n = 0; n < 4; n++) {
        int row = wc * 64 + n * 16 + fr;
        int sl = (kk * 4 + fq) ^ (row & 7);
        bfr[n] = *(const short8*)(&lB[cur][row * 64 + sl * 8]);
      }
      #pragma unroll
      for (int m = 0; m < 4; m++)
        #pragma unroll
        for (int n = 0; n < 4; n++)
          acc[m][n] = __builtin_amdgcn_mfma_f32_16x16x32_bf16(af[m], bfr[n], acc[m][n], 0, 0, 0);
    }
    __syncthreads();   // drains next-tile loads (latency hidden under compute above)
  }

  const bool bf16out = flags & 1, accum = flags & 2, flip = flags & 4, fuse = flags & 8;
  const bool accb = flags & 16;
  #pragma unroll
  for (int m = 0; m < 4; m++) {
    #pragma unroll
    for (int q = 0; q < 4; q++) {
      int rr = bm * 128 + wr * 64 + m * 16 + fq * 4 + q;
      int orow = flip ? (rr ^ 4095) : rr;
      size_t rb = (size_t)orow * ldc;
      #pragma unroll
      for (int n = 0; n < 4; n++) {
        int cc = bn * 128 + wc * 64 + n * 16 + fr;
        float v = acc[m][n][q];
        if (accum) v += Cf[rb + cc];
        if (accb) v += bf2f(ab[rb + cc]);
        if (fuse) {
          float h = bf2f(hp[rb + cc]);
          v = v * (h / (1.f + __expf(-h)));
        }
        if (bf16out) Cb[rb + cc] = f2bf(v);
        else Cf[rb + cc] = v;
      }
    }
  }
}

// ---------- 256x256 bf16 MFMA GEMM for the win projection (r11 proven) ----------
// 8 waves (2Mx4N), per-wave 128x64, BK=64, 128 KiB LDS dbuf, 2-barrier
// structure, counted vmcnt(8) at tile boundaries (never drain mid-loop).
// Fixed shape: M=8192, K=1024, N=4480 (18 N-tiles; ragged: B-row clamp + C guard).
__launch_bounds__(512)
__global__ void k_gemm256(const u16* __restrict__ A, const u16* __restrict__ Bt,
                          u16* __restrict__ Cb) {
  constexpr int K = 1024, N = 4480, NT = 16;
  __shared__ u16 lA[2][256 * 64];
  __shared__ u16 lB[2][256 * 64];
  const int tid = threadIdx.x;
  const int lane = tid & 63;
  const int wid = tid >> 6;
  const int bm = blockIdx.x, bn = blockIdx.y;
  const int wr = wid >> 2, wc = wid & 3;       // 2 x 4 waves
  const int fr = lane & 15, fq = lane >> 4;

  const int srow = tid >> 3;                    // 0..63
  const int scol = ((tid & 7) ^ (srow & 7)) * 8;
  const u16* gA[4];
  const u16* gB[4];
  #pragma unroll
  for (int i = 0; i < 4; i++) {
    int arow = bm * 256 + i * 64 + srow;
    gA[i] = A + (size_t)arow * K + scol;
    int brow = bn * 256 + i * 64 + srow;
    if (brow > N - 1) brow = N - 1;             // ragged-N clamp (cols guarded at C)
    gB[i] = Bt + (size_t)brow * K + scol;
  }

  f32x4 acc[8][4] = {};

  auto stage = [&](int u) {
    const int buf = u & 1, kt = u << 6;
    #pragma unroll
    for (int i = 0; i < 4; i++)
      gload16(gA[i] + kt, &lA[buf][i * 4096 + tid * 8]);
    #pragma unroll
    for (int i = 0; i < 4; i++)
      gload16(gB[i] + kt, &lB[buf][i * 4096 + tid * 8]);
  };

  // prologue: tiles 0,1 in flight; wait tile 0 only (8 newest stay pending)
  stage(0);
  stage(1);
  asm volatile("s_waitcnt vmcnt(8)" ::: "memory");
  __builtin_amdgcn_s_barrier();

  for (int t = 0; t < NT; ++t) {
    const u16* bufA = &lA[t & 1][0];
    const u16* bufB = &lB[t & 1][0];
    #pragma unroll
    for (int kk = 0; kk < 2; kk++) {
      short8 af[8], bfm[4];
      #pragma unroll
      for (int m = 0; m < 8; m++) {
        int row = wr * 128 + m * 16 + fr;
        int sl = (kk * 4 + fq) ^ (row & 7);
        af[m] = *(const short8*)(&bufA[row * 64 + sl * 8]);
      }
      #pragma unroll
      for (int n = 0; n < 4; n++) {
        int row = wc * 64 + n * 16 + fr;
        int sl = (kk * 4 + fq) ^ (row & 7);
        bfm[n] = *(const short8*)(&bufB[row * 64 + sl * 8]);
      }
      #pragma unroll
      for (int m = 0; m < 8; m++)
        #pragma unroll
        for (int n = 0; n < 4; n++)
          acc[m][n] = __builtin_amdgcn_mfma_f32_16x16x32_bf16(af[m], bfm[n], acc[m][n], 0, 0, 0);
    }
    // boundary: buf[t&1] dead -> stage t+2 there; counted wait: t+1 landed,
    // t+2's 8 loads stay in flight (never drain to 0 mid-loop)
    __builtin_amdgcn_s_barrier();
    if (t + 2 < NT) {
      stage(t + 2);
      asm volatile("s_waitcnt vmcnt(8)" ::: "memory");
    } else {
      asm volatile("s_waitcnt vmcnt(0)" ::: "memory");
    }
    __builtin_amdgcn_s_barrier();
  }

  #pragma unroll
  for (int m = 0; m < 8; m++) {
    #pragma unroll
    for (int q = 0; q < 4; q++) {
      size_t rb = (size_t)(bm * 256 + wr * 128 + m * 16 + fq * 4 + q) * N;
      #pragma unroll
      for (int n = 0; n < 4; n++) {
        int cc = bn * 256 + wc * 64 + n * 16 + fr;
        if (cc < N) Cb[rb + cc] = f2bf(acc[m][n][q]);
      }
    }
  }
}

// ---------- pre-LN ----------
__global__ void k_preln(const float* __restrict__ t, const float* __restrict__ bias,
                        const float* __restrict__ g, const float* __restrict__ bb,
                        u16* __restrict__ out) {
  const int row = blockIdx.x, tid = threadIdx.x;
  float4 v = ((const float4*)(t + (size_t)row * 1024))[tid];
  float4 bi = ((const float4*)bias)[tid];
  float v0 = v.x + bi.x, v1 = v.y + bi.y, v2 = v.z + bi.z, v3 = v.w + bi.w;
  float mean = block_sum256(v0 + v1 + v2 + v3) * (1.f / 1024.f);
  float d0 = v0 - mean, d1 = v1 - mean, d2 = v2 - mean, d3 = v3 - mean;
  float var = block_sum256(d0 * d0 + d1 * d1 + d2 * d2 + d3 * d3) * (1.f / 1024.f);
  float rs = rsqrtf(var + 1e-5f);
  float4 gg = ((const float4*)g)[tid];
  float4 bv = ((const float4*)bb)[tid];
  uint2 o;
  o.x = pk2(d0 * rs * gg.x + bv.x, d1 * rs * gg.y + bv.y);
  o.y = pk2(d2 * rs * gg.z + bv.z, d3 * rs * gg.w + bv.w);
  ((uint2*)(out + (size_t)row * 1024))[tid] = o;
}

// ---------- dt/dec in [b][h][t] (flipped-domain) layout ----------
__global__ void k_dt2(const u16* __restrict__ zx, const float* __restrict__ dtb,
                      const float* __restrict__ Alog, float* __restrict__ DTt,
                      float* __restrict__ DECt, int flip) {
  int t = blockIdx.x * 256 + threadIdx.x;
  int h = blockIdx.y, b = blockIdx.z;
  int ts = flip ? 4095 - t : t;
  float raw = bf2f(zx[(size_t)((b << 12) + ts) * 4480 + 4352 + h]) + dtb[h];
  float d = (raw > 20.f) ? raw : log1pf(__expf(raw));
  size_t o = (size_t)(b * 32 + h) * 4096 + t;
  DTt[o] = d;
  DECt[o] = __expf(-__expf(Alog[h]) * d);
}

// ---------- conv(K=4)+silu; vectorized I/O; outputs XT [b][2048][4096],
// ---------- BCtok [m][256] bf16, BCT [b][256][4096] (flipped-domain) ----------
__global__ void k_conv2(const u16* __restrict__ zx, const float* __restrict__ cw,
                        const float* __restrict__ cb, u16* __restrict__ XT,
                        u16* __restrict__ BCtok, u16* __restrict__ BCT, int flip) {
  const int ct = blockIdx.x;           // 0..35 channel tile (64)
  const int tt = blockIdx.y;           // 0..63 token tile (64)
  const int b = blockIdx.z;
  const int tid = threadIdx.x;         // 256
  __shared__ float sin_[67][64];
  __shared__ float sout[64][65];
  const int ch0 = ct * 64, t0 = tt * 64;

  // staging: uint2 = 4 ch/thread; 67 rows x 16 quads
  for (int i = tid; i < 67 * 16; i += 256) {
    int r = i >> 4, c4 = (i & 15) << 2;
    int tok = t0 - 3 + r;
    float f0 = 0.f, f1 = 0.f, f2 = 0.f, f3 = 0.f;
    if (tok >= 0) {
      int src = (b << 12) + (flip ? 4095 - tok : tok);
      uint2 v = *(const uint2*)(zx + (size_t)src * 4480 + 2048 + ch0 + c4);
      f0 = bf2f((u16)(v.x & 0xFFFF)); f1 = bf2f((u16)(v.x >> 16));
      f2 = bf2f((u16)(v.y & 0xFFFF)); f3 = bf2f((u16)(v.y >> 16));
    }
    sin_[r][c4] = f0; sin_[r][c4 + 1] = f1; sin_[r][c4 + 2] = f2; sin_[r][c4 + 3] = f3;
  }
  __syncthreads();

  const int ch = tid & 63, g = tid >> 6;
  const int chg = ch0 + ch;
  float4 wv = *(const float4*)(cw + (size_t)chg * 4);
  float bias = cb[chg];
  #pragma unroll
  for (int i = 0; i < 16; i++) {
    int tl = g * 16 + i;
    float a = bias + wv.x * sin_[tl][ch] + wv.y * sin_[tl + 1][ch]
                   + wv.z * sin_[tl + 2][ch] + wv.w * sin_[tl + 3][ch];
    sout[tl][ch] = a / (1.f + __expf(-a));
  }
  __syncthreads();

  if (ch0 < 2048) {
    for (int i = tid; i < 64 * 16; i += 256) {
      int chw = i >> 4, t4 = (i & 15) << 2;
      uint2 o;
      o.x = pk2(sout[t4][chw], sout[t4 + 1][chw]);
      o.y = pk2(sout[t4 + 2][chw], sout[t4 + 3][chw]);
      *(uint2*)(XT + ((size_t)(b * 2048 + ch0 + chw)) * 4096 + t0 + t4) = o;
    }
  } else {
    int c2b = (ct - 32) * 64;
    for (int i = tid; i < 64 * 16; i += 256) {
      int chw = i >> 4, t4 = (i & 15) << 2;
      uint2 o;
      o.x = pk2(sout[t4][chw], sout[t4 + 1][chw]);
      o.y = pk2(sout[t4 + 2][chw], sout[t4 + 3][chw]);
      *(uint2*)(BCT + ((size_t)(b * 256 + c2b + chw)) * 4096 + t0 + t4) = o;
    }
    for (int i = tid; i < 64 * 8; i += 256) {
      int r = i >> 3, c8 = (i & 7) << 3;
      uint4 o;
      o.x = pk2(sout[r][c8], sout[r][c8 + 1]);
      o.y = pk2(sout[r][c8 + 2], sout[r][c8 + 3]);
      o.z = pk2(sout[r][c8 + 4], sout[r][c8 + 5]);
      o.w = pk2(sout[r][c8 + 6], sout[r][c8 + 7]);
      *(uint4*)(BCtok + ((size_t)(b * 4096 + t0 + r)) * 256 + c2b + c8) = o;
    }
  }
}

// ================= SSD chunked scan, Q=256, NCH=16 =================
#define NCH 16
#define SWZ(row, oct, msk) (((oct) ^ ((row) & (msk))) << 4)

// inclusive cumsum helper over 256 threads (first 4 waves), returns L for tid<256
__device__ __forceinline__ void cumsum256(int tid, int lane, float adt, float dtv,
                                          float* sL, float* sdt, float* spart) {
  float v = adt;
  if (tid < 256) {
    #pragma unroll
    for (int o = 1; o < 64; o <<= 1) {
      float t = __shfl_up(v, o, 64);
      if (lane >= o) v += t;
    }
    if (lane == 63) spart[tid >> 6] = v;
  }
  __syncthreads();
  if (tid < 256) {
    int w = tid >> 6;
    float off = 0.f;
    #pragma unroll
    for (int j = 0; j < 3; j++) if (j < w) off += spart[j];
    sL[tid] = v + off;
    sdt[tid] = dtv;
  }
}

// pass A: H_localT[p][n] = sum_tau w_tau * X[tau][p] * B[tau][n], PR = exp(Lend)
__launch_bounds__(512, 1)
__global__ void k_ssd_a(const u16* __restrict__ XT, const u16* __restrict__ BCT,
                        const float* __restrict__ DTt, const float* __restrict__ Alog,
                        float* __restrict__ HB, float* __restrict__ PR) {
  const int c = blockIdx.x, h = blockIdx.y, b = blockIdx.z;
  const int tid = threadIdx.x;
  const int lane = tid & 63, w = tid >> 6;
  const int fr = lane & 15, fq = lane >> 4;
  const int bh = b * 32 + h;

  __shared__ u16 sX[64 * 256];      // [p][tau], 32 oct/row, swz ^(p&15)
  __shared__ u16 sBW[128 * 256];    // [n][tau], 32 oct/row, swz ^(n&15)
  __shared__ float sL[256], sdt[256], sw_[256], spart[4];

  float dtv = 0.f;
  if (tid < 256) dtv = DTt[(size_t)bh * 4096 + c * 256 + tid];
  float expA = __expf(Alog[h]);
  cumsum256(tid, lane, -expA * dtv, dtv, sL, sdt, spart);
  __syncthreads();
  if (tid < 256) sw_[tid] = __expf(sL[255] - sL[tid]) * sdt[tid];
  for (int i = tid; i < 2048; i += 512) {
    int p = i >> 5, oct = i & 31;
    uint4 v = *(const uint4*)(XT + ((size_t)(b * 2048 + h * 64 + p) << 12) + c * 256 + oct * 8);
    *(uint4*)((char*)sX + p * 512 + SWZ(p, oct, 15)) = v;
  }
  __syncthreads();
  for (int i = tid; i < 4096; i += 512) {
    int n = i >> 5, oct = i & 31;
    uint4 v = *(const uint4*)(BCT + ((size_t)(b * 256 + n) << 12) + c * 256 + oct * 8);
    const float* swp = sw_ + oct * 8;
    float f0 = bf2f((u16)(v.x & 0xFFFF)) * swp[0];
    float f1 = bf2f((u16)(v.x >> 16)) * swp[1];
    float f2 = bf2f((u16)(v.y & 0xFFFF)) * swp[2];
    float f3 = bf2f((u16)(v.y >> 16)) * swp[3];
    float f4 = bf2f((u16)(v.z & 0xFFFF)) * swp[4];
    float f5 = bf2f((u16)(v.z >> 16)) * swp[5];
    float f6 = bf2f((u16)(v.w & 0xFFFF)) * swp[6];
    float f7 = bf2f((u16)(v.w >> 16)) * swp[7];
    uint4 o;
    o.x = pk2(f0, f1); o.y = pk2(f2, f3); o.z = pk2(f4, f5); o.w = pk2(f6, f7);
    *(uint4*)((char*)sBW + n * 512 + SWZ(n, oct, 15)) = o;
  }
  __syncthreads();

  const int pb = w >> 1, nh = w & 1;
  f32x4 acc[4] = {};
  #pragma unroll
  for (int ks = 0; ks < 8; ks++) {
    int p = pb * 16 + fr;
    short8 af = *(const short8*)((char*)sX + p * 512 + SWZ(p, ks * 4 + fq, 15));
    #pragma unroll
    for (int nb = 0; nb < 4; nb++) {
      int n = nh * 64 + nb * 16 + fr;
      short8 bfm = *(const short8*)((char*)sBW + n * 512 + SWZ(n, ks * 4 + fq, 15));
      acc[nb] = __builtin_amdgcn_mfma_f32_16x16x32_bf16(af, bfm, acc[nb], 0, 0, 0);
    }
  }
  float* hb = HB + (size_t)(bh * NCH + c) * 8192;
  #pragma unroll
  for (int nb = 0; nb < 4; nb++)
    #pragma unroll
    for (int q = 0; q < 4; q++) {
      int p = pb * 16 + fq * 4 + q;
      int n = nh * 64 + nb * 16 + fr;
      hb[p * 128 + n] = acc[nb][q];
    }
  if (tid == 0) PR[bh * NCH + c] = __expf(sL[255]);
}

// pass B: sequential combine over chunk boundaries
__global__ void k_scan_b(float* __restrict__ HB, const float* __restrict__ PR) {
  const int eb = blockIdx.x, h = blockIdx.y, b = blockIdx.z;
  const int e = eb * 256 + threadIdx.x;
  const int bh = b * 32 + h;
  float* base = HB + (size_t)bh * NCH * 8192 + e;
  const float* pr = PR + bh * NCH;
  float carry = 0.f;
  #pragma unroll 4
  for (int c = 0; c < NCH; ++c) {
    float v = base[(size_t)c * 8192];
    base[(size_t)c * 8192] = carry;
    carry = pr[c] * carry + v;
  }
}

// pass C: y = (M.(C B^T)) X + exp(L_t) (C Hin) ; D-term added to P diag AFTER *G
// SIMD-balanced wave->t-block map: tb = w<4 ? w : 11-w pairs causal costs
// (1+4),(1+4),(2+3),(2+3) on the 4 SIMDs (waves s,s+4 co-resident) -> 5 each.
__launch_bounds__(512, 1)
__global__ void k_ssd_c(const u16* __restrict__ BCtok, const u16* __restrict__ XT,
                        const float* __restrict__ DTt, const float* __restrict__ HB,
                        const float* __restrict__ Alog, const float* __restrict__ Dp,
                        u16* __restrict__ Y) {
  const int c = blockIdx.x, h = blockIdx.y, b = blockIdx.z;
  const int tid = threadIdx.x;
  const int lane = tid & 63, w = tid >> 6;
  const int tb = (w < 4) ? w : 11 - w;        // balanced t-block assignment
  const int fr = lane & 15, fq = lane >> 4;
  const int bh = b * 32 + h;
  const size_t m0 = (size_t)b * 4096 + c * 256;

  __shared__ u16 sB[256 * 128];     // [tau][n], 16 oct/row, swz ^(tau&15)
  __shared__ u16 sX[64 * 256];      // [p][tau], 32 oct/row, swz ^(p&15)
  __shared__ u16 sH[64 * 128];      // [p][n],  16 oct/row, swz ^(p&15)
  __shared__ u16 sP[8 * 32 * 64];   // per-wave [32t][64tau], 8 oct/row, swz ^(t&7)
  __shared__ float sL[256], sdt[256], spart[4];

  float dtv = 0.f;
  if (tid < 256) dtv = DTt[(size_t)bh * 4096 + c * 256 + tid];
  float expA = __expf(Alog[h]);
  cumsum256(tid, lane, -expA * dtv, dtv, sL, sdt, spart);

  for (int i = tid; i < 4096; i += 512) {
    int tr = i >> 4, oct = i & 15;
    uint4 v = *(const uint4*)(BCtok + ((m0 + tr) << 8) + oct * 8);
    *(uint4*)((char*)sB + tr * 256 + SWZ(tr, oct, 15)) = v;
  }
  for (int i = tid; i < 2048; i += 512) {
    int p = i >> 5, oct = i & 31;
    uint4 v = *(const uint4*)(XT + ((size_t)(b * 2048 + h * 64 + p) << 12) + c * 256 + oct * 8);
    *(uint4*)((char*)sX + p * 512 + SWZ(p, oct, 15)) = v;
  }
  for (int i = tid; i < 1024; i += 512) {
    int p = i >> 4, oct = i & 15;
    const float* src = HB + (size_t)(bh * NCH + c) * 8192 + p * 128 + oct * 8;
    float4 a = *(const float4*)src;
    float4 bb4 = *(const float4*)(src + 4);
    uint4 o;
    o.x = pk2(a.x, a.y); o.y = pk2(a.z, a.w); o.z = pk2(bb4.x, bb4.y); o.w = pk2(bb4.z, bb4.w);
    *(uint4*)((char*)sH + p * 256 + SWZ(p, oct, 15)) = o;
  }
  // C A-fragments (reused by G and Yoff): rows t = tb*32+m*16+fr, ch 128+k
  short8 cf[2][4];
  #pragma unroll
  for (int m = 0; m < 2; m++)
    #pragma unroll
    for (int ks = 0; ks < 4; ks++)
      cf[m][ks] = *(const short8*)(BCtok + ((m0 + tb * 32 + m * 16 + fr) << 8) + 128 + ks * 32 + fq * 8);
  __syncthreads();

  float Lt[2][4], eLt[2][4];
  #pragma unroll
  for (int m = 0; m < 2; m++)
    #pragma unroll
    for (int q = 0; q < 4; q++) {
      Lt[m][q] = sL[tb * 32 + m * 16 + fq * 4 + q];
      eLt[m][q] = __expf(Lt[m][q]);
    }
  const float Dh = Dp[h];

  f32x4 accY[2][4] = {};
  u16* pw = sP + w * 2048;
  const int ntl = (tb >> 1) + 1;
  for (int tt = 0; tt < ntl; tt++) {
    const int t0 = tt * 64;
    f32x4 g[2][4] = {};
    #pragma unroll
    for (int ks = 0; ks < 4; ks++) {
      short8 bfm[4];
      #pragma unroll
      for (int nb = 0; nb < 4; nb++) {
        int tr = t0 + nb * 16 + fr;
        bfm[nb] = *(const short8*)((char*)sB + tr * 256 + SWZ(tr, ks * 4 + fq, 15));
      }
      #pragma unroll
      for (int m = 0; m < 2; m++)
        #pragma unroll
        for (int nb = 0; nb < 4; nb++)
          g[m][nb] = __builtin_amdgcn_mfma_f32_16x16x32_bf16(cf[m][ks], bfm[nb], g[m][nb], 0, 0, 0);
    }
    // mask * G -> P (bf16, per-wave LDS); D added to diag AFTER multiplying by G
    #pragma unroll
    for (int nb = 0; nb < 4; nb++) {
      int tau = t0 + nb * 16 + fr;
      float Ltau = sL[tau], dtau = sdt[tau];
      #pragma unroll
      for (int m = 0; m < 2; m++) {
        #pragma unroll
        for (int q = 0; q < 4; q++) {
          int t = tb * 32 + m * 16 + fq * 4 + q;
          float mask = (tau > t) ? 0.f : __expf(Lt[m][q] - Ltau) * dtau;
          float pv = mask * g[m][nb][q];
          pv = (tau == t) ? pv + Dh : pv;
          int tl = m * 16 + fq * 4 + q, taul = nb * 16 + fr;
          *(u16*)((char*)pw + tl * 128 + ((((taul) >> 3) ^ (tl & 7)) << 4) + (taul & 7) * 2) = f2bf(pv);
        }
      }
    }
    // P @ X
    #pragma unroll
    for (int ks = 0; ks < 2; ks++) {
      short8 pf[2], xf[4];
      #pragma unroll
      for (int m = 0; m < 2; m++) {
        int tl = m * 16 + fr;
        pf[m] = *(const short8*)((char*)pw + tl * 128 + (((ks * 4 + fq) ^ (tl & 7)) << 4));
      }
      #pragma unroll
      for (int pb = 0; pb < 4; pb++) {
        int p = pb * 16 + fr;
        int oct = (t0 >> 3) + ks * 4 + fq;
        xf[pb] = *(const short8*)((char*)sX + p * 512 + SWZ(p, oct, 15));
      }
      #pragma unroll
      for (int m = 0; m < 2; m++)
        #pragma unroll
        for (int pb = 0; pb < 4; pb++)
          accY[m][pb] = __builtin_amdgcn_mfma_f32_16x16x32_bf16(pf[m], xf[pb], accY[m][pb], 0, 0, 0);
    }
  }
  // Yoff = C @ HinT
  f32x4 accO[2][4] = {};
  #pragma unroll
  for (int ks = 0; ks < 4; ks++) {
    short8 hf[4];
    #pragma unroll
    for (int pb = 0; pb < 4; pb++) {
      int p = pb * 16 + fr;
      hf[pb] = *(const short8*)((char*)sH + p * 256 + SWZ(p, ks * 4 + fq, 15));
    }
    #pragma unroll
    for (int m = 0; m < 2; m++)
      #pragma unroll
      for (int pb = 0; pb < 4; pb++)
        accO[m][pb] = __builtin_amdgcn_mfma_f32_16x16x32_bf16(cf[m][ks], hf[pb], accO[m][pb], 0, 0, 0);
  }
  #pragma unroll
  for (int m = 0; m < 2; m++)
    #pragma unroll
    for (int pb = 0; pb < 4; pb++)
      #pragma unroll
      for (int q = 0; q < 4; q++) {
        int t = tb * 32 + m * 16 + fq * 4 + q;
        float val = accY[m][pb][q] + eLt[m][q] * accO[m][pb][q];
        Y[(m0 + t) * 2048 + h * 64 + pb * 16 + fr] = f2bf(val);
      }
}

// ---------- fallback: sequential scan on new layouts ----------
__launch_bounds__(256)
__global__ void k_scan(const u16* __restrict__ XT, const u16* __restrict__ BCtok,
                       const float* __restrict__ DTt, const float* __restrict__ DECt,
                       const float* __restrict__ Dp, u16* __restrict__ y) {
  const int ps = blockIdx.x, h = blockIdx.y, b = blockIdx.z;
  const int tid = threadIdx.x;
  const int tsub = tid & 15, pl = tid >> 4;
  const int p = ps * 16 + pl;
  const u16* xp = XT + ((size_t)(b * 2048 + h * 64 + p)) * 4096;
  const float* dth = DTt + (size_t)(b * 32 + h) * 4096;
  const float* dch = DECt + (size_t)(b * 32 + h) * 4096;
  u16* yp = y + (size_t)b * 4096 * 2048 + h * 64 + p;
  const float Dh = Dp[h];
  float s0 = 0, s1 = 0, s2 = 0, s3 = 0, s4 = 0, s5 = 0, s6 = 0, s7 = 0;
  for (int tau = 0; tau < 4096; ++tau) {
    const u16* bcr = BCtok + ((size_t)(b * 4096 + tau)) * 256;
    uint4 vB = *(const uint4*)(bcr + tsub * 8);
    uint4 vC = *(const uint4*)(bcr + 128 + tsub * 8);
    float xv = bf2f(xp[tau]);
    float a = dth[tau] * xv;
    float dcv = dch[tau];
    s0 = s0 * dcv + a * bf2f((u16)(vB.x & 0xFFFF)); s1 = s1 * dcv + a * bf2f((u16)(vB.x >> 16));
    s2 = s2 * dcv + a * bf2f((u16)(vB.y & 0xFFFF)); s3 = s3 * dcv + a * bf2f((u16)(vB.y >> 16));
    s4 = s4 * dcv + a * bf2f((u16)(vB.z & 0xFFFF)); s5 = s5 * dcv + a * bf2f((u16)(vB.z >> 16));
    s6 = s6 * dcv + a * bf2f((u16)(vB.w & 0xFFFF)); s7 = s7 * dcv + a * bf2f((u16)(vB.w >> 16));
    float sum = s0 * bf2f((u16)(vC.x & 0xFFFF)) + s1 * bf2f((u16)(vC.x >> 16))
              + s2 * bf2f((u16)(vC.y & 0xFFFF)) + s3 * bf2f((u16)(vC.y >> 16))
              + s4 * bf2f((u16)(vC.z & 0xFFFF)) + s5 * bf2f((u16)(vC.z >> 16))
              + s6 * bf2f((u16)(vC.w & 0xFFFF)) + s7 * bf2f((u16)(vC.w >> 16));
    sum += __shfl_xor(sum, 1, 64);
    sum += __shfl_xor(sum, 2, 64);
    sum += __shfl_xor(sum, 4, 64);
    sum += __shfl_xor(sum, 8, 64);
    if (tsub == 0) yp[(size_t)tau * 2048] = f2bf(sum + Dh * xv);
  }
}

// ---------- gated RMSNorm (vectorized: uint4 loads, thread owns 8 channels) ----------
__global__ void k_gate(const u16* __restrict__ y, const u16* __restrict__ zx,
                       const float* __restrict__ normw, u16* __restrict__ u, int flip) {
  const int m = blockIdx.x, tid = threadIdx.x;
  const int ms = flip ? (m ^ 4095) : m;
  uint4 yv = *(const uint4*)(y + (size_t)m * 2048 + tid * 8);
  uint4 zv = *(const uint4*)(zx + (size_t)ms * 4480 + tid * 8);
  const u16* yp = (const u16*)&yv;
  const u16* zp = (const u16*)&zv;
  float vals[8];
  float ss = 0.f;
  #pragma unroll
  for (int i = 0; i < 8; i++) {
    float zf = bf2f(zp[i]);
    float wv = bf2f(yp[i]) * (zf / (1.f + __expf(-zf)));
    vals[i] = wv;
    ss += wv * wv;
  }
  float rs = rsqrtf(block_sum256(ss) * (1.f / 2048.f) + 1e-5f);
  float4 n0 = *(const float4*)(normw + tid * 8);
  float4 n1 = *(const float4*)(normw + tid * 8 + 4);
  uint4 o;
  o.x = pk2(vals[0] * rs * n0.x, vals[1] * rs * n0.y);
  o.y = pk2(vals[2] * rs * n0.z, vals[3] * rs * n0.w);
  o.z = pk2(vals[4] * rs * n1.x, vals[5] * rs * n1.y);
  o.w = pk2(vals[6] * rs * n1.z, vals[7] * rs * n1.w);
  *(uint4*)(u + (size_t)m * 2048 + tid * 8) = o;
}

// ---------- final LN + residual ----------
__global__ void k_final(const float* __restrict__ t2, const float* __restrict__ bias,
                        const float* __restrict__ g, const float* __restrict__ bb,
                        const float* __restrict__ x, float* __restrict__ out) {
  const int row = blockIdx.x, tid = threadIdx.x;
  float2 v = ((const float2*)(t2 + (size_t)row * 512))[tid];
  float v0 = v.x + bias[tid * 2], v1 = v.y + bias[tid * 2 + 1];
  float mean = block_sum256(v0 + v1) * (1.f / 512.f);
  float d0 = v0 - mean, d1 = v1 - mean;
  float var = block_sum256(d0 * d0 + d1 * d1) * (1.f / 512.f);
  float rs = rsqrtf(var + 1e-5f);
  float2 xr = ((const float2*)(x + (size_t)row * 512))[tid];
  float2 o;
  o.x = d0 * rs * g[tid * 2] + bb[tid * 2] + xr.x;
  o.y = d1 * rs * g[tid * 2 + 1] + bb[tid * 2 + 1] + xr.y;
  ((float2*)(out + (size_t)row * 512))[tid] = o;
}

extern "C" void kernel_launch(void* const* d_in, const int* in_sizes, int n_in,
                              void* d_out, int out_size, void* d_ws, size_t ws_size,
                              hipStream_t stream) {
  const float* x      = (const float*)d_in[0];
  const float* pre_w  = (const float*)d_in[1];
  const float* pre_b  = (const float*)d_in[2];
  const float* pre_g  = (const float*)d_in[3];
  const float* pre_bb = (const float*)d_in[4];
  const float* post_w = (const float*)d_in[5];
  const float* post_b = (const float*)d_in[6];
  const float* post_g = (const float*)d_in[7];
  const float* post_bb= (const float*)d_in[8];
  const float* win_[2]   = {(const float*)d_in[9],  (const float*)d_in[17]};
  const float* convw_[2] = {(const float*)d_in[10], (const float*)d_in[18]};
  const float* convb_[2] = {(const float*)d_in[11], (const float*)d_in[19]};
  const float* dtb_[2]   = {(const float*)d_in[12], (const float*)d_in[20]};
  const float* Alog_[2]  = {(const float*)d_in[13], (const float*)d_in[21]};
  const float* Dp_[2]    = {(const float*)d_in[14], (const float*)d_in[22]};
  const float* normw_[2] = {(const float*)d_in[15], (const float*)d_in[23]};
  const float* wout_[2]  = {(const float*)d_in[16], (const float*)d_in[24]};

  char* ws = (char*)d_ws;
  constexpr size_t OFF_WT_PRE  = 0;                         // 1 MB (PR aliases later)
  constexpr size_t OFF_WT_WINF = OFF_WT_PRE  + 1048576;
  constexpr size_t OFF_WT_WINB = OFF_WT_WINF + 9175040;
  constexpr size_t OFF_WT_WOF  = OFF_WT_WINB + 9175040;
  constexpr size_t OFF_WT_WOB  = OFF_WT_WOF  + 4194304;
  constexpr size_t OFF_WT_POST = OFF_WT_WOB  + 4194304;
  constexpr size_t OFF_HPRE    = OFF_WT_POST + 1048576;     // 16 MB
  constexpr size_t OFF_ZX      = OFF_HPRE + 16777216;       // 70 MB
  constexpr size_t OFF_XT      = OFF_ZX + 73400320;         // 32 MB: XT [2][2048][4096] bf16
  constexpr size_t OFF_BC      = OFF_XT + 33554432;         // 4 MB BCtok + 4 MB BCT
  constexpr size_t OFF_DT      = OFF_BC + 8388608;          // 1 MB DT_T
  constexpr size_t OFF_DEC     = OFF_DT + 1048576;          // 1 MB DEC_T
  constexpr size_t OFF_Y       = OFF_DEC + 1048576;         // 16 MB bf16 y
  constexpr size_t OFF_S       = OFF_Y + 33554432;          // 32 MB (bf16 S uses half)
  constexpr size_t OFF_HB      = OFF_S + 33554432;          // 32 MB
  constexpr size_t ARENA_END   = OFF_HB + 33554432;         // == 263716864

  u16* WtPre    = (u16*)(ws + OFF_WT_PRE);
  u16* WtWin[2] = {(u16*)(ws + OFF_WT_WINF), (u16*)(ws + OFF_WT_WINB)};
  u16* WtWo[2]  = {(u16*)(ws + OFF_WT_WOF),  (u16*)(ws + OFF_WT_WOB)};
  u16* WtPost   = (u16*)(ws + OFF_WT_POST);
  u16* HPRE = (u16*)(ws + OFF_HPRE);
  u16* ZX   = (u16*)(ws + OFF_ZX);
  u16* XT   = (u16*)(ws + OFF_XT);
  u16* BCtok= (u16*)(ws + OFF_BC);
  u16* BCT  = (u16*)(ws + OFF_BC + 4194304);
  float* DTt = (float*)(ws + OFF_DT);
  float* DECt= (float*)(ws + OFF_DEC);
  u16*  Y   = (u16*)(ws + OFF_Y);
  u16*  Sb  = (u16*)(ws + OFF_S);          // bf16 wout_f intermediate
  float* HB = (float*)(ws + OFF_HB);
  // aliases
  float* PRb  = (float*)(ws + OFF_WT_PRE); // 4 KB (WtPre dead after pre-GEMM)
  u16*   XBF  = (u16*)(ws + OFF_Y);        // bf16 x for pre-GEMM
  float* TMP  = (float*)(ws + OFF_S);      // pre-GEMM f32 out (before Sb written)
  u16*   U    = (u16*)(ws + OFF_XT);       // gated y bf16 (XT dead after ssd_c)
  u16*   U2   = ZX;                        // final gated sum (ZX dead)
  float* TMP2 = (float*)(ws + OFF_XT);     // post-GEMM f32 out (U dead)

  const bool chunked = (ws_size >= ARENA_END);

  dim3 tb(32, 8);
  k_tcast<<<dim3(32, 16),  tb, 0, stream>>>(pre_w,   WtPre,    512, 1024, 1024);
  k_tcast<<<dim3(140, 32), tb, 0, stream>>>(win_[0], WtWin[0], 1024, 4384, 4480);
  k_tcast<<<dim3(140, 32), tb, 0, stream>>>(win_[1], WtWin[1], 1024, 4384, 4480);
  k_tcast<<<dim3(32, 64),  tb, 0, stream>>>(wout_[0], WtWo[0], 2048, 1024, 1024);
  k_tcast<<<dim3(32, 64),  tb, 0, stream>>>(wout_[1], WtWo[1], 2048, 1024, 1024);
  k_tcast<<<dim3(16, 32),  tb, 0, stream>>>(post_w,  WtPost,   1024,  512,  512);
  k_cast<<<4096, 256, 0, stream>>>(x, XBF, 1048576);
  k_gemm<<<dim3(64, 8), 256, 0, stream>>>(XBF, WtPre, TMP, nullptr, nullptr, nullptr,
                                          8192, 1024, 512, 1024, 0);
  k_preln<<<8192, 256, 0, stream>>>(TMP, pre_b, pre_g, pre_bb, HPRE);

  for (int d = 0; d < 2; d++) {
    int flip = d;
    k_gemm256<<<dim3(32, 18), 512, 0, stream>>>(HPRE, WtWin[d], ZX);
    k_dt2<<<dim3(16, 32, 2), 256, 0, stream>>>(ZX, dtb_[d], Alog_[d], DTt, DECt, flip);
    k_conv2<<<dim3(36, 64, 2), 256, 0, stream>>>(ZX, convw_[d], convb_[d], XT, BCtok, BCT, flip);
    if (chunked) {
      k_ssd_a<<<dim3(NCH, 32, 2), 512, 0, stream>>>(XT, BCT, DTt, Alog_[d], HB, PRb);
      k_scan_b<<<dim3(32, 32, 2), 256, 0, stream>>>(HB, PRb);
      k_ssd_c<<<dim3(NCH, 32, 2), 512, 0, stream>>>(BCtok, XT, DTt, HB, Alog_[d], Dp_[d], Y);
    } else {
      k_scan<<<dim3(4, 32, 2), 256, 0, stream>>>(XT, BCtok, DTt, DECt, Dp_[d], Y);
    }
    k_gate<<<8192, 256, 0, stream>>>(Y, ZX, normw_[d], U, flip);
    // d=0: bf16 out to Sb. d=1: accumulate bf16 Sb + fused u2 (silu(HPRE)) -> bf16 U2.
    if (d == 0) {
      k_gemm<<<dim3(64, 8), 256, 0, stream>>>(U, WtWo[d], nullptr, Sb, nullptr, nullptr,
                                              8192, 1024, 2048, 1024, 1);
    } else {
      k_gemm<<<dim3(64, 8), 256, 0, stream>>>(U, WtWo[d], nullptr, U2, HPRE, Sb,
                                              8192, 1024, 2048, 1024, 1 | 4 | 8 | 16);
    }
  }

  k_gemm<<<dim3(64, 4), 256, 0, stream>>>(U2, WtPost, TMP2, nullptr, nullptr, nullptr,
                                          8192, 512, 1024, 512, 0);
  k_final<<<8192, 256, 0, stream>>>(TMP2, post_b, post_g, post_bb, x, (float*)d_out);
}

// Round 18
// 685.683 us; speedup vs baseline: 1.1381x; 1.0297x over previous
//
#include <hip/hip_runtime.h>
#include <stdint.h>

typedef unsigned short u16;
typedef __attribute__((ext_vector_type(8))) short short8;
typedef __attribute__((ext_vector_type(4))) float f32x4;

__device__ __forceinline__ float bf2f(u16 u) {
  union { float f; uint32_t i; } v; v.i = ((uint32_t)u) << 16; return v.f;
}
__device__ __forceinline__ u16 f2bf(float f) {
  union { float f; uint32_t i; } v; v.f = f;
  uint32_t r = v.i + 0x7FFFu + ((v.i >> 16) & 1u);
  return (u16)(r >> 16);
}
__device__ __forceinline__ uint32_t pk2(float a, float b) {
  return (uint32_t)f2bf(a) | ((uint32_t)f2bf(b) << 16);
}
// async global->LDS, 16B per lane; LDS dest is wave-uniform base + lane*16
__device__ __forceinline__ void gload16(const u16* g, u16* l) {
  __builtin_amdgcn_global_load_lds(
      (const __attribute__((address_space(1))) unsigned int*)g,
      (__attribute__((address_space(3))) unsigned int*)l, 16, 0, 0);
}

__device__ __forceinline__ float block_sum256(float v) {
  __shared__ float red[4];
  #pragma unroll
  for (int o = 1; o < 64; o <<= 1) v += __shfl_xor(v, o, 64);
  int lane = threadIdx.x & 63, w = threadIdx.x >> 6;
  __syncthreads();
  if (lane == 0) red[w] = v;
  __syncthreads();
  return red[0] + red[1] + red[2] + red[3];
}

// ---------- W[K][N] f32 -> Wt[Npad][K] bf16 (zero-pad rows >= N) ----------
__global__ void k_tcast(const float* __restrict__ W, u16* __restrict__ Wt,
                        int K, int N, int Npad) {
  __shared__ float tile[32][33];
  int n0 = blockIdx.x * 32, k0 = blockIdx.y * 32;
  int tx = threadIdx.x, ty0 = threadIdx.y;
  #pragma unroll
  for (int i = 0; i < 4; i++) {
    int ty = ty0 + i * 8;
    int k = k0 + ty, n = n0 + tx;
    tile[ty][tx] = (k < K && n < N) ? W[(size_t)k * N + n] : 0.f;
  }
  __syncthreads();
  #pragma unroll
  for (int i = 0; i < 4; i++) {
    int ty = ty0 + i * 8;
    int n = n0 + ty, k = k0 + tx;
    if (n < Npad && k < K) Wt[(size_t)n * K + k] = f2bf(tile[tx][ty]);
  }
}

// ---------- f32 -> bf16 elementwise (x4) ----------
__global__ void k_cast(const float* __restrict__ in, u16* __restrict__ out, int n4) {
  int i = blockIdx.x * 256 + threadIdx.x;
  if (i >= n4) return;
  float4 v = ((const float4*)in)[i];
  uint2 o;
  o.x = pk2(v.x, v.y);
  o.y = pk2(v.z, v.w);
  ((uint2*)out)[i] = o;
}

// ---------- 128x128 bf16 MFMA GEMM (dbuf global_load_lds), general ----------
// flags: 1=bf16 out, 2=accum f32 Cf, 4=flip row, 8=fuse u2 (v *= silu(hp)),
//        16=accum bf16 ab
__launch_bounds__(256)
__global__ void k_gemm(const u16* __restrict__ A, const u16* __restrict__ Bt,
                       float* __restrict__ Cf, u16* __restrict__ Cb,
                       const u16* __restrict__ hp, const u16* __restrict__ ab,
                       int M, int N, int K, int ldc, int flags) {
  __shared__ u16 lA[2][128 * 64];
  __shared__ u16 lB[2][128 * 64];
  const int tid = threadIdx.x;
  const int lane = tid & 63;
  const int wave = tid >> 6;
  const int bm = blockIdx.x, bn = blockIdx.y;
  const int wr = wave >> 1, wc = wave & 1;
  const int fr = lane & 15, fq = lane >> 4;

  const int srow = wave * 32 + (lane >> 3);
  const int scol = ((lane & 7) ^ (srow & 7)) * 8;   // inverse-swizzled source col
  const u16* gA = A + (size_t)(bm * 128 + srow) * K + scol;
  const u16* gB = Bt + (size_t)(bn * 128 + srow) * K + scol;
  const int lofs = wave * 2048;

  f32x4 acc[4][4] = {};

  #pragma unroll
  for (int i = 0; i < 4; i++) {
    gload16(gA + (size_t)(i * 8) * K, &lA[0][lofs + i * 512]);
    gload16(gB + (size_t)(i * 8) * K, &lB[0][lofs + i * 512]);
  }
  __syncthreads();

  const int NT = K >> 6;
  for (int t = 0; t < NT; ++t) {
    const int cur = t & 1;
    if (t + 1 < NT) {
      const int kt = (t + 1) << 6;
      #pragma unroll
      for (int i = 0; i < 4; i++) {
        gload16(gA + (size_t)(i * 8) * K + kt, &lA[cur ^ 1][lofs + i * 512]);
        gload16(gB + (size_t)(i * 8) * K + kt, &lB[cur ^ 1][lofs + i * 512]);
      }
    }
    #pragma unroll
    for (int kk = 0; kk < 2; kk++) {
      short8 af[4], bfr[4];
      #pragma unroll
      for (int m = 0; m < 4; m++) {
        int row = wr * 64 + m * 16 + fr;
        int sl = (kk * 4 + fq) ^ (row & 7);
        af[m] = *(const short8*)(&lA[cur][row * 64 + sl * 8]);
      }
      #pragma unroll
      for (int n = 0; n < 4; n++) {
        int row = wc * 64 + n * 16 + fr;
        int sl = (kk * 4 + fq) ^ (row & 7);
        bfr[n] = *(const short8*)(&lB[cur][row * 64 + sl * 8]);
      }
      #pragma unroll
      for (int m = 0; m < 4; m++)
        #pragma unroll
        for (int n = 0; n < 4; n++)
          acc[m][n] = __builtin_amdgcn_mfma_f32_16x16x32_bf16(af[m], bfr[n], acc[m][n], 0, 0, 0);
    }
    __syncthreads();   // drains next-tile loads (latency hidden under compute above)
  }

  const bool bf16out = flags & 1, accum = flags & 2, flip = flags & 4, fuse = flags & 8;
  const bool accb = flags & 16;
  #pragma unroll
  for (int m = 0; m < 4; m++) {
    #pragma unroll
    for (int q = 0; q < 4; q++) {
      int rr = bm * 128 + wr * 64 + m * 16 + fq * 4 + q;
      int orow = flip ? (rr ^ 4095) : rr;
      size_t rb = (size_t)orow * ldc;
      #pragma unroll
      for (int n = 0; n < 4; n++) {
        int cc = bn * 128 + wc * 64 + n * 16 + fr;
        float v = acc[m][n][q];
        if (accum) v += Cf[rb + cc];
        if (accb) v += bf2f(ab[rb + cc]);
        if (fuse) {
          float h = bf2f(hp[rb + cc]);
          v = v * (h / (1.f + __expf(-h)));
        }
        if (bf16out) Cb[rb + cc] = f2bf(v);
        else Cf[rb + cc] = v;
      }
    }
  }
}

// ---------- 256x256 bf16 MFMA GEMM for the win projection (r11 proven) ----------
// 8 waves (2Mx4N), per-wave 128x64, BK=64, 128 KiB LDS dbuf, 2-barrier
// structure, counted vmcnt(8) at tile boundaries (never drain mid-loop).
// Fixed shape: M=8192, K=1024, N=4480 (18 N-tiles; ragged: B-row clamp + C guard).
__launch_bounds__(512)
__global__ void k_gemm256(const u16* __restrict__ A, const u16* __restrict__ Bt,
                          u16* __restrict__ Cb) {
  constexpr int K = 1024, N = 4480, NT = 16;
  __shared__ u16 lA[2][256 * 64];
  __shared__ u16 lB[2][256 * 64];
  const int tid = threadIdx.x;
  const int lane = tid & 63;
  const int wid = tid >> 6;
  const int bm = blockIdx.x, bn = blockIdx.y;
  const int wr = wid >> 2, wc = wid & 3;       // 2 x 4 waves
  const int fr = lane & 15, fq = lane >> 4;

  const int srow = tid >> 3;                    // 0..63
  const int scol = ((tid & 7) ^ (srow & 7)) * 8;
  const u16* gA[4];
  const u16* gB[4];
  #pragma unroll
  for (int i = 0; i < 4; i++) {
    int arow = bm * 256 + i * 64 + srow;
    gA[i] = A + (size_t)arow * K + scol;
    int brow = bn * 256 + i * 64 + srow;
    if (brow > N - 1) brow = N - 1;             // ragged-N clamp (cols guarded at C)
    gB[i] = Bt + (size_t)brow * K + scol;
  }

  f32x4 acc[8][4] = {};

  auto stage = [&](int u) {
    const int buf = u & 1, kt = u << 6;
    #pragma unroll
    for (int i = 0; i < 4; i++)
      gload16(gA[i] + kt, &lA[buf][i * 4096 + tid * 8]);
    #pragma unroll
    for (int i = 0; i < 4; i++)
      gload16(gB[i] + kt, &lB[buf][i * 4096 + tid * 8]);
  };

  // prologue: tiles 0,1 in flight; wait tile 0 only (8 newest stay pending)
  stage(0);
  stage(1);
  asm volatile("s_waitcnt vmcnt(8)" ::: "memory");
  __builtin_amdgcn_s_barrier();

  for (int t = 0; t < NT; ++t) {
    const u16* bufA = &lA[t & 1][0];
    const u16* bufB = &lB[t & 1][0];
    #pragma unroll
    for (int kk = 0; kk < 2; kk++) {
      short8 af[8], bfm[4];
      #pragma unroll
      for (int m = 0; m < 8; m++) {
        int row = wr * 128 + m * 16 + fr;
        int sl = (kk * 4 + fq) ^ (row & 7);
        af[m] = *(const short8*)(&bufA[row * 64 + sl * 8]);
      }
      #pragma unroll
      for (int n = 0; n < 4; n++) {
        int row = wc * 64 + n * 16 + fr;
        int sl = (kk * 4 + fq) ^ (row & 7);
        bfm[n] = *(const short8*)(&bufB[row * 64 + sl * 8]);
      }
      #pragma unroll
      for (int m = 0; m < 8; m++)
        #pragma unroll
        for (int n = 0; n < 4; n++)
          acc[m][n] = __builtin_amdgcn_mfma_f32_16x16x32_bf16(af[m], bfm[n], acc[m][n], 0, 0, 0);
    }
    // boundary: buf[t&1] dead -> stage t+2 there; counted wait: t+1 landed,
    // t+2's 8 loads stay in flight (never drain to 0 mid-loop)
    __builtin_amdgcn_s_barrier();
    if (t + 2 < NT) {
      stage(t + 2);
      asm volatile("s_waitcnt vmcnt(8)" ::: "memory");
    } else {
      asm volatile("s_waitcnt vmcnt(0)" ::: "memory");
    }
    __builtin_amdgcn_s_barrier();
  }

  #pragma unroll
  for (int m = 0; m < 8; m++) {
    #pragma unroll
    for (int q = 0; q < 4; q++) {
      size_t rb = (size_t)(bm * 256 + wr * 128 + m * 16 + fq * 4 + q) * N;
      #pragma unroll
      for (int n = 0; n < 4; n++) {
        int cc = bn * 256 + wc * 64 + n * 16 + fr;
        if (cc < N) Cb[rb + cc] = f2bf(acc[m][n][q]);
      }
    }
  }
}

// ---------- pre-LN ----------
__global__ void k_preln(const float* __restrict__ t, const float* __restrict__ bias,
                        const float* __restrict__ g, const float* __restrict__ bb,
                        u16* __restrict__ out) {
  const int row = blockIdx.x, tid = threadIdx.x;
  float4 v = ((const float4*)(t + (size_t)row * 1024))[tid];
  float4 bi = ((const float4*)bias)[tid];
  float v0 = v.x + bi.x, v1 = v.y + bi.y, v2 = v.z + bi.z, v3 = v.w + bi.w;
  float mean = block_sum256(v0 + v1 + v2 + v3) * (1.f / 1024.f);
  float d0 = v0 - mean, d1 = v1 - mean, d2 = v2 - mean, d3 = v3 - mean;
  float var = block_sum256(d0 * d0 + d1 * d1 + d2 * d2 + d3 * d3) * (1.f / 1024.f);
  float rs = rsqrtf(var + 1e-5f);
  float4 gg = ((const float4*)g)[tid];
  float4 bv = ((const float4*)bb)[tid];
  uint2 o;
  o.x = pk2(d0 * rs * gg.x + bv.x, d1 * rs * gg.y + bv.y);
  o.y = pk2(d2 * rs * gg.z + bv.z, d3 * rs * gg.w + bv.w);
  ((uint2*)(out + (size_t)row * 1024))[tid] = o;
}

// ---------- dt/dec in [b][h][t] (flipped-domain) layout ----------
__global__ void k_dt2(const u16* __restrict__ zx, const float* __restrict__ dtb,
                      const float* __restrict__ Alog, float* __restrict__ DTt,
                      float* __restrict__ DECt, int flip) {
  int t = blockIdx.x * 256 + threadIdx.x;
  int h = blockIdx.y, b = blockIdx.z;
  int ts = flip ? 4095 - t : t;
  float raw = bf2f(zx[(size_t)((b << 12) + ts) * 4480 + 4352 + h]) + dtb[h];
  float d = (raw > 20.f) ? raw : log1pf(__expf(raw));
  size_t o = (size_t)(b * 32 + h) * 4096 + t;
  DTt[o] = d;
  DECt[o] = __expf(-__expf(Alog[h]) * d);
}

// ---------- conv(K=4)+silu; vectorized I/O; outputs XT [b][2048][4096],
// ---------- BCtok [m][256] bf16, BCT [b][256][4096] (flipped-domain) ----------
__global__ void k_conv2(const u16* __restrict__ zx, const float* __restrict__ cw,
                        const float* __restrict__ cb, u16* __restrict__ XT,
                        u16* __restrict__ BCtok, u16* __restrict__ BCT, int flip) {
  const int ct = blockIdx.x;           // 0..35 channel tile (64)
  const int tt = blockIdx.y;           // 0..63 token tile (64)
  const int b = blockIdx.z;
  const int tid = threadIdx.x;         // 256
  __shared__ float sin_[67][64];
  __shared__ float sout[64][65];
  const int ch0 = ct * 64, t0 = tt * 64;

  // staging: uint2 = 4 ch/thread; 67 rows x 16 quads
  for (int i = tid; i < 67 * 16; i += 256) {
    int r = i >> 4, c4 = (i & 15) << 2;
    int tok = t0 - 3 + r;
    float f0 = 0.f, f1 = 0.f, f2 = 0.f, f3 = 0.f;
    if (tok >= 0) {
      int src = (b << 12) + (flip ? 4095 - tok : tok);
      uint2 v = *(const uint2*)(zx + (size_t)src * 4480 + 2048 + ch0 + c4);
      f0 = bf2f((u16)(v.x & 0xFFFF)); f1 = bf2f((u16)(v.x >> 16));
      f2 = bf2f((u16)(v.y & 0xFFFF)); f3 = bf2f((u16)(v.y >> 16));
    }
    sin_[r][c4] = f0; sin_[r][c4 + 1] = f1; sin_[r][c4 + 2] = f2; sin_[r][c4 + 3] = f3;
  }
  __syncthreads();

  const int ch = tid & 63, g = tid >> 6;
  const int chg = ch0 + ch;
  float4 wv = *(const float4*)(cw + (size_t)chg * 4);
  float bias = cb[chg];
  #pragma unroll
  for (int i = 0; i < 16; i++) {
    int tl = g * 16 + i;
    float a = bias + wv.x * sin_[tl][ch] + wv.y * sin_[tl + 1][ch]
                   + wv.z * sin_[tl + 2][ch] + wv.w * sin_[tl + 3][ch];
    sout[tl][ch] = a / (1.f + __expf(-a));
  }
  __syncthreads();

  if (ch0 < 2048) {
    for (int i = tid; i < 64 * 16; i += 256) {
      int chw = i >> 4, t4 = (i & 15) << 2;
      uint2 o;
      o.x = pk2(sout[t4][chw], sout[t4 + 1][chw]);
      o.y = pk2(sout[t4 + 2][chw], sout[t4 + 3][chw]);
      *(uint2*)(XT + ((size_t)(b * 2048 + ch0 + chw)) * 4096 + t0 + t4) = o;
    }
  } else {
    int c2b = (ct - 32) * 64;
    for (int i = tid; i < 64 * 16; i += 256) {
      int chw = i >> 4, t4 = (i & 15) << 2;
      uint2 o;
      o.x = pk2(sout[t4][chw], sout[t4 + 1][chw]);
      o.y = pk2(sout[t4 + 2][chw], sout[t4 + 3][chw]);
      *(uint2*)(BCT + ((size_t)(b * 256 + c2b + chw)) * 4096 + t0 + t4) = o;
    }
    for (int i = tid; i < 64 * 8; i += 256) {
      int r = i >> 3, c8 = (i & 7) << 3;
      uint4 o;
      o.x = pk2(sout[r][c8], sout[r][c8 + 1]);
      o.y = pk2(sout[r][c8 + 2], sout[r][c8 + 3]);
      o.z = pk2(sout[r][c8 + 4], sout[r][c8 + 5]);
      o.w = pk2(sout[r][c8 + 6], sout[r][c8 + 7]);
      *(uint4*)(BCtok + ((size_t)(b * 4096 + t0 + r)) * 256 + c2b + c8) = o;
    }
  }
}

// ================= SSD chunked scan, Q=256, NCH=16 =================
#define NCH 16
#define SWZ(row, oct, msk) (((oct) ^ ((row) & (msk))) << 4)

// inclusive cumsum helper over 256 threads (first 4 waves), returns L for tid<256
__device__ __forceinline__ void cumsum256(int tid, int lane, float adt, float dtv,
                                          float* sL, float* sdt, float* spart) {
  float v = adt;
  if (tid < 256) {
    #pragma unroll
    for (int o = 1; o < 64; o <<= 1) {
      float t = __shfl_up(v, o, 64);
      if (lane >= o) v += t;
    }
    if (lane == 63) spart[tid >> 6] = v;
  }
  __syncthreads();
  if (tid < 256) {
    int w = tid >> 6;
    float off = 0.f;
    #pragma unroll
    for (int j = 0; j < 3; j++) if (j < w) off += spart[j];
    sL[tid] = v + off;
    sdt[tid] = dtv;
  }
}

// pass A: H_localT[p][n] = sum_tau w_tau * X[tau][p] * B[tau][n]; HB bf16
__launch_bounds__(512, 1)
__global__ void k_ssd_a(const u16* __restrict__ XT, const u16* __restrict__ BCT,
                        const float* __restrict__ DTt, const float* __restrict__ Alog,
                        u16* __restrict__ HB, float* __restrict__ PR) {
  const int c = blockIdx.x, h = blockIdx.y, b = blockIdx.z;
  const int tid = threadIdx.x;
  const int lane = tid & 63, w = tid >> 6;
  const int fr = lane & 15, fq = lane >> 4;
  const int bh = b * 32 + h;

  __shared__ u16 sX[64 * 256];      // [p][tau], 32 oct/row, swz ^(p&15)
  __shared__ u16 sBW[128 * 256];    // [n][tau], 32 oct/row, swz ^(n&15)
  __shared__ float sL[256], sdt[256], sw_[256], spart[4];

  float dtv = 0.f;
  if (tid < 256) dtv = DTt[(size_t)bh * 4096 + c * 256 + tid];
  float expA = __expf(Alog[h]);
  cumsum256(tid, lane, -expA * dtv, dtv, sL, sdt, spart);
  __syncthreads();
  if (tid < 256) sw_[tid] = __expf(sL[255] - sL[tid]) * sdt[tid];
  for (int i = tid; i < 2048; i += 512) {
    int p = i >> 5, oct = i & 31;
    uint4 v = *(const uint4*)(XT + ((size_t)(b * 2048 + h * 64 + p) << 12) + c * 256 + oct * 8);
    *(uint4*)((char*)sX + p * 512 + SWZ(p, oct, 15)) = v;
  }
  __syncthreads();
  for (int i = tid; i < 4096; i += 512) {
    int n = i >> 5, oct = i & 31;
    uint4 v = *(const uint4*)(BCT + ((size_t)(b * 256 + n) << 12) + c * 256 + oct * 8);
    const float* swp = sw_ + oct * 8;
    float f0 = bf2f((u16)(v.x & 0xFFFF)) * swp[0];
    float f1 = bf2f((u16)(v.x >> 16)) * swp[1];
    float f2 = bf2f((u16)(v.y & 0xFFFF)) * swp[2];
    float f3 = bf2f((u16)(v.y >> 16)) * swp[3];
    float f4 = bf2f((u16)(v.z & 0xFFFF)) * swp[4];
    float f5 = bf2f((u16)(v.z >> 16)) * swp[5];
    float f6 = bf2f((u16)(v.w & 0xFFFF)) * swp[6];
    float f7 = bf2f((u16)(v.w >> 16)) * swp[7];
    uint4 o;
    o.x = pk2(f0, f1); o.y = pk2(f2, f3); o.z = pk2(f4, f5); o.w = pk2(f6, f7);
    *(uint4*)((char*)sBW + n * 512 + SWZ(n, oct, 15)) = o;
  }
  __syncthreads();

  const int pb = w >> 1, nh = w & 1;
  f32x4 acc[4] = {};
  #pragma unroll
  for (int ks = 0; ks < 8; ks++) {
    int p = pb * 16 + fr;
    short8 af = *(const short8*)((char*)sX + p * 512 + SWZ(p, ks * 4 + fq, 15));
    #pragma unroll
    for (int nb = 0; nb < 4; nb++) {
      int n = nh * 64 + nb * 16 + fr;
      short8 bfm = *(const short8*)((char*)sBW + n * 512 + SWZ(n, ks * 4 + fq, 15));
      acc[nb] = __builtin_amdgcn_mfma_f32_16x16x32_bf16(af, bfm, acc[nb], 0, 0, 0);
    }
  }
  u16* hb = HB + (size_t)(bh * NCH + c) * 8192;
  #pragma unroll
  for (int nb = 0; nb < 4; nb++)
    #pragma unroll
    for (int q = 0; q < 4; q++) {
      int p = pb * 16 + fq * 4 + q;
      int n = nh * 64 + nb * 16 + fr;
      hb[p * 128 + n] = f2bf(acc[nb][q]);
    }
  if (tid == 0) PR[bh * NCH + c] = __expf(sL[255]);
}

// pass B: sequential combine over chunk boundaries (bf16 storage, f32 carry)
__global__ void k_scan_b(u16* __restrict__ HB, const float* __restrict__ PR) {
  const int eb = blockIdx.x, h = blockIdx.y, b = blockIdx.z;
  const int e = eb * 256 + threadIdx.x;
  const int bh = b * 32 + h;
  u16* base = HB + (size_t)bh * NCH * 8192 + e;
  const float* pr = PR + bh * NCH;
  float carry = 0.f;
  #pragma unroll 4
  for (int c = 0; c < NCH; ++c) {
    float v = bf2f(base[(size_t)c * 8192]);
    base[(size_t)c * 8192] = f2bf(carry);
    carry = pr[c] * carry + v;
  }
}

// pass C: y = (M.(C B^T)) X + exp(L_t) (C Hin) ; D-term added to P diag AFTER *G
// SIMD-balanced wave->t-block map: tb = w<4 ? w : 11-w pairs causal costs
// (1+4),(1+4),(2+3),(2+3) on the 4 SIMDs (waves s,s+4 co-resident) -> 5 each.
__launch_bounds__(512, 1)
__global__ void k_ssd_c(const u16* __restrict__ BCtok, const u16* __restrict__ XT,
                        const float* __restrict__ DTt, const u16* __restrict__ HB,
                        const float* __restrict__ Alog, const float* __restrict__ Dp,
                        u16* __restrict__ Y) {
  const int c = blockIdx.x, h = blockIdx.y, b = blockIdx.z;
  const int tid = threadIdx.x;
  const int lane = tid & 63, w = tid >> 6;
  const int tb = (w < 4) ? w : 11 - w;        // balanced t-block assignment
  const int fr = lane & 15, fq = lane >> 4;
  const int bh = b * 32 + h;
  const size_t m0 = (size_t)b * 4096 + c * 256;

  __shared__ u16 sB[256 * 128];     // [tau][n], 16 oct/row, swz ^(tau&15)
  __shared__ u16 sX[64 * 256];      // [p][tau], 32 oct/row, swz ^(p&15)
  __shared__ u16 sH[64 * 128];      // [p][n],  16 oct/row, swz ^(p&15)
  __shared__ u16 sP[8 * 32 * 64];   // per-wave [32t][64tau], 8 oct/row, swz ^(t&7)
  __shared__ float sL[256], sdt[256], spart[4];

  float dtv = 0.f;
  if (tid < 256) dtv = DTt[(size_t)bh * 4096 + c * 256 + tid];
  float expA = __expf(Alog[h]);
  cumsum256(tid, lane, -expA * dtv, dtv, sL, sdt, spart);

  for (int i = tid; i < 4096; i += 512) {
    int tr = i >> 4, oct = i & 15;
    uint4 v = *(const uint4*)(BCtok + ((m0 + tr) << 8) + oct * 8);
    *(uint4*)((char*)sB + tr * 256 + SWZ(tr, oct, 15)) = v;
  }
  for (int i = tid; i < 2048; i += 512) {
    int p = i >> 5, oct = i & 31;
    uint4 v = *(const uint4*)(XT + ((size_t)(b * 2048 + h * 64 + p) << 12) + c * 256 + oct * 8);
    *(uint4*)((char*)sX + p * 512 + SWZ(p, oct, 15)) = v;
  }
  for (int i = tid; i < 1024; i += 512) {
    int p = i >> 4, oct = i & 15;
    uint4 v = *(const uint4*)(HB + (size_t)(bh * NCH + c) * 8192 + p * 128 + oct * 8);
    *(uint4*)((char*)sH + p * 256 + SWZ(p, oct, 15)) = v;
  }
  // C A-fragments (reused by G and Yoff): rows t = tb*32+m*16+fr, ch 128+k
  short8 cf[2][4];
  #pragma unroll
  for (int m = 0; m < 2; m++)
    #pragma unroll
    for (int ks = 0; ks < 4; ks++)
      cf[m][ks] = *(const short8*)(BCtok + ((m0 + tb * 32 + m * 16 + fr) << 8) + 128 + ks * 32 + fq * 8);
  __syncthreads();

  float Lt[2][4], eLt[2][4];
  #pragma unroll
  for (int m = 0; m < 2; m++)
    #pragma unroll
    for (int q = 0; q < 4; q++) {
      Lt[m][q] = sL[tb * 32 + m * 16 + fq * 4 + q];
      eLt[m][q] = __expf(Lt[m][q]);
    }
  const float Dh = Dp[h];

  f32x4 accY[2][4] = {};
  u16* pw = sP + w * 2048;
  const int ntl = (tb >> 1) + 1;
  for (int tt = 0; tt < ntl; tt++) {
    const int t0 = tt * 64;
    f32x4 g[2][4] = {};
    #pragma unroll
    for (int ks = 0; ks < 4; ks++) {
      short8 bfm[4];
      #pragma unroll
      for (int nb = 0; nb < 4; nb++) {
        int tr = t0 + nb * 16 + fr;
        bfm[nb] = *(const short8*)((char*)sB + tr * 256 + SWZ(tr, ks * 4 + fq, 15));
      }
      #pragma unroll
      for (int m = 0; m < 2; m++)
        #pragma unroll
        for (int nb = 0; nb < 4; nb++)
          g[m][nb] = __builtin_amdgcn_mfma_f32_16x16x32_bf16(cf[m][ks], bfm[nb], g[m][nb], 0, 0, 0);
    }
    // mask * G -> P (bf16, per-wave LDS); D added to diag AFTER multiplying by G
    #pragma unroll
    for (int nb = 0; nb < 4; nb++) {
      int tau = t0 + nb * 16 + fr;
      float Ltau = sL[tau], dtau = sdt[tau];
      #pragma unroll
      for (int m = 0; m < 2; m++) {
        #pragma unroll
        for (int q = 0; q < 4; q++) {
          int t = tb * 32 + m * 16 + fq * 4 + q;
          float mask = (tau > t) ? 0.f : __expf(Lt[m][q] - Ltau) * dtau;
          float pv = mask * g[m][nb][q];
          pv = (tau == t) ? pv + Dh : pv;
          int tl = m * 16 + fq * 4 + q, taul = nb * 16 + fr;
          *(u16*)((char*)pw + tl * 128 + ((((taul) >> 3) ^ (tl & 7)) << 4) + (taul & 7) * 2) = f2bf(pv);
        }
      }
    }
    // P @ X
    #pragma unroll
    for (int ks = 0; ks < 2; ks++) {
      short8 pf[2], xf[4];
      #pragma unroll
      for (int m = 0; m < 2; m++) {
        int tl = m * 16 + fr;
        pf[m] = *(const short8*)((char*)pw + tl * 128 + (((ks * 4 + fq) ^ (tl & 7)) << 4));
      }
      #pragma unroll
      for (int pb = 0; pb < 4; pb++) {
        int p = pb * 16 + fr;
        int oct = (t0 >> 3) + ks * 4 + fq;
        xf[pb] = *(const short8*)((char*)sX + p * 512 + SWZ(p, oct, 15));
      }
      #pragma unroll
      for (int m = 0; m < 2; m++)
        #pragma unroll
        for (int pb = 0; pb < 4; pb++)
          accY[m][pb] = __builtin_amdgcn_mfma_f32_16x16x32_bf16(pf[m], xf[pb], accY[m][pb], 0, 0, 0);
    }
  }
  // Yoff = C @ HinT
  f32x4 accO[2][4] = {};
  #pragma unroll
  for (int ks = 0; ks < 4; ks++) {
    short8 hf[4];
    #pragma unroll
    for (int pb = 0; pb < 4; pb++) {
      int p = pb * 16 + fr;
      hf[pb] = *(const short8*)((char*)sH + p * 256 + SWZ(p, ks * 4 + fq, 15));
    }
    #pragma unroll
    for (int m = 0; m < 2; m++)
      #pragma unroll
      for (int pb = 0; pb < 4; pb++)
        accO[m][pb] = __builtin_amdgcn_mfma_f32_16x16x32_bf16(cf[m][ks], hf[pb], accO[m][pb], 0, 0, 0);
  }
  #pragma unroll
  for (int m = 0; m < 2; m++)
    #pragma unroll
    for (int pb = 0; pb < 4; pb++)
      #pragma unroll
      for (int q = 0; q < 4; q++) {
        int t = tb * 32 + m * 16 + fq * 4 + q;
        float val = accY[m][pb][q] + eLt[m][q] * accO[m][pb][q];
        Y[(m0 + t) * 2048 + h * 64 + pb * 16 + fr] = f2bf(val);
      }
}

// ---------- fallback: sequential scan on new layouts ----------
__launch_bounds__(256)
__global__ void k_scan(const u16* __restrict__ XT, const u16* __restrict__ BCtok,
                       const float* __restrict__ DTt, const float* __restrict__ DECt,
                       const float* __restrict__ Dp, u16* __restrict__ y) {
  const int ps = blockIdx.x, h = blockIdx.y, b = blockIdx.z;
  const int tid = threadIdx.x;
  const int tsub = tid & 15, pl = tid >> 4;
  const int p = ps * 16 + pl;
  const u16* xp = XT + ((size_t)(b * 2048 + h * 64 + p)) * 4096;
  const float* dth = DTt + (size_t)(b * 32 + h) * 4096;
  const float* dch = DECt + (size_t)(b * 32 + h) * 4096;
  u16* yp = y + (size_t)b * 4096 * 2048 + h * 64 + p;
  const float Dh = Dp[h];
  float s0 = 0, s1 = 0, s2 = 0, s3 = 0, s4 = 0, s5 = 0, s6 = 0, s7 = 0;
  for (int tau = 0; tau < 4096; ++tau) {
    const u16* bcr = BCtok + ((size_t)(b * 4096 + tau)) * 256;
    uint4 vB = *(const uint4*)(bcr + tsub * 8);
    uint4 vC = *(const uint4*)(bcr + 128 + tsub * 8);
    float xv = bf2f(xp[tau]);
    float a = dth[tau] * xv;
    float dcv = dch[tau];
    s0 = s0 * dcv + a * bf2f((u16)(vB.x & 0xFFFF)); s1 = s1 * dcv + a * bf2f((u16)(vB.x >> 16));
    s2 = s2 * dcv + a * bf2f((u16)(vB.y & 0xFFFF)); s3 = s3 * dcv + a * bf2f((u16)(vB.y >> 16));
    s4 = s4 * dcv + a * bf2f((u16)(vB.z & 0xFFFF)); s5 = s5 * dcv + a * bf2f((u16)(vB.z >> 16));
    s6 = s6 * dcv + a * bf2f((u16)(vB.w & 0xFFFF)); s7 = s7 * dcv + a * bf2f((u16)(vB.w >> 16));
    float sum = s0 * bf2f((u16)(vC.x & 0xFFFF)) + s1 * bf2f((u16)(vC.x >> 16))
              + s2 * bf2f((u16)(vC.y & 0xFFFF)) + s3 * bf2f((u16)(vC.y >> 16))
              + s4 * bf2f((u16)(vC.z & 0xFFFF)) + s5 * bf2f((u16)(vC.z >> 16))
              + s6 * bf2f((u16)(vC.w & 0xFFFF)) + s7 * bf2f((u16)(vC.w >> 16));
    sum += __shfl_xor(sum, 1, 64);
    sum += __shfl_xor(sum, 2, 64);
    sum += __shfl_xor(sum, 4, 64);
    sum += __shfl_xor(sum, 8, 64);
    if (tsub == 0) yp[(size_t)tau * 2048] = f2bf(sum + Dh * xv);
  }
}

// ---------- gated RMSNorm (vectorized: uint4 loads, thread owns 8 channels) ----------
__global__ void k_gate(const u16* __restrict__ y, const u16* __restrict__ zx,
                       const float* __restrict__ normw, u16* __restrict__ u, int flip) {
  const int m = blockIdx.x, tid = threadIdx.x;
  const int ms = flip ? (m ^ 4095) : m;
  uint4 yv = *(const uint4*)(y + (size_t)m * 2048 + tid * 8);
  uint4 zv = *(const uint4*)(zx + (size_t)ms * 4480 + tid * 8);
  const u16* yp = (const u16*)&yv;
  const u16* zp = (const u16*)&zv;
  float vals[8];
  float ss = 0.f;
  #pragma unroll
  for (int i = 0; i < 8; i++) {
    float zf = bf2f(zp[i]);
    float wv = bf2f(yp[i]) * (zf / (1.f + __expf(-zf)));
    vals[i] = wv;
    ss += wv * wv;
  }
  float rs = rsqrtf(block_sum256(ss) * (1.f / 2048.f) + 1e-5f);
  float4 n0 = *(const float4*)(normw + tid * 8);
  float4 n1 = *(const float4*)(normw + tid * 8 + 4);
  uint4 o;
  o.x = pk2(vals[0] * rs * n0.x, vals[1] * rs * n0.y);
  o.y = pk2(vals[2] * rs * n0.z, vals[3] * rs * n0.w);
  o.z = pk2(vals[4] * rs * n1.x, vals[5] * rs * n1.y);
  o.w = pk2(vals[6] * rs * n1.z, vals[7] * rs * n1.w);
  *(uint4*)(u + (size_t)m * 2048 + tid * 8) = o;
}

// ---------- final LN + residual ----------
__global__ void k_final(const float* __restrict__ t2, const float* __restrict__ bias,
                        const float* __restrict__ g, const float* __restrict__ bb,
                        const float* __restrict__ x, float* __restrict__ out) {
  const int row = blockIdx.x, tid = threadIdx.x;
  float2 v = ((const float2*)(t2 + (size_t)row * 512))[tid];
  float v0 = v.x + bias[tid * 2], v1 = v.y + bias[tid * 2 + 1];
  float mean = block_sum256(v0 + v1) * (1.f / 512.f);
  float d0 = v0 - mean, d1 = v1 - mean;
  float var = block_sum256(d0 * d0 + d1 * d1) * (1.f / 512.f);
  float rs = rsqrtf(var + 1e-5f);
  float2 xr = ((const float2*)(x + (size_t)row * 512))[tid];
  float2 o;
  o.x = d0 * rs * g[tid * 2] + bb[tid * 2] + xr.x;
  o.y = d1 * rs * g[tid * 2 + 1] + bb[tid * 2 + 1] + xr.y;
  ((float2*)(out + (size_t)row * 512))[tid] = o;
}

extern "C" void kernel_launch(void* const* d_in, const int* in_sizes, int n_in,
                              void* d_out, int out_size, void* d_ws, size_t ws_size,
                              hipStream_t stream) {
  const float* x      = (const float*)d_in[0];
  const float* pre_w  = (const float*)d_in[1];
  const float* pre_b  = (const float*)d_in[2];
  const float* pre_g  = (const float*)d_in[3];
  const float* pre_bb = (const float*)d_in[4];
  const float* post_w = (const float*)d_in[5];
  const float* post_b = (const float*)d_in[6];
  const float* post_g = (const float*)d_in[7];
  const float* post_bb= (const float*)d_in[8];
  const float* win_[2]   = {(const float*)d_in[9],  (const float*)d_in[17]};
  const float* convw_[2] = {(const float*)d_in[10], (const float*)d_in[18]};
  const float* convb_[2] = {(const float*)d_in[11], (const float*)d_in[19]};
  const float* dtb_[2]   = {(const float*)d_in[12], (const float*)d_in[20]};
  const float* Alog_[2]  = {(const float*)d_in[13], (const float*)d_in[21]};
  const float* Dp_[2]    = {(const float*)d_in[14], (const float*)d_in[22]};
  const float* normw_[2] = {(const float*)d_in[15], (const float*)d_in[23]};
  const float* wout_[2]  = {(const float*)d_in[16], (const float*)d_in[24]};

  char* ws = (char*)d_ws;
  constexpr size_t OFF_WT_PRE  = 0;                         // 1 MB (PR aliases later)
  constexpr size_t OFF_WT_WINF = OFF_WT_PRE  + 1048576;
  constexpr size_t OFF_WT_WINB = OFF_WT_WINF + 9175040;
  constexpr size_t OFF_WT_WOF  = OFF_WT_WINB + 9175040;
  constexpr size_t OFF_WT_WOB  = OFF_WT_WOF  + 4194304;
  constexpr size_t OFF_WT_POST = OFF_WT_WOB  + 4194304;
  constexpr size_t OFF_HPRE    = OFF_WT_POST + 1048576;     // 16 MB
  constexpr size_t OFF_ZX      = OFF_HPRE + 16777216;       // 70 MB
  constexpr size_t OFF_XT      = OFF_ZX + 73400320;         // 32 MB: XT [2][2048][4096] bf16
  constexpr size_t OFF_BC      = OFF_XT + 33554432;         // 4 MB BCtok + 4 MB BCT
  constexpr size_t OFF_DT      = OFF_BC + 8388608;          // 1 MB DT_T
  constexpr size_t OFF_DEC     = OFF_DT + 1048576;          // 1 MB DEC_T
  constexpr size_t OFF_Y       = OFF_DEC + 1048576;         // 16 MB bf16 y
  constexpr size_t OFF_S       = OFF_Y + 33554432;          // 32 MB (bf16 S uses half)
  constexpr size_t OFF_HB      = OFF_S + 33554432;          // 32 MB (bf16 HB uses half)
  constexpr size_t ARENA_END   = OFF_HB + 33554432;         // == 263716864

  u16* WtPre    = (u16*)(ws + OFF_WT_PRE);
  u16* WtWin[2] = {(u16*)(ws + OFF_WT_WINF), (u16*)(ws + OFF_WT_WINB)};
  u16* WtWo[2]  = {(u16*)(ws + OFF_WT_WOF),  (u16*)(ws + OFF_WT_WOB)};
  u16* WtPost   = (u16*)(ws + OFF_WT_POST);
  u16* HPRE = (u16*)(ws + OFF_HPRE);
  u16* ZX   = (u16*)(ws + OFF_ZX);
  u16* XT   = (u16*)(ws + OFF_XT);
  u16* BCtok= (u16*)(ws + OFF_BC);
  u16* BCT  = (u16*)(ws + OFF_BC + 4194304);
  float* DTt = (float*)(ws + OFF_DT);
  float* DECt= (float*)(ws + OFF_DEC);
  u16*  Y   = (u16*)(ws + OFF_Y);
  u16*  Sb  = (u16*)(ws + OFF_S);          // bf16 wout_f intermediate
  u16*  HB  = (u16*)(ws + OFF_HB);         // bf16 chunk states
  // aliases
  float* PRb  = (float*)(ws + OFF_WT_PRE); // 4 KB (WtPre dead after pre-GEMM)
  u16*   XBF  = (u16*)(ws + OFF_Y);        // bf16 x for pre-GEMM
  float* TMP  = (float*)(ws + OFF_S);      // pre-GEMM f32 out (before Sb written)
  u16*   U    = (u16*)(ws + OFF_XT);       // gated y bf16 (XT dead after ssd_c)
  u16*   U2   = ZX;                        // final gated sum (ZX dead)
  float* TMP2 = (float*)(ws + OFF_XT);     // post-GEMM f32 out (U dead)

  const bool chunked = (ws_size >= ARENA_END);

  dim3 tb(32, 8);
  k_tcast<<<dim3(32, 16),  tb, 0, stream>>>(pre_w,   WtPre,    512, 1024, 1024);
  k_tcast<<<dim3(140, 32), tb, 0, stream>>>(win_[0], WtWin[0], 1024, 4384, 4480);
  k_tcast<<<dim3(140, 32), tb, 0, stream>>>(win_[1], WtWin[1], 1024, 4384, 4480);
  k_tcast<<<dim3(32, 64),  tb, 0, stream>>>(wout_[0], WtWo[0], 2048, 1024, 1024);
  k_tcast<<<dim3(32, 64),  tb, 0, stream>>>(wout_[1], WtWo[1], 2048, 1024, 1024);
  k_tcast<<<dim3(16, 32),  tb, 0, stream>>>(post_w,  WtPost,   1024,  512,  512);
  k_cast<<<4096, 256, 0, stream>>>(x, XBF, 1048576);
  k_gemm<<<dim3(64, 8), 256, 0, stream>>>(XBF, WtPre, TMP, nullptr, nullptr, nullptr,
                                          8192, 1024, 512, 1024, 0);
  k_preln<<<8192, 256, 0, stream>>>(TMP, pre_b, pre_g, pre_bb, HPRE);

  for (int d = 0; d < 2; d++) {
    int flip = d;
    k_gemm256<<<dim3(32, 18), 512, 0, stream>>>(HPRE, WtWin[d], ZX);
    k_dt2<<<dim3(16, 32, 2), 256, 0, stream>>>(ZX, dtb_[d], Alog_[d], DTt, DECt, flip);
    k_conv2<<<dim3(36, 64, 2), 256, 0, stream>>>(ZX, convw_[d], convb_[d], XT, BCtok, BCT, flip);
    if (chunked) {
      k_ssd_a<<<dim3(NCH, 32, 2), 512, 0, stream>>>(XT, BCT, DTt, Alog_[d], HB, PRb);
      k_scan_b<<<dim3(32, 32, 2), 256, 0, stream>>>(HB, PRb);
      k_ssd_c<<<dim3(NCH, 32, 2), 512, 0, stream>>>(BCtok, XT, DTt, HB, Alog_[d], Dp_[d], Y);
    } else {
      k_scan<<<dim3(4, 32, 2), 256, 0, stream>>>(XT, BCtok, DTt, DECt, Dp_[d], Y);
    }
    k_gate<<<8192, 256, 0, stream>>>(Y, ZX, normw_[d], U, flip);
    // d=0: bf16 out to Sb. d=1: accumulate bf16 Sb + fused u2 (silu(HPRE)) -> bf16 U2.
    if (d == 0) {
      k_gemm<<<dim3(64, 8), 256, 0, stream>>>(U, WtWo[d], nullptr, Sb, nullptr, nullptr,
                                              8192, 1024, 2048, 1024, 1);
    } else {
      k_gemm<<<dim3(64, 8), 256, 0, stream>>>(U, WtWo[d], nullptr, U2, HPRE, Sb,
                                              8192, 1024, 2048, 1024, 1 | 4 | 8 | 16);
    }
  }

  k_gemm<<<dim3(64, 4), 256, 0, stream>>>(U2, WtPost, TMP2, nullptr, nullptr, nullptr,
                                          8192, 512, 1024, 512, 0);
  k_final<<<8192, 256, 0, stream>>>(TMP2, post_b, post_g, post_bb, x, (float*)d_out);
}

// Round 19
// 680.095 us; speedup vs baseline: 1.1474x; 1.0082x over previous
//
#include <hip/hip_runtime.h>
#include <stdint.h>

typedef unsigned short u16;
typedef __attribute__((ext_vector_type(8))) short short8;
typedef __attribute__((ext_vector_type(4))) float f32x4;

__device__ __forceinline__ float bf2f(u16 u) {
  union { float f; uint32_t i; } v; v.i = ((uint32_t)u) << 16; return v.f;
}
__device__ __forceinline__ u16 f2bf(float f) {
  union { float f; uint32_t i; } v; v.f = f;
  uint32_t r = v.i + 0x7FFFu + ((v.i >> 16) & 1u);
  return (u16)(r >> 16);
}
__device__ __forceinline__ uint32_t pk2(float a, float b) {
  return (uint32_t)f2bf(a) | ((uint32_t)f2bf(b) << 16);
}
// async global->LDS, 16B per lane; LDS dest is wave-uniform base + lane*16
__device__ __forceinline__ void gload16(const u16* g, u16* l) {
  __builtin_amdgcn_global_load_lds(
      (const __attribute__((address_space(1))) unsigned int*)g,
      (__attribute__((address_space(3))) unsigned int*)l, 16, 0, 0);
}

__device__ __forceinline__ float block_sum256(float v) {
  __shared__ float red[4];
  #pragma unroll
  for (int o = 1; o < 64; o <<= 1) v += __shfl_xor(v, o, 64);
  int lane = threadIdx.x & 63, w = threadIdx.x >> 6;
  __syncthreads();
  if (lane == 0) red[w] = v;
  __syncthreads();
  return red[0] + red[1] + red[2] + red[3];
}

// ---------- W[K][N] f32 -> Wt[Npad][K] bf16 (zero-pad rows >= N) ----------
__global__ void k_tcast(const float* __restrict__ W, u16* __restrict__ Wt,
                        int K, int N, int Npad) {
  __shared__ float tile[32][33];
  int n0 = blockIdx.x * 32, k0 = blockIdx.y * 32;
  int tx = threadIdx.x, ty0 = threadIdx.y;
  #pragma unroll
  for (int i = 0; i < 4; i++) {
    int ty = ty0 + i * 8;
    int k = k0 + ty, n = n0 + tx;
    tile[ty][tx] = (k < K && n < N) ? W[(size_t)k * N + n] : 0.f;
  }
  __syncthreads();
  #pragma unroll
  for (int i = 0; i < 4; i++) {
    int ty = ty0 + i * 8;
    int n = n0 + ty, k = k0 + tx;
    if (n < Npad && k < K) Wt[(size_t)n * K + k] = f2bf(tile[tx][ty]);
  }
}

// ---------- f32 -> bf16 elementwise (x4) ----------
__global__ void k_cast(const float* __restrict__ in, u16* __restrict__ out, int n4) {
  int i = blockIdx.x * 256 + threadIdx.x;
  if (i >= n4) return;
  float4 v = ((const float4*)in)[i];
  uint2 o;
  o.x = pk2(v.x, v.y);
  o.y = pk2(v.z, v.w);
  ((uint2*)out)[i] = o;
}

// ---------- 128x128 bf16 MFMA GEMM (dbuf global_load_lds), general ----------
// flags: 1=bf16 out, 2=accum f32 Cf, 4=flip row, 8=fuse u2 (v *= silu(hp)),
//        16=accum bf16 ab
__launch_bounds__(256)
__global__ void k_gemm(const u16* __restrict__ A, const u16* __restrict__ Bt,
                       float* __restrict__ Cf, u16* __restrict__ Cb,
                       const u16* __restrict__ hp, const u16* __restrict__ ab,
                       int M, int N, int K, int ldc, int flags) {
  __shared__ u16 lA[2][128 * 64];
  __shared__ u16 lB[2][128 * 64];
  const int tid = threadIdx.x;
  const int lane = tid & 63;
  const int wave = tid >> 6;
  const int bm = blockIdx.x, bn = blockIdx.y;
  const int wr = wave >> 1, wc = wave & 1;
  const int fr = lane & 15, fq = lane >> 4;

  const int srow = wave * 32 + (lane >> 3);
  const int scol = ((lane & 7) ^ (srow & 7)) * 8;   // inverse-swizzled source col
  const u16* gA = A + (size_t)(bm * 128 + srow) * K + scol;
  const u16* gB = Bt + (size_t)(bn * 128 + srow) * K + scol;
  const int lofs = wave * 2048;

  f32x4 acc[4][4] = {};

  #pragma unroll
  for (int i = 0; i < 4; i++) {
    gload16(gA + (size_t)(i * 8) * K, &lA[0][lofs + i * 512]);
    gload16(gB + (size_t)(i * 8) * K, &lB[0][lofs + i * 512]);
  }
  __syncthreads();

  const int NT = K >> 6;
  for (int t = 0; t < NT; ++t) {
    const int cur = t & 1;
    if (t + 1 < NT) {
      const int kt = (t + 1) << 6;
      #pragma unroll
      for (int i = 0; i < 4; i++) {
        gload16(gA + (size_t)(i * 8) * K + kt, &lA[cur ^ 1][lofs + i * 512]);
        gload16(gB + (size_t)(i * 8) * K + kt, &lB[cur ^ 1][lofs + i * 512]);
      }
    }
    #pragma unroll
    for (int kk = 0; kk < 2; kk++) {
      short8 af[4], bfr[4];
      #pragma unroll
      for (int m = 0; m < 4; m++) {
        int row = wr * 64 + m * 16 + fr;
        int sl = (kk * 4 + fq) ^ (row & 7);
        af[m] = *(const short8*)(&lA[cur][row * 64 + sl * 8]);
      }
      #pragma unroll
      for (int n = 0; n < 4; n++) {
        int row = wc * 64 + n * 16 + fr;
        int sl = (kk * 4 + fq) ^ (row & 7);
        bfr[n] = *(const short8*)(&lB[cur][row * 64 + sl * 8]);
      }
      #pragma unroll
      for (int m = 0; m < 4; m++)
        #pragma unroll
        for (int n = 0; n < 4; n++)
          acc[m][n] = __builtin_amdgcn_mfma_f32_16x16x32_bf16(af[m], bfr[n], acc[m][n], 0, 0, 0);
    }
    __syncthreads();   // drains next-tile loads (latency hidden under compute above)
  }

  const bool bf16out = flags & 1, accum = flags & 2, flip = flags & 4, fuse = flags & 8;
  const bool accb = flags & 16;
  #pragma unroll
  for (int m = 0; m < 4; m++) {
    #pragma unroll
    for (int q = 0; q < 4; q++) {
      int rr = bm * 128 + wr * 64 + m * 16 + fq * 4 + q;
      int orow = flip ? (rr ^ 4095) : rr;
      size_t rb = (size_t)orow * ldc;
      #pragma unroll
      for (int n = 0; n < 4; n++) {
        int cc = bn * 128 + wc * 64 + n * 16 + fr;
        float v = acc[m][n][q];
        if (accum) v += Cf[rb + cc];
        if (accb) v += bf2f(ab[rb + cc]);
        if (fuse) {
          float h = bf2f(hp[rb + cc]);
          v = v * (h / (1.f + __expf(-h)));
        }
        if (bf16out) Cb[rb + cc] = f2bf(v);
        else Cf[rb + cc] = v;
      }
    }
  }
}

// ---------- 256x256 bf16 MFMA GEMM for the win projection (r11 proven) ----------
// 8 waves (2Mx4N), per-wave 128x64, BK=64, 128 KiB LDS dbuf, 2-barrier
// structure, counted vmcnt(8) at tile boundaries (never drain mid-loop).
// Fixed shape: M=8192, K=1024, N=4480 (18 N-tiles; ragged: B-row clamp + C guard).
__launch_bounds__(512)
__global__ void k_gemm256(const u16* __restrict__ A, const u16* __restrict__ Bt,
                          u16* __restrict__ Cb) {
  constexpr int K = 1024, N = 4480, NT = 16;
  __shared__ u16 lA[2][256 * 64];
  __shared__ u16 lB[2][256 * 64];
  const int tid = threadIdx.x;
  const int lane = tid & 63;
  const int wid = tid >> 6;
  const int bm = blockIdx.x, bn = blockIdx.y;
  const int wr = wid >> 2, wc = wid & 3;       // 2 x 4 waves
  const int fr = lane & 15, fq = lane >> 4;

  const int srow = tid >> 3;                    // 0..63
  const int scol = ((tid & 7) ^ (srow & 7)) * 8;
  const u16* gA[4];
  const u16* gB[4];
  #pragma unroll
  for (int i = 0; i < 4; i++) {
    int arow = bm * 256 + i * 64 + srow;
    gA[i] = A + (size_t)arow * K + scol;
    int brow = bn * 256 + i * 64 + srow;
    if (brow > N - 1) brow = N - 1;             // ragged-N clamp (cols guarded at C)
    gB[i] = Bt + (size_t)brow * K + scol;
  }

  f32x4 acc[8][4] = {};

  auto stage = [&](int u) {
    const int buf = u & 1, kt = u << 6;
    #pragma unroll
    for (int i = 0; i < 4; i++)
      gload16(gA[i] + kt, &lA[buf][i * 4096 + tid * 8]);
    #pragma unroll
    for (int i = 0; i < 4; i++)
      gload16(gB[i] + kt, &lB[buf][i * 4096 + tid * 8]);
  };

  // prologue: tiles 0,1 in flight; wait tile 0 only (8 newest stay pending)
  stage(0);
  stage(1);
  asm volatile("s_waitcnt vmcnt(8)" ::: "memory");
  __builtin_amdgcn_s_barrier();

  for (int t = 0; t < NT; ++t) {
    const u16* bufA = &lA[t & 1][0];
    const u16* bufB = &lB[t & 1][0];
    #pragma unroll
    for (int kk = 0; kk < 2; kk++) {
      short8 af[8], bfm[4];
      #pragma unroll
      for (int m = 0; m < 8; m++) {
        int row = wr * 128 + m * 16 + fr;
        int sl = (kk * 4 + fq) ^ (row & 7);
        af[m] = *(const short8*)(&bufA[row * 64 + sl * 8]);
      }
      #pragma unroll
      for (int n = 0; n < 4; n++) {
        int row = wc * 64 + n * 16 + fr;
        int sl = (kk * 4 + fq) ^ (row & 7);
        bfm[n] = *(const short8*)(&bufB[row * 64 + sl * 8]);
      }
      #pragma unroll
      for (int m = 0; m < 8; m++)
        #pragma unroll
        for (int n = 0; n < 4; n++)
          acc[m][n] = __builtin_amdgcn_mfma_f32_16x16x32_bf16(af[m], bfm[n], acc[m][n], 0, 0, 0);
    }
    // boundary: buf[t&1] dead -> stage t+2 there; counted wait: t+1 landed,
    // t+2's 8 loads stay in flight (never drain to 0 mid-loop)
    __builtin_amdgcn_s_barrier();
    if (t + 2 < NT) {
      stage(t + 2);
      asm volatile("s_waitcnt vmcnt(8)" ::: "memory");
    } else {
      asm volatile("s_waitcnt vmcnt(0)" ::: "memory");
    }
    __builtin_amdgcn_s_barrier();
  }

  #pragma unroll
  for (int m = 0; m < 8; m++) {
    #pragma unroll
    for (int q = 0; q < 4; q++) {
      size_t rb = (size_t)(bm * 256 + wr * 128 + m * 16 + fq * 4 + q) * N;
      #pragma unroll
      for (int n = 0; n < 4; n++) {
        int cc = bn * 256 + wc * 64 + n * 16 + fr;
        if (cc < N) Cb[rb + cc] = f2bf(acc[m][n][q]);
      }
    }
  }
}

// ---------- pre-LN (bf16 input) ----------
__global__ void k_preln(const u16* __restrict__ t, const float* __restrict__ bias,
                        const float* __restrict__ g, const float* __restrict__ bb,
                        u16* __restrict__ out) {
  const int row = blockIdx.x, tid = threadIdx.x;
  uint2 v = *(const uint2*)(t + (size_t)row * 1024 + tid * 4);
  float4 bi = ((const float4*)bias)[tid];
  float v0 = bf2f((u16)(v.x & 0xFFFF)) + bi.x;
  float v1 = bf2f((u16)(v.x >> 16)) + bi.y;
  float v2 = bf2f((u16)(v.y & 0xFFFF)) + bi.z;
  float v3 = bf2f((u16)(v.y >> 16)) + bi.w;
  float mean = block_sum256(v0 + v1 + v2 + v3) * (1.f / 1024.f);
  float d0 = v0 - mean, d1 = v1 - mean, d2 = v2 - mean, d3 = v3 - mean;
  float var = block_sum256(d0 * d0 + d1 * d1 + d2 * d2 + d3 * d3) * (1.f / 1024.f);
  float rs = rsqrtf(var + 1e-5f);
  float4 gg = ((const float4*)g)[tid];
  float4 bv = ((const float4*)bb)[tid];
  uint2 o;
  o.x = pk2(d0 * rs * gg.x + bv.x, d1 * rs * gg.y + bv.y);
  o.y = pk2(d2 * rs * gg.z + bv.z, d3 * rs * gg.w + bv.w);
  ((uint2*)(out + (size_t)row * 1024))[tid] = o;
}

// ---------- dt/dec in [b][h][t] (flipped-domain) layout ----------
__global__ void k_dt2(const u16* __restrict__ zx, const float* __restrict__ dtb,
                      const float* __restrict__ Alog, float* __restrict__ DTt,
                      float* __restrict__ DECt, int flip) {
  int t = blockIdx.x * 256 + threadIdx.x;
  int h = blockIdx.y, b = blockIdx.z;
  int ts = flip ? 4095 - t : t;
  float raw = bf2f(zx[(size_t)((b << 12) + ts) * 4480 + 4352 + h]) + dtb[h];
  float d = (raw > 20.f) ? raw : log1pf(__expf(raw));
  size_t o = (size_t)(b * 32 + h) * 4096 + t;
  DTt[o] = d;
  DECt[o] = __expf(-__expf(Alog[h]) * d);
}

// ---------- conv(K=4)+silu; vectorized I/O; outputs XT [b][2048][4096],
// ---------- BCtok [m][256] bf16, BCT [b][256][4096] (flipped-domain) ----------
__global__ void k_conv2(const u16* __restrict__ zx, const float* __restrict__ cw,
                        const float* __restrict__ cb, u16* __restrict__ XT,
                        u16* __restrict__ BCtok, u16* __restrict__ BCT, int flip) {
  const int ct = blockIdx.x;           // 0..35 channel tile (64)
  const int tt = blockIdx.y;           // 0..63 token tile (64)
  const int b = blockIdx.z;
  const int tid = threadIdx.x;         // 256
  __shared__ float sin_[67][64];
  __shared__ float sout[64][65];
  const int ch0 = ct * 64, t0 = tt * 64;

  // staging: uint2 = 4 ch/thread; 67 rows x 16 quads
  for (int i = tid; i < 67 * 16; i += 256) {
    int r = i >> 4, c4 = (i & 15) << 2;
    int tok = t0 - 3 + r;
    float f0 = 0.f, f1 = 0.f, f2 = 0.f, f3 = 0.f;
    if (tok >= 0) {
      int src = (b << 12) + (flip ? 4095 - tok : tok);
      uint2 v = *(const uint2*)(zx + (size_t)src * 4480 + 2048 + ch0 + c4);
      f0 = bf2f((u16)(v.x & 0xFFFF)); f1 = bf2f((u16)(v.x >> 16));
      f2 = bf2f((u16)(v.y & 0xFFFF)); f3 = bf2f((u16)(v.y >> 16));
    }
    sin_[r][c4] = f0; sin_[r][c4 + 1] = f1; sin_[r][c4 + 2] = f2; sin_[r][c4 + 3] = f3;
  }
  __syncthreads();

  const int ch = tid & 63, g = tid >> 6;
  const int chg = ch0 + ch;
  float4 wv = *(const float4*)(cw + (size_t)chg * 4);
  float bias = cb[chg];
  #pragma unroll
  for (int i = 0; i < 16; i++) {
    int tl = g * 16 + i;
    float a = bias + wv.x * sin_[tl][ch] + wv.y * sin_[tl + 1][ch]
                   + wv.z * sin_[tl + 2][ch] + wv.w * sin_[tl + 3][ch];
    sout[tl][ch] = a / (1.f + __expf(-a));
  }
  __syncthreads();

  if (ch0 < 2048) {
    for (int i = tid; i < 64 * 16; i += 256) {
      int chw = i >> 4, t4 = (i & 15) << 2;
      uint2 o;
      o.x = pk2(sout[t4][chw], sout[t4 + 1][chw]);
      o.y = pk2(sout[t4 + 2][chw], sout[t4 + 3][chw]);
      *(uint2*)(XT + ((size_t)(b * 2048 + ch0 + chw)) * 4096 + t0 + t4) = o;
    }
  } else {
    int c2b = (ct - 32) * 64;
    for (int i = tid; i < 64 * 16; i += 256) {
      int chw = i >> 4, t4 = (i & 15) << 2;
      uint2 o;
      o.x = pk2(sout[t4][chw], sout[t4 + 1][chw]);
      o.y = pk2(sout[t4 + 2][chw], sout[t4 + 3][chw]);
      *(uint2*)(BCT + ((size_t)(b * 256 + c2b + chw)) * 4096 + t0 + t4) = o;
    }
    for (int i = tid; i < 64 * 8; i += 256) {
      int r = i >> 3, c8 = (i & 7) << 3;
      uint4 o;
      o.x = pk2(sout[r][c8], sout[r][c8 + 1]);
      o.y = pk2(sout[r][c8 + 2], sout[r][c8 + 3]);
      o.z = pk2(sout[r][c8 + 4], sout[r][c8 + 5]);
      o.w = pk2(sout[r][c8 + 6], sout[r][c8 + 7]);
      *(uint4*)(BCtok + ((size_t)(b * 4096 + t0 + r)) * 256 + c2b + c8) = o;
    }
  }
}

// ================= SSD chunked scan, Q=256, NCH=16 =================
#define NCH 16
#define SWZ(row, oct, msk) (((oct) ^ ((row) & (msk))) << 4)

// inclusive cumsum helper over 256 threads (first 4 waves), returns L for tid<256
__device__ __forceinline__ void cumsum256(int tid, int lane, float adt, float dtv,
                                          float* sL, float* sdt, float* spart) {
  float v = adt;
  if (tid < 256) {
    #pragma unroll
    for (int o = 1; o < 64; o <<= 1) {
      float t = __shfl_up(v, o, 64);
      if (lane >= o) v += t;
    }
    if (lane == 63) spart[tid >> 6] = v;
  }
  __syncthreads();
  if (tid < 256) {
    int w = tid >> 6;
    float off = 0.f;
    #pragma unroll
    for (int j = 0; j < 3; j++) if (j < w) off += spart[j];
    sL[tid] = v + off;
    sdt[tid] = dtv;
  }
}

// pass A: H_localT[p][n] = sum_tau w_tau * X[tau][p] * B[tau][n]; HB bf16
__launch_bounds__(512, 1)
__global__ void k_ssd_a(const u16* __restrict__ XT, const u16* __restrict__ BCT,
                        const float* __restrict__ DTt, const float* __restrict__ Alog,
                        u16* __restrict__ HB, float* __restrict__ PR) {
  const int c = blockIdx.x, h = blockIdx.y, b = blockIdx.z;
  const int tid = threadIdx.x;
  const int lane = tid & 63, w = tid >> 6;
  const int fr = lane & 15, fq = lane >> 4;
  const int bh = b * 32 + h;

  __shared__ u16 sX[64 * 256];      // [p][tau], 32 oct/row, swz ^(p&15)
  __shared__ u16 sBW[128 * 256];    // [n][tau], 32 oct/row, swz ^(n&15)
  __shared__ float sL[256], sdt[256], sw_[256], spart[4];

  float dtv = 0.f;
  if (tid < 256) dtv = DTt[(size_t)bh * 4096 + c * 256 + tid];
  float expA = __expf(Alog[h]);
  cumsum256(tid, lane, -expA * dtv, dtv, sL, sdt, spart);
  __syncthreads();
  if (tid < 256) sw_[tid] = __expf(sL[255] - sL[tid]) * sdt[tid];
  for (int i = tid; i < 2048; i += 512) {
    int p = i >> 5, oct = i & 31;
    uint4 v = *(const uint4*)(XT + ((size_t)(b * 2048 + h * 64 + p) << 12) + c * 256 + oct * 8);
    *(uint4*)((char*)sX + p * 512 + SWZ(p, oct, 15)) = v;
  }
  __syncthreads();
  for (int i = tid; i < 4096; i += 512) {
    int n = i >> 5, oct = i & 31;
    uint4 v = *(const uint4*)(BCT + ((size_t)(b * 256 + n) << 12) + c * 256 + oct * 8);
    const float* swp = sw_ + oct * 8;
    float f0 = bf2f((u16)(v.x & 0xFFFF)) * swp[0];
    float f1 = bf2f((u16)(v.x >> 16)) * swp[1];
    float f2 = bf2f((u16)(v.y & 0xFFFF)) * swp[2];
    float f3 = bf2f((u16)(v.y >> 16)) * swp[3];
    float f4 = bf2f((u16)(v.z & 0xFFFF)) * swp[4];
    float f5 = bf2f((u16)(v.z >> 16)) * swp[5];
    float f6 = bf2f((u16)(v.w & 0xFFFF)) * swp[6];
    float f7 = bf2f((u16)(v.w >> 16)) * swp[7];
    uint4 o;
    o.x = pk2(f0, f1); o.y = pk2(f2, f3); o.z = pk2(f4, f5); o.w = pk2(f6, f7);
    *(uint4*)((char*)sBW + n * 512 + SWZ(n, oct, 15)) = o;
  }
  __syncthreads();

  const int pb = w >> 1, nh = w & 1;
  f32x4 acc[4] = {};
  #pragma unroll
  for (int ks = 0; ks < 8; ks++) {
    int p = pb * 16 + fr;
    short8 af = *(const short8*)((char*)sX + p * 512 + SWZ(p, ks * 4 + fq, 15));
    #pragma unroll
    for (int nb = 0; nb < 4; nb++) {
      int n = nh * 64 + nb * 16 + fr;
      short8 bfm = *(const short8*)((char*)sBW + n * 512 + SWZ(n, ks * 4 + fq, 15));
      acc[nb] = __builtin_amdgcn_mfma_f32_16x16x32_bf16(af, bfm, acc[nb], 0, 0, 0);
    }
  }
  u16* hb = HB + (size_t)(bh * NCH + c) * 8192;
  #pragma unroll
  for (int nb = 0; nb < 4; nb++)
    #pragma unroll
    for (int q = 0; q < 4; q++) {
      int p = pb * 16 + fq * 4 + q;
      int n = nh * 64 + nb * 16 + fr;
      hb[p * 128 + n] = f2bf(acc[nb][q]);
    }
  if (tid == 0) PR[bh * NCH + c] = __expf(sL[255]);
}

// pass B: sequential combine over chunk boundaries (bf16 storage, f32 carry)
__global__ void k_scan_b(u16* __restrict__ HB, const float* __restrict__ PR) {
  const int eb = blockIdx.x, h = blockIdx.y, b = blockIdx.z;
  const int e = eb * 256 + threadIdx.x;
  const int bh = b * 32 + h;
  u16* base = HB + (size_t)bh * NCH * 8192 + e;
  const float* pr = PR + bh * NCH;
  float carry = 0.f;
  #pragma unroll 4
  for (int c = 0; c < NCH; ++c) {
    float v = bf2f(base[(size_t)c * 8192]);
    base[(size_t)c * 8192] = f2bf(carry);
    carry = pr[c] * carry + v;
  }
}

// pass C: y = (M.(C B^T)) X + exp(L_t) (C Hin) ; D-term added to P diag AFTER *G
// SIMD-balanced wave->t-block map: tb = w<4 ? w : 11-w pairs causal costs
// (1+4),(1+4),(2+3),(2+3) on the 4 SIMDs (waves s,s+4 co-resident) -> 5 each.
__launch_bounds__(512, 1)
__global__ void k_ssd_c(const u16* __restrict__ BCtok, const u16* __restrict__ XT,
                        const float* __restrict__ DTt, const u16* __restrict__ HB,
                        const float* __restrict__ Alog, const float* __restrict__ Dp,
                        u16* __restrict__ Y) {
  const int c = blockIdx.x, h = blockIdx.y, b = blockIdx.z;
  const int tid = threadIdx.x;
  const int lane = tid & 63, w = tid >> 6;
  const int tb = (w < 4) ? w : 11 - w;        // balanced t-block assignment
  const int fr = lane & 15, fq = lane >> 4;
  const int bh = b * 32 + h;
  const size_t m0 = (size_t)b * 4096 + c * 256;

  __shared__ u16 sB[256 * 128];     // [tau][n], 16 oct/row, swz ^(tau&15)
  __shared__ u16 sX[64 * 256];      // [p][tau], 32 oct/row, swz ^(p&15)
  __shared__ u16 sH[64 * 128];      // [p][n],  16 oct/row, swz ^(p&15)
  __shared__ u16 sP[8 * 32 * 64];   // per-wave [32t][64tau], 8 oct/row, swz ^(t&7)
  __shared__ float sL[256], sdt[256], spart[4];

  float dtv = 0.f;
  if (tid < 256) dtv = DTt[(size_t)bh * 4096 + c * 256 + tid];
  float expA = __expf(Alog[h]);
  cumsum256(tid, lane, -expA * dtv, dtv, sL, sdt, spart);

  for (int i = tid; i < 4096; i += 512) {
    int tr = i >> 4, oct = i & 15;
    uint4 v = *(const uint4*)(BCtok + ((m0 + tr) << 8) + oct * 8);
    *(uint4*)((char*)sB + tr * 256 + SWZ(tr, oct, 15)) = v;
  }
  for (int i = tid; i < 2048; i += 512) {
    int p = i >> 5, oct = i & 31;
    uint4 v = *(const uint4*)(XT + ((size_t)(b * 2048 + h * 64 + p) << 12) + c * 256 + oct * 8);
    *(uint4*)((char*)sX + p * 512 + SWZ(p, oct, 15)) = v;
  }
  for (int i = tid; i < 1024; i += 512) {
    int p = i >> 4, oct = i & 15;
    uint4 v = *(const uint4*)(HB + (size_t)(bh * NCH + c) * 8192 + p * 128 + oct * 8);
    *(uint4*)((char*)sH + p * 256 + SWZ(p, oct, 15)) = v;
  }
  // C A-fragments (reused by G and Yoff): rows t = tb*32+m*16+fr, ch 128+k
  short8 cf[2][4];
  #pragma unroll
  for (int m = 0; m < 2; m++)
    #pragma unroll
    for (int ks = 0; ks < 4; ks++)
      cf[m][ks] = *(const short8*)(BCtok + ((m0 + tb * 32 + m * 16 + fr) << 8) + 128 + ks * 32 + fq * 8);
  __syncthreads();

  float Lt[2][4], eLt[2][4];
  #pragma unroll
  for (int m = 0; m < 2; m++)
    #pragma unroll
    for (int q = 0; q < 4; q++) {
      Lt[m][q] = sL[tb * 32 + m * 16 + fq * 4 + q];
      eLt[m][q] = __expf(Lt[m][q]);
    }
  const float Dh = Dp[h];

  f32x4 accY[2][4] = {};
  u16* pw = sP + w * 2048;
  const int ntl = (tb >> 1) + 1;
  for (int tt = 0; tt < ntl; tt++) {
    const int t0 = tt * 64;
    f32x4 g[2][4] = {};
    #pragma unroll
    for (int ks = 0; ks < 4; ks++) {
      short8 bfm[4];
      #pragma unroll
      for (int nb = 0; nb < 4; nb++) {
        int tr = t0 + nb * 16 + fr;
        bfm[nb] = *(const short8*)((char*)sB + tr * 256 + SWZ(tr, ks * 4 + fq, 15));
      }
      #pragma unroll
      for (int m = 0; m < 2; m++)
        #pragma unroll
        for (int nb = 0; nb < 4; nb++)
          g[m][nb] = __builtin_amdgcn_mfma_f32_16x16x32_bf16(cf[m][ks], bfm[nb], g[m][nb], 0, 0, 0);
    }
    // mask * G -> P (bf16, per-wave LDS); D added to diag AFTER multiplying by G
    #pragma unroll
    for (int nb = 0; nb < 4; nb++) {
      int tau = t0 + nb * 16 + fr;
      float Ltau = sL[tau], dtau = sdt[tau];
      #pragma unroll
      for (int m = 0; m < 2; m++) {
        #pragma unroll
        for (int q = 0; q < 4; q++) {
          int t = tb * 32 + m * 16 + fq * 4 + q;
          float mask = (tau > t) ? 0.f : __expf(Lt[m][q] - Ltau) * dtau;
          float pv = mask * g[m][nb][q];
          pv = (tau == t) ? pv + Dh : pv;
          int tl = m * 16 + fq * 4 + q, taul = nb * 16 + fr;
          *(u16*)((char*)pw + tl * 128 + ((((taul) >> 3) ^ (tl & 7)) << 4) + (taul & 7) * 2) = f2bf(pv);
        }
      }
    }
    // P @ X
    #pragma unroll
    for (int ks = 0; ks < 2; ks++) {
      short8 pf[2], xf[4];
      #pragma unroll
      for (int m = 0; m < 2; m++) {
        int tl = m * 16 + fr;
        pf[m] = *(const short8*)((char*)pw + tl * 128 + (((ks * 4 + fq) ^ (tl & 7)) << 4));
      }
      #pragma unroll
      for (int pb = 0; pb < 4; pb++) {
        int p = pb * 16 + fr;
        int oct = (t0 >> 3) + ks * 4 + fq;
        xf[pb] = *(const short8*)((char*)sX + p * 512 + SWZ(p, oct, 15));
      }
      #pragma unroll
      for (int m = 0; m < 2; m++)
        #pragma unroll
        for (int pb = 0; pb < 4; pb++)
          accY[m][pb] = __builtin_amdgcn_mfma_f32_16x16x32_bf16(pf[m], xf[pb], accY[m][pb], 0, 0, 0);
    }
  }
  // Yoff = C @ HinT
  f32x4 accO[2][4] = {};
  #pragma unroll
  for (int ks = 0; ks < 4; ks++) {
    short8 hf[4];
    #pragma unroll
    for (int pb = 0; pb < 4; pb++) {
      int p = pb * 16 + fr;
      hf[pb] = *(const short8*)((char*)sH + p * 256 + SWZ(p, ks * 4 + fq, 15));
    }
    #pragma unroll
    for (int m = 0; m < 2; m++)
      #pragma unroll
      for (int pb = 0; pb < 4; pb++)
        accO[m][pb] = __builtin_amdgcn_mfma_f32_16x16x32_bf16(cf[m][ks], hf[pb], accO[m][pb], 0, 0, 0);
  }
  #pragma unroll
  for (int m = 0; m < 2; m++)
    #pragma unroll
    for (int pb = 0; pb < 4; pb++)
      #pragma unroll
      for (int q = 0; q < 4; q++) {
        int t = tb * 32 + m * 16 + fq * 4 + q;
        float val = accY[m][pb][q] + eLt[m][q] * accO[m][pb][q];
        Y[(m0 + t) * 2048 + h * 64 + pb * 16 + fr] = f2bf(val);
      }
}

// ---------- fallback: sequential scan on new layouts ----------
__launch_bounds__(256)
__global__ void k_scan(const u16* __restrict__ XT, const u16* __restrict__ BCtok,
                       const float* __restrict__ DTt, const float* __restrict__ DECt,
                       const float* __restrict__ Dp, u16* __restrict__ y) {
  const int ps = blockIdx.x, h = blockIdx.y, b = blockIdx.z;
  const int tid = threadIdx.x;
  const int tsub = tid & 15, pl = tid >> 4;
  const int p = ps * 16 + pl;
  const u16* xp = XT + ((size_t)(b * 2048 + h * 64 + p)) * 4096;
  const float* dth = DTt + (size_t)(b * 32 + h) * 4096;
  const float* dch = DECt + (size_t)(b * 32 + h) * 4096;
  u16* yp = y + (size_t)b * 4096 * 2048 + h * 64 + p;
  const float Dh = Dp[h];
  float s0 = 0, s1 = 0, s2 = 0, s3 = 0, s4 = 0, s5 = 0, s6 = 0, s7 = 0;
  for (int tau = 0; tau < 4096; ++tau) {
    const u16* bcr = BCtok + ((size_t)(b * 4096 + tau)) * 256;
    uint4 vB = *(const uint4*)(bcr + tsub * 8);
    uint4 vC = *(const uint4*)(bcr + 128 + tsub * 8);
    float xv = bf2f(xp[tau]);
    float a = dth[tau] * xv;
    float dcv = dch[tau];
    s0 = s0 * dcv + a * bf2f((u16)(vB.x & 0xFFFF)); s1 = s1 * dcv + a * bf2f((u16)(vB.x >> 16));
    s2 = s2 * dcv + a * bf2f((u16)(vB.y & 0xFFFF)); s3 = s3 * dcv + a * bf2f((u16)(vB.y >> 16));
    s4 = s4 * dcv + a * bf2f((u16)(vB.z & 0xFFFF)); s5 = s5 * dcv + a * bf2f((u16)(vB.z >> 16));
    s6 = s6 * dcv + a * bf2f((u16)(vB.w & 0xFFFF)); s7 = s7 * dcv + a * bf2f((u16)(vB.w >> 16));
    float sum = s0 * bf2f((u16)(vC.x & 0xFFFF)) + s1 * bf2f((u16)(vC.x >> 16))
              + s2 * bf2f((u16)(vC.y & 0xFFFF)) + s3 * bf2f((u16)(vC.y >> 16))
              + s4 * bf2f((u16)(vC.z & 0xFFFF)) + s5 * bf2f((u16)(vC.z >> 16))
              + s6 * bf2f((u16)(vC.w & 0xFFFF)) + s7 * bf2f((u16)(vC.w >> 16));
    sum += __shfl_xor(sum, 1, 64);
    sum += __shfl_xor(sum, 2, 64);
    sum += __shfl_xor(sum, 4, 64);
    sum += __shfl_xor(sum, 8, 64);
    if (tsub == 0) yp[(size_t)tau * 2048] = f2bf(sum + Dh * xv);
  }
}

// ---------- gated RMSNorm (vectorized: uint4 loads, thread owns 8 channels) ----------
__global__ void k_gate(const u16* __restrict__ y, const u16* __restrict__ zx,
                       const float* __restrict__ normw, u16* __restrict__ u, int flip) {
  const int m = blockIdx.x, tid = threadIdx.x;
  const int ms = flip ? (m ^ 4095) : m;
  uint4 yv = *(const uint4*)(y + (size_t)m * 2048 + tid * 8);
  uint4 zv = *(const uint4*)(zx + (size_t)ms * 4480 + tid * 8);
  const u16* yp = (const u16*)&yv;
  const u16* zp = (const u16*)&zv;
  float vals[8];
  float ss = 0.f;
  #pragma unroll
  for (int i = 0; i < 8; i++) {
    float zf = bf2f(zp[i]);
    float wv = bf2f(yp[i]) * (zf / (1.f + __expf(-zf)));
    vals[i] = wv;
    ss += wv * wv;
  }
  float rs = rsqrtf(block_sum256(ss) * (1.f / 2048.f) + 1e-5f);
  float4 n0 = *(const float4*)(normw + tid * 8);
  float4 n1 = *(const float4*)(normw + tid * 8 + 4);
  uint4 o;
  o.x = pk2(vals[0] * rs * n0.x, vals[1] * rs * n0.y);
  o.y = pk2(vals[2] * rs * n0.z, vals[3] * rs * n0.w);
  o.z = pk2(vals[4] * rs * n1.x, vals[5] * rs * n1.y);
  o.w = pk2(vals[6] * rs * n1.z, vals[7] * rs * n1.w);
  *(uint4*)(u + (size_t)m * 2048 + tid * 8) = o;
}

// ---------- final LN + residual (bf16 input) ----------
__global__ void k_final(const u16* __restrict__ t2, const float* __restrict__ bias,
                        const float* __restrict__ g, const float* __restrict__ bb,
                        const float* __restrict__ x, float* __restrict__ out) {
  const int row = blockIdx.x, tid = threadIdx.x;
  uint32_t v = *(const uint32_t*)(t2 + (size_t)row * 512 + tid * 2);
  float v0 = bf2f((u16)(v & 0xFFFF)) + bias[tid * 2];
  float v1 = bf2f((u16)(v >> 16)) + bias[tid * 2 + 1];
  float mean = block_sum256(v0 + v1) * (1.f / 512.f);
  float d0 = v0 - mean, d1 = v1 - mean;
  float var = block_sum256(d0 * d0 + d1 * d1) * (1.f / 512.f);
  float rs = rsqrtf(var + 1e-5f);
  float2 xr = ((const float2*)(x + (size_t)row * 512))[tid];
  float2 o;
  o.x = d0 * rs * g[tid * 2] + bb[tid * 2] + xr.x;
  o.y = d1 * rs * g[tid * 2 + 1] + bb[tid * 2 + 1] + xr.y;
  ((float2*)(out + (size_t)row * 512))[tid] = o;
}

extern "C" void kernel_launch(void* const* d_in, const int* in_sizes, int n_in,
                              void* d_out, int out_size, void* d_ws, size_t ws_size,
                              hipStream_t stream) {
  const float* x      = (const float*)d_in[0];
  const float* pre_w  = (const float*)d_in[1];
  const float* pre_b  = (const float*)d_in[2];
  const float* pre_g  = (const float*)d_in[3];
  const float* pre_bb = (const float*)d_in[4];
  const float* post_w = (const float*)d_in[5];
  const float* post_b = (const float*)d_in[6];
  const float* post_g = (const float*)d_in[7];
  const float* post_bb= (const float*)d_in[8];
  const float* win_[2]   = {(const float*)d_in[9],  (const float*)d_in[17]};
  const float* convw_[2] = {(const float*)d_in[10], (const float*)d_in[18]};
  const float* convb_[2] = {(const float*)d_in[11], (const float*)d_in[19]};
  const float* dtb_[2]   = {(const float*)d_in[12], (const float*)d_in[20]};
  const float* Alog_[2]  = {(const float*)d_in[13], (const float*)d_in[21]};
  const float* Dp_[2]    = {(const float*)d_in[14], (const float*)d_in[22]};
  const float* normw_[2] = {(const float*)d_in[15], (const float*)d_in[23]};
  const float* wout_[2]  = {(const float*)d_in[16], (const float*)d_in[24]};

  char* ws = (char*)d_ws;
  constexpr size_t OFF_WT_PRE  = 0;                         // 1 MB (PR aliases later)
  constexpr size_t OFF_WT_WINF = OFF_WT_PRE  + 1048576;
  constexpr size_t OFF_WT_WINB = OFF_WT_WINF + 9175040;
  constexpr size_t OFF_WT_WOF  = OFF_WT_WINB + 9175040;
  constexpr size_t OFF_WT_WOB  = OFF_WT_WOF  + 4194304;
  constexpr size_t OFF_WT_POST = OFF_WT_WOB  + 4194304;
  constexpr size_t OFF_HPRE    = OFF_WT_POST + 1048576;     // 16 MB
  constexpr size_t OFF_ZX      = OFF_HPRE + 16777216;       // 70 MB
  constexpr size_t OFF_XT      = OFF_ZX + 73400320;         // 32 MB: XT [2][2048][4096] bf16
  constexpr size_t OFF_BC      = OFF_XT + 33554432;         // 4 MB BCtok + 4 MB BCT
  constexpr size_t OFF_DT      = OFF_BC + 8388608;          // 1 MB DT_T
  constexpr size_t OFF_DEC     = OFF_DT + 1048576;          // 1 MB DEC_T
  constexpr size_t OFF_Y       = OFF_DEC + 1048576;         // 16 MB bf16 y
  constexpr size_t OFF_S       = OFF_Y + 33554432;          // 32 MB (bf16 S uses half)
  constexpr size_t OFF_HB      = OFF_S + 33554432;          // 32 MB (bf16 HB uses half)
  constexpr size_t ARENA_END   = OFF_HB + 33554432;         // == 263716864

  u16* WtPre    = (u16*)(ws + OFF_WT_PRE);
  u16* WtWin[2] = {(u16*)(ws + OFF_WT_WINF), (u16*)(ws + OFF_WT_WINB)};
  u16* WtWo[2]  = {(u16*)(ws + OFF_WT_WOF),  (u16*)(ws + OFF_WT_WOB)};
  u16* WtPost   = (u16*)(ws + OFF_WT_POST);
  u16* HPRE = (u16*)(ws + OFF_HPRE);
  u16* ZX   = (u16*)(ws + OFF_ZX);
  u16* XT   = (u16*)(ws + OFF_XT);
  u16* BCtok= (u16*)(ws + OFF_BC);
  u16* BCT  = (u16*)(ws + OFF_BC + 4194304);
  float* DTt = (float*)(ws + OFF_DT);
  float* DECt= (float*)(ws + OFF_DEC);
  u16*  Y   = (u16*)(ws + OFF_Y);
  u16*  Sb  = (u16*)(ws + OFF_S);          // bf16 wout_f intermediate
  u16*  HB  = (u16*)(ws + OFF_HB);         // bf16 chunk states
  // aliases
  float* PRb  = (float*)(ws + OFF_WT_PRE); // 4 KB (WtPre dead after pre-GEMM)
  u16*   XBF  = (u16*)(ws + OFF_Y);        // bf16 x for pre-GEMM
  u16*   TMPb = (u16*)(ws + OFF_S);        // pre-GEMM bf16 out (before Sb written)
  u16*   U    = (u16*)(ws + OFF_XT);       // gated y bf16 (XT dead after ssd_c)
  u16*   U2   = ZX;                        // final gated sum (ZX dead)
  u16*   TMP2b= (u16*)(ws + OFF_XT);       // post-GEMM bf16 out (U dead)

  const bool chunked = (ws_size >= ARENA_END);

  dim3 tb(32, 8);
  k_tcast<<<dim3(32, 16),  tb, 0, stream>>>(pre_w,   WtPre,    512, 1024, 1024);
  k_tcast<<<dim3(140, 32), tb, 0, stream>>>(win_[0], WtWin[0], 1024, 4384, 4480);
  k_tcast<<<dim3(140, 32), tb, 0, stream>>>(win_[1], WtWin[1], 1024, 4384, 4480);
  k_tcast<<<dim3(32, 64),  tb, 0, stream>>>(wout_[0], WtWo[0], 2048, 1024, 1024);
  k_tcast<<<dim3(32, 64),  tb, 0, stream>>>(wout_[1], WtWo[1], 2048, 1024, 1024);
  k_tcast<<<dim3(16, 32),  tb, 0, stream>>>(post_w,  WtPost,   1024,  512,  512);
  k_cast<<<4096, 256, 0, stream>>>(x, XBF, 1048576);
  k_gemm<<<dim3(64, 8), 256, 0, stream>>>(XBF, WtPre, nullptr, TMPb, nullptr, nullptr,
                                          8192, 1024, 512, 1024, 1);
  k_preln<<<8192, 256, 0, stream>>>(TMPb, pre_b, pre_g, pre_bb, HPRE);

  for (int d = 0; d < 2; d++) {
    int flip = d;
    k_gemm256<<<dim3(32, 18), 512, 0, stream>>>(HPRE, WtWin[d], ZX);
    k_dt2<<<dim3(16, 32, 2), 256, 0, stream>>>(ZX, dtb_[d], Alog_[d], DTt, DECt, flip);
    k_conv2<<<dim3(36, 64, 2), 256, 0, stream>>>(ZX, convw_[d], convb_[d], XT, BCtok, BCT, flip);
    if (chunked) {
      k_ssd_a<<<dim3(NCH, 32, 2), 512, 0, stream>>>(XT, BCT, DTt, Alog_[d], HB, PRb);
      k_scan_b<<<dim3(32, 32, 2), 256, 0, stream>>>(HB, PRb);
      k_ssd_c<<<dim3(NCH, 32, 2), 512, 0, stream>>>(BCtok, XT, DTt, HB, Alog_[d], Dp_[d], Y);
    } else {
      k_scan<<<dim3(4, 32, 2), 256, 0, stream>>>(XT, BCtok, DTt, DECt, Dp_[d], Y);
    }
    k_gate<<<8192, 256, 0, stream>>>(Y, ZX, normw_[d], U, flip);
    // d=0: bf16 out to Sb. d=1: accumulate bf16 Sb + fused u2 (silu(HPRE)) -> bf16 U2.
    if (d == 0) {
      k_gemm<<<dim3(64, 8), 256, 0, stream>>>(U, WtWo[d], nullptr, Sb, nullptr, nullptr,
                                              8192, 1024, 2048, 1024, 1);
    } else {
      k_gemm<<<dim3(64, 8), 256, 0, stream>>>(U, WtWo[d], nullptr, U2, HPRE, Sb,
                                              8192, 1024, 2048, 1024, 1 | 4 | 8 | 16);
    }
  }

  k_gemm<<<dim3(64, 4), 256, 0, stream>>>(U2, WtPost, nullptr, TMP2b, nullptr, nullptr,
                                          8192, 512, 1024, 512, 1);
  k_final<<<8192, 256, 0, stream>>>(TMP2b, post_b, post_g, post_bb, x, (float*)d_out);
}

// Round 20
// 678.348 us; speedup vs baseline: 1.1504x; 1.0026x over previous
//
#include <hip/hip_runtime.h>
#include <stdint.h>

typedef unsigned short u16;
typedef __attribute__((ext_vector_type(8))) short short8;
typedef __attribute__((ext_vector_type(4))) float f32x4;

__device__ __forceinline__ float bf2f(u16 u) {
  union { float f; uint32_t i; } v; v.i = ((uint32_t)u) << 16; return v.f;
}
__device__ __forceinline__ u16 f2bf(float f) {
  union { float f; uint32_t i; } v; v.f = f;
  uint32_t r = v.i + 0x7FFFu + ((v.i >> 16) & 1u);
  return (u16)(r >> 16);
}
__device__ __forceinline__ uint32_t pk2(float a, float b) {
  return (uint32_t)f2bf(a) | ((uint32_t)f2bf(b) << 16);
}
// async global->LDS, 16B per lane; LDS dest is wave-uniform base + lane*16
__device__ __forceinline__ void gload16(const u16* g, u16* l) {
  __builtin_amdgcn_global_load_lds(
      (const __attribute__((address_space(1))) unsigned int*)g,
      (__attribute__((address_space(3))) unsigned int*)l, 16, 0, 0);
}

__device__ __forceinline__ float block_sum256(float v) {
  __shared__ float red[4];
  #pragma unroll
  for (int o = 1; o < 64; o <<= 1) v += __shfl_xor(v, o, 64);
  int lane = threadIdx.x & 63, w = threadIdx.x >> 6;
  __syncthreads();
  if (lane == 0) red[w] = v;
  __syncthreads();
  return red[0] + red[1] + red[2] + red[3];
}

// ---------- W[K][N] f32 -> Wt[Npad][K] bf16 (zero-pad rows >= N) ----------
__global__ void k_tcast(const float* __restrict__ W, u16* __restrict__ Wt,
                        int K, int N, int Npad) {
  __shared__ float tile[32][33];
  int n0 = blockIdx.x * 32, k0 = blockIdx.y * 32;
  int tx = threadIdx.x, ty0 = threadIdx.y;
  #pragma unroll
  for (int i = 0; i < 4; i++) {
    int ty = ty0 + i * 8;
    int k = k0 + ty, n = n0 + tx;
    tile[ty][tx] = (k < K && n < N) ? W[(size_t)k * N + n] : 0.f;
  }
  __syncthreads();
  #pragma unroll
  for (int i = 0; i < 4; i++) {
    int ty = ty0 + i * 8;
    int n = n0 + ty, k = k0 + tx;
    if (n < Npad && k < K) Wt[(size_t)n * K + k] = f2bf(tile[tx][ty]);
  }
}

// ---------- f32 -> bf16 elementwise (x4) ----------
__global__ void k_cast(const float* __restrict__ in, u16* __restrict__ out, int n4) {
  int i = blockIdx.x * 256 + threadIdx.x;
  if (i >= n4) return;
  float4 v = ((const float4*)in)[i];
  uint2 o;
  o.x = pk2(v.x, v.y);
  o.y = pk2(v.z, v.w);
  ((uint2*)out)[i] = o;
}

// ---------- 128x128 bf16 MFMA GEMM (dbuf global_load_lds), general ----------
// flags: 1=bf16 out, 2=accum f32 Cf, 4=flip row, 8=fuse u2 (v *= silu(hp)),
//        16=accum bf16 ab
__launch_bounds__(256)
__global__ void k_gemm(const u16* __restrict__ A, const u16* __restrict__ Bt,
                       float* __restrict__ Cf, u16* __restrict__ Cb,
                       const u16* __restrict__ hp, const u16* __restrict__ ab,
                       int M, int N, int K, int ldc, int flags) {
  __shared__ u16 lA[2][128 * 64];
  __shared__ u16 lB[2][128 * 64];
  const int tid = threadIdx.x;
  const int lane = tid & 63;
  const int wave = tid >> 6;
  const int bm = blockIdx.x, bn = blockIdx.y;
  const int wr = wave >> 1, wc = wave & 1;
  const int fr = lane & 15, fq = lane >> 4;

  const int srow = wave * 32 + (lane >> 3);
  const int scol = ((lane & 7) ^ (srow & 7)) * 8;   // inverse-swizzled source col
  const u16* gA = A + (size_t)(bm * 128 + srow) * K + scol;
  const u16* gB = Bt + (size_t)(bn * 128 + srow) * K + scol;
  const int lofs = wave * 2048;

  f32x4 acc[4][4] = {};

  #pragma unroll
  for (int i = 0; i < 4; i++) {
    gload16(gA + (size_t)(i * 8) * K, &lA[0][lofs + i * 512]);
    gload16(gB + (size_t)(i * 8) * K, &lB[0][lofs + i * 512]);
  }
  __syncthreads();

  const int NT = K >> 6;
  for (int t = 0; t < NT; ++t) {
    const int cur = t & 1;
    if (t + 1 < NT) {
      const int kt = (t + 1) << 6;
      #pragma unroll
      for (int i = 0; i < 4; i++) {
        gload16(gA + (size_t)(i * 8) * K + kt, &lA[cur ^ 1][lofs + i * 512]);
        gload16(gB + (size_t)(i * 8) * K + kt, &lB[cur ^ 1][lofs + i * 512]);
      }
    }
    #pragma unroll
    for (int kk = 0; kk < 2; kk++) {
      short8 af[4], bfr[4];
      #pragma unroll
      for (int m = 0; m < 4; m++) {
        int row = wr * 64 + m * 16 + fr;
        int sl = (kk * 4 + fq) ^ (row & 7);
        af[m] = *(const short8*)(&lA[cur][row * 64 + sl * 8]);
      }
      #pragma unroll
      for (int n = 0; n < 4; n++) {
        int row = wc * 64 + n * 16 + fr;
        int sl = (kk * 4 + fq) ^ (row & 7);
        bfr[n] = *(const short8*)(&lB[cur][row * 64 + sl * 8]);
      }
      #pragma unroll
      for (int m = 0; m < 4; m++)
        #pragma unroll
        for (int n = 0; n < 4; n++)
          acc[m][n] = __builtin_amdgcn_mfma_f32_16x16x32_bf16(af[m], bfr[n], acc[m][n], 0, 0, 0);
    }
    __syncthreads();   // drains next-tile loads (latency hidden under compute above)
  }

  const bool bf16out = flags & 1, accum = flags & 2, flip = flags & 4, fuse = flags & 8;
  const bool accb = flags & 16;
  #pragma unroll
  for (int m = 0; m < 4; m++) {
    #pragma unroll
    for (int q = 0; q < 4; q++) {
      int rr = bm * 128 + wr * 64 + m * 16 + fq * 4 + q;
      int orow = flip ? (rr ^ 4095) : rr;
      size_t rb = (size_t)orow * ldc;
      #pragma unroll
      for (int n = 0; n < 4; n++) {
        int cc = bn * 128 + wc * 64 + n * 16 + fr;
        float v = acc[m][n][q];
        if (accum) v += Cf[rb + cc];
        if (accb) v += bf2f(ab[rb + cc]);
        if (fuse) {
          float h = bf2f(hp[rb + cc]);
          v = v * (h / (1.f + __expf(-h)));
        }
        if (bf16out) Cb[rb + cc] = f2bf(v);
        else Cf[rb + cc] = v;
      }
    }
  }
}

// ---------- 256x256 bf16 MFMA GEMM for the win projection (r11 proven) ----------
// 8 waves (2Mx4N), per-wave 128x64, BK=64, 128 KiB LDS dbuf, 2-barrier
// structure, counted vmcnt(8) at tile boundaries (never drain mid-loop).
// Fixed shape: M=8192, K=1024, N=4480 (18 N-tiles; ragged: B-row clamp + C guard).
__launch_bounds__(512)
__global__ void k_gemm256(const u16* __restrict__ A, const u16* __restrict__ Bt,
                          u16* __restrict__ Cb) {
  constexpr int K = 1024, N = 4480, NT = 16;
  __shared__ u16 lA[2][256 * 64];
  __shared__ u16 lB[2][256 * 64];
  const int tid = threadIdx.x;
  const int lane = tid & 63;
  const int wid = tid >> 6;
  const int bm = blockIdx.x, bn = blockIdx.y;
  const int wr = wid >> 2, wc = wid & 3;       // 2 x 4 waves
  const int fr = lane & 15, fq = lane >> 4;

  const int srow = tid >> 3;                    // 0..63
  const int scol = ((tid & 7) ^ (srow & 7)) * 8;
  const u16* gA[4];
  const u16* gB[4];
  #pragma unroll
  for (int i = 0; i < 4; i++) {
    int arow = bm * 256 + i * 64 + srow;
    gA[i] = A + (size_t)arow * K + scol;
    int brow = bn * 256 + i * 64 + srow;
    if (brow > N - 1) brow = N - 1;             // ragged-N clamp (cols guarded at C)
    gB[i] = Bt + (size_t)brow * K + scol;
  }

  f32x4 acc[8][4] = {};

  auto stage = [&](int u) {
    const int buf = u & 1, kt = u << 6;
    #pragma unroll
    for (int i = 0; i < 4; i++)
      gload16(gA[i] + kt, &lA[buf][i * 4096 + tid * 8]);
    #pragma unroll
    for (int i = 0; i < 4; i++)
      gload16(gB[i] + kt, &lB[buf][i * 4096 + tid * 8]);
  };

  // prologue: tiles 0,1 in flight; wait tile 0 only (8 newest stay pending)
  stage(0);
  stage(1);
  asm volatile("s_waitcnt vmcnt(8)" ::: "memory");
  __builtin_amdgcn_s_barrier();

  for (int t = 0; t < NT; ++t) {
    const u16* bufA = &lA[t & 1][0];
    const u16* bufB = &lB[t & 1][0];
    #pragma unroll
    for (int kk = 0; kk < 2; kk++) {
      short8 af[8], bfm[4];
      #pragma unroll
      for (int m = 0; m < 8; m++) {
        int row = wr * 128 + m * 16 + fr;
        int sl = (kk * 4 + fq) ^ (row & 7);
        af[m] = *(const short8*)(&bufA[row * 64 + sl * 8]);
      }
      #pragma unroll
      for (int n = 0; n < 4; n++) {
        int row = wc * 64 + n * 16 + fr;
        int sl = (kk * 4 + fq) ^ (row & 7);
        bfm[n] = *(const short8*)(&bufB[row * 64 + sl * 8]);
      }
      #pragma unroll
      for (int m = 0; m < 8; m++)
        #pragma unroll
        for (int n = 0; n < 4; n++)
          acc[m][n] = __builtin_amdgcn_mfma_f32_16x16x32_bf16(af[m], bfm[n], acc[m][n], 0, 0, 0);
    }
    // boundary: buf[t&1] dead -> stage t+2 there; counted wait: t+1 landed,
    // t+2's 8 loads stay in flight (never drain to 0 mid-loop)
    __builtin_amdgcn_s_barrier();
    if (t + 2 < NT) {
      stage(t + 2);
      asm volatile("s_waitcnt vmcnt(8)" ::: "memory");
    } else {
      asm volatile("s_waitcnt vmcnt(0)" ::: "memory");
    }
    __builtin_amdgcn_s_barrier();
  }

  #pragma unroll
  for (int m = 0; m < 8; m++) {
    #pragma unroll
    for (int q = 0; q < 4; q++) {
      size_t rb = (size_t)(bm * 256 + wr * 128 + m * 16 + fq * 4 + q) * N;
      #pragma unroll
      for (int n = 0; n < 4; n++) {
        int cc = bn * 256 + wc * 64 + n * 16 + fr;
        if (cc < N) Cb[rb + cc] = f2bf(acc[m][n][q]);
      }
    }
  }
}

// ---------- pre-LN (bf16 input) ----------
__global__ void k_preln(const u16* __restrict__ t, const float* __restrict__ bias,
                        const float* __restrict__ g, const float* __restrict__ bb,
                        u16* __restrict__ out) {
  const int row = blockIdx.x, tid = threadIdx.x;
  uint2 v = *(const uint2*)(t + (size_t)row * 1024 + tid * 4);
  float4 bi = ((const float4*)bias)[tid];
  float v0 = bf2f((u16)(v.x & 0xFFFF)) + bi.x;
  float v1 = bf2f((u16)(v.x >> 16)) + bi.y;
  float v2 = bf2f((u16)(v.y & 0xFFFF)) + bi.z;
  float v3 = bf2f((u16)(v.y >> 16)) + bi.w;
  float mean = block_sum256(v0 + v1 + v2 + v3) * (1.f / 1024.f);
  float d0 = v0 - mean, d1 = v1 - mean, d2 = v2 - mean, d3 = v3 - mean;
  float var = block_sum256(d0 * d0 + d1 * d1 + d2 * d2 + d3 * d3) * (1.f / 1024.f);
  float rs = rsqrtf(var + 1e-5f);
  float4 gg = ((const float4*)g)[tid];
  float4 bv = ((const float4*)bb)[tid];
  uint2 o;
  o.x = pk2(d0 * rs * gg.x + bv.x, d1 * rs * gg.y + bv.y);
  o.y = pk2(d2 * rs * gg.z + bv.z, d3 * rs * gg.w + bv.w);
  ((uint2*)(out + (size_t)row * 1024))[tid] = o;
}

// ---------- dt/dec in [b][h][t] (flipped-domain) layout ----------
// wdec: write DECt only when the fallback scan needs it
__global__ void k_dt2(const u16* __restrict__ zx, const float* __restrict__ dtb,
                      const float* __restrict__ Alog, float* __restrict__ DTt,
                      float* __restrict__ DECt, int flip, int wdec) {
  int t = blockIdx.x * 256 + threadIdx.x;
  int h = blockIdx.y, b = blockIdx.z;
  int ts = flip ? 4095 - t : t;
  float raw = bf2f(zx[(size_t)((b << 12) + ts) * 4480 + 4352 + h]) + dtb[h];
  float d = (raw > 20.f) ? raw : log1pf(__expf(raw));
  size_t o = (size_t)(b * 32 + h) * 4096 + t;
  DTt[o] = d;
  if (wdec) DECt[o] = __expf(-__expf(Alog[h]) * d);
}

// ---------- conv(K=4)+silu; vectorized I/O; outputs XT [b][2048][4096],
// ---------- BCtok [m][256] bf16, BCT [b][256][4096] (flipped-domain) ----------
__global__ void k_conv2(const u16* __restrict__ zx, const float* __restrict__ cw,
                        const float* __restrict__ cb, u16* __restrict__ XT,
                        u16* __restrict__ BCtok, u16* __restrict__ BCT, int flip) {
  const int ct = blockIdx.x;           // 0..35 channel tile (64)
  const int tt = blockIdx.y;           // 0..63 token tile (64)
  const int b = blockIdx.z;
  const int tid = threadIdx.x;         // 256
  __shared__ float sin_[67][64];
  __shared__ float sout[64][65];
  const int ch0 = ct * 64, t0 = tt * 64;

  // staging: uint2 = 4 ch/thread; 67 rows x 16 quads
  for (int i = tid; i < 67 * 16; i += 256) {
    int r = i >> 4, c4 = (i & 15) << 2;
    int tok = t0 - 3 + r;
    float f0 = 0.f, f1 = 0.f, f2 = 0.f, f3 = 0.f;
    if (tok >= 0) {
      int src = (b << 12) + (flip ? 4095 - tok : tok);
      uint2 v = *(const uint2*)(zx + (size_t)src * 4480 + 2048 + ch0 + c4);
      f0 = bf2f((u16)(v.x & 0xFFFF)); f1 = bf2f((u16)(v.x >> 16));
      f2 = bf2f((u16)(v.y & 0xFFFF)); f3 = bf2f((u16)(v.y >> 16));
    }
    sin_[r][c4] = f0; sin_[r][c4 + 1] = f1; sin_[r][c4 + 2] = f2; sin_[r][c4 + 3] = f3;
  }
  __syncthreads();

  const int ch = tid & 63, g = tid >> 6;
  const int chg = ch0 + ch;
  float4 wv = *(const float4*)(cw + (size_t)chg * 4);
  float bias = cb[chg];
  #pragma unroll
  for (int i = 0; i < 16; i++) {
    int tl = g * 16 + i;
    float a = bias + wv.x * sin_[tl][ch] + wv.y * sin_[tl + 1][ch]
                   + wv.z * sin_[tl + 2][ch] + wv.w * sin_[tl + 3][ch];
    sout[tl][ch] = a / (1.f + __expf(-a));
  }
  __syncthreads();

  if (ch0 < 2048) {
    for (int i = tid; i < 64 * 16; i += 256) {
      int chw = i >> 4, t4 = (i & 15) << 2;
      uint2 o;
      o.x = pk2(sout[t4][chw], sout[t4 + 1][chw]);
      o.y = pk2(sout[t4 + 2][chw], sout[t4 + 3][chw]);
      *(uint2*)(XT + ((size_t)(b * 2048 + ch0 + chw)) * 4096 + t0 + t4) = o;
    }
  } else {
    int c2b = (ct - 32) * 64;
    for (int i = tid; i < 64 * 16; i += 256) {
      int chw = i >> 4, t4 = (i & 15) << 2;
      uint2 o;
      o.x = pk2(sout[t4][chw], sout[t4 + 1][chw]);
      o.y = pk2(sout[t4 + 2][chw], sout[t4 + 3][chw]);
      *(uint2*)(BCT + ((size_t)(b * 256 + c2b + chw)) * 4096 + t0 + t4) = o;
    }
    for (int i = tid; i < 64 * 8; i += 256) {
      int r = i >> 3, c8 = (i & 7) << 3;
      uint4 o;
      o.x = pk2(sout[r][c8], sout[r][c8 + 1]);
      o.y = pk2(sout[r][c8 + 2], sout[r][c8 + 3]);
      o.z = pk2(sout[r][c8 + 4], sout[r][c8 + 5]);
      o.w = pk2(sout[r][c8 + 6], sout[r][c8 + 7]);
      *(uint4*)(BCtok + ((size_t)(b * 4096 + t0 + r)) * 256 + c2b + c8) = o;
    }
  }
}

// ================= SSD chunked scan, Q=256, NCH=16 =================
#define NCH 16
#define SWZ(row, oct, msk) (((oct) ^ ((row) & (msk))) << 4)

// inclusive cumsum helper over 256 threads (first 4 waves), returns L for tid<256
__device__ __forceinline__ void cumsum256(int tid, int lane, float adt, float dtv,
                                          float* sL, float* sdt, float* spart) {
  float v = adt;
  if (tid < 256) {
    #pragma unroll
    for (int o = 1; o < 64; o <<= 1) {
      float t = __shfl_up(v, o, 64);
      if (lane >= o) v += t;
    }
    if (lane == 63) spart[tid >> 6] = v;
  }
  __syncthreads();
  if (tid < 256) {
    int w = tid >> 6;
    float off = 0.f;
    #pragma unroll
    for (int j = 0; j < 3; j++) if (j < w) off += spart[j];
    sL[tid] = v + off;
    sdt[tid] = dtv;
  }
}

// pass A: H_localT[p][n] = sum_tau w_tau * X[tau][p] * B[tau][n]; HB bf16
__launch_bounds__(512, 1)
__global__ void k_ssd_a(const u16* __restrict__ XT, const u16* __restrict__ BCT,
                        const float* __restrict__ DTt, const float* __restrict__ Alog,
                        u16* __restrict__ HB, float* __restrict__ PR) {
  const int c = blockIdx.x, h = blockIdx.y, b = blockIdx.z;
  const int tid = threadIdx.x;
  const int lane = tid & 63, w = tid >> 6;
  const int fr = lane & 15, fq = lane >> 4;
  const int bh = b * 32 + h;

  __shared__ u16 sX[64 * 256];      // [p][tau], 32 oct/row, swz ^(p&15)
  __shared__ u16 sBW[128 * 256];    // [n][tau], 32 oct/row, swz ^(n&15)
  __shared__ float sL[256], sdt[256], sw_[256], spart[4];

  float dtv = 0.f;
  if (tid < 256) dtv = DTt[(size_t)bh * 4096 + c * 256 + tid];
  float expA = __expf(Alog[h]);
  cumsum256(tid, lane, -expA * dtv, dtv, sL, sdt, spart);
  __syncthreads();
  if (tid < 256) sw_[tid] = __expf(sL[255] - sL[tid]) * sdt[tid];
  for (int i = tid; i < 2048; i += 512) {
    int p = i >> 5, oct = i & 31;
    uint4 v = *(const uint4*)(XT + ((size_t)(b * 2048 + h * 64 + p) << 12) + c * 256 + oct * 8);
    *(uint4*)((char*)sX + p * 512 + SWZ(p, oct, 15)) = v;
  }
  __syncthreads();
  for (int i = tid; i < 4096; i += 512) {
    int n = i >> 5, oct = i & 31;
    uint4 v = *(const uint4*)(BCT + ((size_t)(b * 256 + n) << 12) + c * 256 + oct * 8);
    const float* swp = sw_ + oct * 8;
    float f0 = bf2f((u16)(v.x & 0xFFFF)) * swp[0];
    float f1 = bf2f((u16)(v.x >> 16)) * swp[1];
    float f2 = bf2f((u16)(v.y & 0xFFFF)) * swp[2];
    float f3 = bf2f((u16)(v.y >> 16)) * swp[3];
    float f4 = bf2f((u16)(v.z & 0xFFFF)) * swp[4];
    float f5 = bf2f((u16)(v.z >> 16)) * swp[5];
    float f6 = bf2f((u16)(v.w & 0xFFFF)) * swp[6];
    float f7 = bf2f((u16)(v.w >> 16)) * swp[7];
    uint4 o;
    o.x = pk2(f0, f1); o.y = pk2(f2, f3); o.z = pk2(f4, f5); o.w = pk2(f6, f7);
    *(uint4*)((char*)sBW + n * 512 + SWZ(n, oct, 15)) = o;
  }
  __syncthreads();

  const int pb = w >> 1, nh = w & 1;
  f32x4 acc[4] = {};
  #pragma unroll
  for (int ks = 0; ks < 8; ks++) {
    int p = pb * 16 + fr;
    short8 af = *(const short8*)((char*)sX + p * 512 + SWZ(p, ks * 4 + fq, 15));
    #pragma unroll
    for (int nb = 0; nb < 4; nb++) {
      int n = nh * 64 + nb * 16 + fr;
      short8 bfm = *(const short8*)((char*)sBW + n * 512 + SWZ(n, ks * 4 + fq, 15));
      acc[nb] = __builtin_amdgcn_mfma_f32_16x16x32_bf16(af, bfm, acc[nb], 0, 0, 0);
    }
  }
  u16* hb = HB + (size_t)(bh * NCH + c) * 8192;
  #pragma unroll
  for (int nb = 0; nb < 4; nb++)
    #pragma unroll
    for (int q = 0; q < 4; q++) {
      int p = pb * 16 + fq * 4 + q;
      int n = nh * 64 + nb * 16 + fr;
      hb[p * 128 + n] = f2bf(acc[nb][q]);
    }
  if (tid == 0) PR[bh * NCH + c] = __expf(sL[255]);
}

// pass B: sequential combine over chunk boundaries (bf16 storage, f32 carry).
// All 16 loads issued upfront (independent -> one latency), then carry chain.
__global__ void k_scan_b(u16* __restrict__ HB, const float* __restrict__ PR) {
  const int eb = blockIdx.x, h = blockIdx.y, b = blockIdx.z;
  const int e = eb * 256 + threadIdx.x;
  const int bh = b * 32 + h;
  u16* base = HB + (size_t)bh * NCH * 8192 + e;
  const float* pr = PR + bh * NCH;
  float v[NCH];
  #pragma unroll
  for (int c = 0; c < NCH; ++c) v[c] = bf2f(base[(size_t)c * 8192]);
  float carry = 0.f;
  #pragma unroll
  for (int c = 0; c < NCH; ++c) {
    base[(size_t)c * 8192] = f2bf(carry);
    carry = pr[c] * carry + v[c];
  }
}

// pass C: y = (M.(C B^T)) X + exp(L_t) (C Hin) ; D-term added to P diag AFTER *G
// SIMD-balanced wave->t-block map: tb = w<4 ? w : 11-w pairs causal costs
// (1+4),(1+4),(2+3),(2+3) on the 4 SIMDs (waves s,s+4 co-resident) -> 5 each.
__launch_bounds__(512, 1)
__global__ void k_ssd_c(const u16* __restrict__ BCtok, const u16* __restrict__ XT,
                        const float* __restrict__ DTt, const u16* __restrict__ HB,
                        const float* __restrict__ Alog, const float* __restrict__ Dp,
                        u16* __restrict__ Y) {
  const int c = blockIdx.x, h = blockIdx.y, b = blockIdx.z;
  const int tid = threadIdx.x;
  const int lane = tid & 63, w = tid >> 6;
  const int tb = (w < 4) ? w : 11 - w;        // balanced t-block assignment
  const int fr = lane & 15, fq = lane >> 4;
  const int bh = b * 32 + h;
  const size_t m0 = (size_t)b * 4096 + c * 256;

  __shared__ u16 sB[256 * 128];     // [tau][n], 16 oct/row, swz ^(tau&15)
  __shared__ u16 sX[64 * 256];      // [p][tau], 32 oct/row, swz ^(p&15)
  __shared__ u16 sH[64 * 128];      // [p][n],  16 oct/row, swz ^(p&15)
  __shared__ u16 sP[8 * 32 * 64];   // per-wave [32t][64tau], 8 oct/row, swz ^(t&7)
  __shared__ float sL[256], sdt[256], spart[4];

  float dtv = 0.f;
  if (tid < 256) dtv = DTt[(size_t)bh * 4096 + c * 256 + tid];
  float expA = __expf(Alog[h]);
  cumsum256(tid, lane, -expA * dtv, dtv, sL, sdt, spart);

  for (int i = tid; i < 4096; i += 512) {
    int tr = i >> 4, oct = i & 15;
    uint4 v = *(const uint4*)(BCtok + ((m0 + tr) << 8) + oct * 8);
    *(uint4*)((char*)sB + tr * 256 + SWZ(tr, oct, 15)) = v;
  }
  for (int i = tid; i < 2048; i += 512) {
    int p = i >> 5, oct = i & 31;
    uint4 v = *(const uint4*)(XT + ((size_t)(b * 2048 + h * 64 + p) << 12) + c * 256 + oct * 8);
    *(uint4*)((char*)sX + p * 512 + SWZ(p, oct, 15)) = v;
  }
  for (int i = tid; i < 1024; i += 512) {
    int p = i >> 4, oct = i & 15;
    uint4 v = *(const uint4*)(HB + (size_t)(bh * NCH + c) * 8192 + p * 128 + oct * 8);
    *(uint4*)((char*)sH + p * 256 + SWZ(p, oct, 15)) = v;
  }
  // C A-fragments (reused by G and Yoff): rows t = tb*32+m*16+fr, ch 128+k
  short8 cf[2][4];
  #pragma unroll
  for (int m = 0; m < 2; m++)
    #pragma unroll
    for (int ks = 0; ks < 4; ks++)
      cf[m][ks] = *(const short8*)(BCtok + ((m0 + tb * 32 + m * 16 + fr) << 8) + 128 + ks * 32 + fq * 8);
  __syncthreads();

  float Lt[2][4], eLt[2][4];
  #pragma unroll
  for (int m = 0; m < 2; m++)
    #pragma unroll
    for (int q = 0; q < 4; q++) {
      Lt[m][q] = sL[tb * 32 + m * 16 + fq * 4 + q];
      eLt[m][q] = __expf(Lt[m][q]);
    }
  const float Dh = Dp[h];

  f32x4 accY[2][4] = {};
  u16* pw = sP + w * 2048;
  const int ntl = (tb >> 1) + 1;
  for (int tt = 0; tt < ntl; tt++) {
    const int t0 = tt * 64;
    f32x4 g[2][4] = {};
    #pragma unroll
    for (int ks = 0; ks < 4; ks++) {
      short8 bfm[4];
      #pragma unroll
      for (int nb = 0; nb < 4; nb++) {
        int tr = t0 + nb * 16 + fr;
        bfm[nb] = *(const short8*)((char*)sB + tr * 256 + SWZ(tr, ks * 4 + fq, 15));
      }
      #pragma unroll
      for (int m = 0; m < 2; m++)
        #pragma unroll
        for (int nb = 0; nb < 4; nb++)
          g[m][nb] = __builtin_amdgcn_mfma_f32_16x16x32_bf16(cf[m][ks], bfm[nb], g[m][nb], 0, 0, 0);
    }
    // mask * G -> P (bf16, per-wave LDS); D added to diag AFTER multiplying by G
    #pragma unroll
    for (int nb = 0; nb < 4; nb++) {
      int tau = t0 + nb * 16 + fr;
      float Ltau = sL[tau], dtau = sdt[tau];
      #pragma unroll
      for (int m = 0; m < 2; m++) {
        #pragma unroll
        for (int q = 0; q < 4; q++) {
          int t = tb * 32 + m * 16 + fq * 4 + q;
          float mask = (tau > t) ? 0.f : __expf(Lt[m][q] - Ltau) * dtau;
          float pv = mask * g[m][nb][q];
          pv = (tau == t) ? pv + Dh : pv;
          int tl = m * 16 + fq * 4 + q, taul = nb * 16 + fr;
          *(u16*)((char*)pw + tl * 128 + ((((taul) >> 3) ^ (tl & 7)) << 4) + (taul & 7) * 2) = f2bf(pv);
        }
      }
    }
    // P @ X
    #pragma unroll
    for (int ks = 0; ks < 2; ks++) {
      short8 pf[2], xf[4];
      #pragma unroll
      for (int m = 0; m < 2; m++) {
        int tl = m * 16 + fr;
        pf[m] = *(const short8*)((char*)pw + tl * 128 + (((ks * 4 + fq) ^ (tl & 7)) << 4));
      }
      #pragma unroll
      for (int pb = 0; pb < 4; pb++) {
        int p = pb * 16 + fr;
        int oct = (t0 >> 3) + ks * 4 + fq;
        xf[pb] = *(const short8*)((char*)sX + p * 512 + SWZ(p, oct, 15));
      }
      #pragma unroll
      for (int m = 0; m < 2; m++)
        #pragma unroll
        for (int pb = 0; pb < 4; pb++)
          accY[m][pb] = __builtin_amdgcn_mfma_f32_16x16x32_bf16(pf[m], xf[pb], accY[m][pb], 0, 0, 0);
    }
  }
  // Yoff = C @ HinT
  f32x4 accO[2][4] = {};
  #pragma unroll
  for (int ks = 0; ks < 4; ks++) {
    short8 hf[4];
    #pragma unroll
    for (int pb = 0; pb < 4; pb++) {
      int p = pb * 16 + fr;
      hf[pb] = *(const short8*)((char*)sH + p * 256 + SWZ(p, ks * 4 + fq, 15));
    }
    #pragma unroll
    for (int m = 0; m < 2; m++)
      #pragma unroll
      for (int pb = 0; pb < 4; pb++)
        accO[m][pb] = __builtin_amdgcn_mfma_f32_16x16x32_bf16(cf[m][ks], hf[pb], accO[m][pb], 0, 0, 0);
  }
  #pragma unroll
  for (int m = 0; m < 2; m++)
    #pragma unroll
    for (int pb = 0; pb < 4; pb++)
      #pragma unroll
      for (int q = 0; q < 4; q++) {
        int t = tb * 32 + m * 16 + fq * 4 + q;
        float val = accY[m][pb][q] + eLt[m][q] * accO[m][pb][q];
        Y[(m0 + t) * 2048 + h * 64 + pb * 16 + fr] = f2bf(val);
      }
}

// ---------- fallback: sequential scan on new layouts ----------
__launch_bounds__(256)
__global__ void k_scan(const u16* __restrict__ XT, const u16* __restrict__ BCtok,
                       const float* __restrict__ DTt, const float* __restrict__ DECt,
                       const float* __restrict__ Dp, u16* __restrict__ y) {
  const int ps = blockIdx.x, h = blockIdx.y, b = blockIdx.z;
  const int tid = threadIdx.x;
  const int tsub = tid & 15, pl = tid >> 4;
  const int p = ps * 16 + pl;
  const u16* xp = XT + ((size_t)(b * 2048 + h * 64 + p)) * 4096;
  const float* dth = DTt + (size_t)(b * 32 + h) * 4096;
  const float* dch = DECt + (size_t)(b * 32 + h) * 4096;
  u16* yp = y + (size_t)b * 4096 * 2048 + h * 64 + p;
  const float Dh = Dp[h];
  float s0 = 0, s1 = 0, s2 = 0, s3 = 0, s4 = 0, s5 = 0, s6 = 0, s7 = 0;
  for (int tau = 0; tau < 4096; ++tau) {
    const u16* bcr = BCtok + ((size_t)(b * 4096 + tau)) * 256;
    uint4 vB = *(const uint4*)(bcr + tsub * 8);
    uint4 vC = *(const uint4*)(bcr + 128 + tsub * 8);
    float xv = bf2f(xp[tau]);
    float a = dth[tau] * xv;
    float dcv = dch[tau];
    s0 = s0 * dcv + a * bf2f((u16)(vB.x & 0xFFFF)); s1 = s1 * dcv + a * bf2f((u16)(vB.x >> 16));
    s2 = s2 * dcv + a * bf2f((u16)(vB.y & 0xFFFF)); s3 = s3 * dcv + a * bf2f((u16)(vB.y >> 16));
    s4 = s4 * dcv + a * bf2f((u16)(vB.z & 0xFFFF)); s5 = s5 * dcv + a * bf2f((u16)(vB.z >> 16));
    s6 = s6 * dcv + a * bf2f((u16)(vB.w & 0xFFFF)); s7 = s7 * dcv + a * bf2f((u16)(vB.w >> 16));
    float sum = s0 * bf2f((u16)(vC.x & 0xFFFF)) + s1 * bf2f((u16)(vC.x >> 16))
              + s2 * bf2f((u16)(vC.y & 0xFFFF)) + s3 * bf2f((u16)(vC.y >> 16))
              + s4 * bf2f((u16)(vC.z & 0xFFFF)) + s5 * bf2f((u16)(vC.z >> 16))
              + s6 * bf2f((u16)(vC.w & 0xFFFF)) + s7 * bf2f((u16)(vC.w >> 16));
    sum += __shfl_xor(sum, 1, 64);
    sum += __shfl_xor(sum, 2, 64);
    sum += __shfl_xor(sum, 4, 64);
    sum += __shfl_xor(sum, 8, 64);
    if (tsub == 0) yp[(size_t)tau * 2048] = f2bf(sum + Dh * xv);
  }
}

// ---------- gated RMSNorm (vectorized: uint4 loads, thread owns 8 channels) ----------
__global__ void k_gate(const u16* __restrict__ y, const u16* __restrict__ zx,
                       const float* __restrict__ normw, u16* __restrict__ u, int flip) {
  const int m = blockIdx.x, tid = threadIdx.x;
  const int ms = flip ? (m ^ 4095) : m;
  uint4 yv = *(const uint4*)(y + (size_t)m * 2048 + tid * 8);
  uint4 zv = *(const uint4*)(zx + (size_t)ms * 4480 + tid * 8);
  const u16* yp = (const u16*)&yv;
  const u16* zp = (const u16*)&zv;
  float vals[8];
  float ss = 0.f;
  #pragma unroll
  for (int i = 0; i < 8; i++) {
    float zf = bf2f(zp[i]);
    float wv = bf2f(yp[i]) * (zf / (1.f + __expf(-zf)));
    vals[i] = wv;
    ss += wv * wv;
  }
  float rs = rsqrtf(block_sum256(ss) * (1.f / 2048.f) + 1e-5f);
  float4 n0 = *(const float4*)(normw + tid * 8);
  float4 n1 = *(const float4*)(normw + tid * 8 + 4);
  uint4 o;
  o.x = pk2(vals[0] * rs * n0.x, vals[1] * rs * n0.y);
  o.y = pk2(vals[2] * rs * n0.z, vals[3] * rs * n0.w);
  o.z = pk2(vals[4] * rs * n1.x, vals[5] * rs * n1.y);
  o.w = pk2(vals[6] * rs * n1.z, vals[7] * rs * n1.w);
  *(uint4*)(u + (size_t)m * 2048 + tid * 8) = o;
}

// ---------- final LN + residual (bf16 input) ----------
__global__ void k_final(const u16* __restrict__ t2, const float* __restrict__ bias,
                        const float* __restrict__ g, const float* __restrict__ bb,
                        const float* __restrict__ x, float* __restrict__ out) {
  const int row = blockIdx.x, tid = threadIdx.x;
  uint32_t v = *(const uint32_t*)(t2 + (size_t)row * 512 + tid * 2);
  float v0 = bf2f((u16)(v & 0xFFFF)) + bias[tid * 2];
  float v1 = bf2f((u16)(v >> 16)) + bias[tid * 2 + 1];
  float mean = block_sum256(v0 + v1) * (1.f / 512.f);
  float d0 = v0 - mean, d1 = v1 - mean;
  float var = block_sum256(d0 * d0 + d1 * d1) * (1.f / 512.f);
  float rs = rsqrtf(var + 1e-5f);
  float2 xr = ((const float2*)(x + (size_t)row * 512))[tid];
  float2 o;
  o.x = d0 * rs * g[tid * 2] + bb[tid * 2] + xr.x;
  o.y = d1 * rs * g[tid * 2 + 1] + bb[tid * 2 + 1] + xr.y;
  ((float2*)(out + (size_t)row * 512))[tid] = o;
}

extern "C" void kernel_launch(void* const* d_in, const int* in_sizes, int n_in,
                              void* d_out, int out_size, void* d_ws, size_t ws_size,
                              hipStream_t stream) {
  const float* x      = (const float*)d_in[0];
  const float* pre_w  = (const float*)d_in[1];
  const float* pre_b  = (const float*)d_in[2];
  const float* pre_g  = (const float*)d_in[3];
  const float* pre_bb = (const float*)d_in[4];
  const float* post_w = (const float*)d_in[5];
  const float* post_b = (const float*)d_in[6];
  const float* post_g = (const float*)d_in[7];
  const float* post_bb= (const float*)d_in[8];
  const float* win_[2]   = {(const float*)d_in[9],  (const float*)d_in[17]};
  const float* convw_[2] = {(const float*)d_in[10], (const float*)d_in[18]};
  const float* convb_[2] = {(const float*)d_in[11], (const float*)d_in[19]};
  const float* dtb_[2]   = {(const float*)d_in[12], (const float*)d_in[20]};
  const float* Alog_[2]  = {(const float*)d_in[13], (const float*)d_in[21]};
  const float* Dp_[2]    = {(const float*)d_in[14], (const float*)d_in[22]};
  const float* normw_[2] = {(const float*)d_in[15], (const float*)d_in[23]};
  const float* wout_[2]  = {(const float*)d_in[16], (const float*)d_in[24]};

  char* ws = (char*)d_ws;
  constexpr size_t OFF_WT_PRE  = 0;                         // 1 MB (PR aliases later)
  constexpr size_t OFF_WT_WINF = OFF_WT_PRE  + 1048576;
  constexpr size_t OFF_WT_WINB = OFF_WT_WINF + 9175040;
  constexpr size_t OFF_WT_WOF  = OFF_WT_WINB + 9175040;
  constexpr size_t OFF_WT_WOB  = OFF_WT_WOF  + 4194304;
  constexpr size_t OFF_WT_POST = OFF_WT_WOB  + 4194304;
  constexpr size_t OFF_HPRE    = OFF_WT_POST + 1048576;     // 16 MB
  constexpr size_t OFF_ZX      = OFF_HPRE + 16777216;       // 70 MB
  constexpr size_t OFF_XT      = OFF_ZX + 73400320;         // 32 MB: XT [2][2048][4096] bf16
  constexpr size_t OFF_BC      = OFF_XT + 33554432;         // 4 MB BCtok + 4 MB BCT
  constexpr size_t OFF_DT      = OFF_BC + 8388608;          // 1 MB DT_T
  constexpr size_t OFF_DEC     = OFF_DT + 1048576;          // 1 MB DEC_T
  constexpr size_t OFF_Y       = OFF_DEC + 1048576;         // 16 MB bf16 y
  constexpr size_t OFF_S       = OFF_Y + 33554432;          // 32 MB (bf16 S uses half)
  constexpr size_t OFF_HB      = OFF_S + 33554432;          // 32 MB (bf16 HB uses half)
  constexpr size_t ARENA_END   = OFF_HB + 33554432;         // == 263716864

  u16* WtPre    = (u16*)(ws + OFF_WT_PRE);
  u16* WtWin[2] = {(u16*)(ws + OFF_WT_WINF), (u16*)(ws + OFF_WT_WINB)};
  u16* WtWo[2]  = {(u16*)(ws + OFF_WT_WOF),  (u16*)(ws + OFF_WT_WOB)};
  u16* WtPost   = (u16*)(ws + OFF_WT_POST);
  u16* HPRE = (u16*)(ws + OFF_HPRE);
  u16* ZX   = (u16*)(ws + OFF_ZX);
  u16* XT   = (u16*)(ws + OFF_XT);
  u16* BCtok= (u16*)(ws + OFF_BC);
  u16* BCT  = (u16*)(ws + OFF_BC + 4194304);
  float* DTt = (float*)(ws + OFF_DT);
  float* DECt= (float*)(ws + OFF_DEC);
  u16*  Y   = (u16*)(ws + OFF_Y);
  u16*  Sb  = (u16*)(ws + OFF_S);          // bf16 wout_f intermediate
  u16*  HB  = (u16*)(ws + OFF_HB);         // bf16 chunk states
  // aliases
  float* PRb  = (float*)(ws + OFF_WT_PRE); // 4 KB (WtPre dead after pre-GEMM)
  u16*   XBF  = (u16*)(ws + OFF_Y);        // bf16 x for pre-GEMM
  u16*   TMPb = (u16*)(ws + OFF_S);        // pre-GEMM bf16 out (before Sb written)
  u16*   U    = (u16*)(ws + OFF_XT);       // gated y bf16 (XT dead after ssd_c)
  u16*   U2   = ZX;                        // final gated sum (ZX dead)
  u16*   TMP2b= (u16*)(ws + OFF_XT);       // post-GEMM bf16 out (U dead)

  const bool chunked = (ws_size >= ARENA_END);

  dim3 tb(32, 8);
  k_tcast<<<dim3(32, 16),  tb, 0, stream>>>(pre_w,   WtPre,    512, 1024, 1024);
  k_tcast<<<dim3(140, 32), tb, 0, stream>>>(win_[0], WtWin[0], 1024, 4384, 4480);
  k_tcast<<<dim3(140, 32), tb, 0, stream>>>(win_[1], WtWin[1], 1024, 4384, 4480);
  k_tcast<<<dim3(32, 64),  tb, 0, stream>>>(wout_[0], WtWo[0], 2048, 1024, 1024);
  k_tcast<<<dim3(32, 64),  tb, 0, stream>>>(wout_[1], WtWo[1], 2048, 1024, 1024);
  k_tcast<<<dim3(16, 32),  tb, 0, stream>>>(post_w,  WtPost,   1024,  512,  512);
  k_cast<<<4096, 256, 0, stream>>>(x, XBF, 1048576);
  k_gemm<<<dim3(64, 8), 256, 0, stream>>>(XBF, WtPre, nullptr, TMPb, nullptr, nullptr,
                                          8192, 1024, 512, 1024, 1);
  k_preln<<<8192, 256, 0, stream>>>(TMPb, pre_b, pre_g, pre_bb, HPRE);

  for (int d = 0; d < 2; d++) {
    int flip = d;
    k_gemm256<<<dim3(32, 18), 512, 0, stream>>>(HPRE, WtWin[d], ZX);
    k_dt2<<<dim3(16, 32, 2), 256, 0, stream>>>(ZX, dtb_[d], Alog_[d], DTt, DECt, flip,
                                               chunked ? 0 : 1);
    k_conv2<<<dim3(36, 64, 2), 256, 0, stream>>>(ZX, convw_[d], convb_[d], XT, BCtok, BCT, flip);
    if (chunked) {
      k_ssd_a<<<dim3(NCH, 32, 2), 512, 0, stream>>>(XT, BCT, DTt, Alog_[d], HB, PRb);
      k_scan_b<<<dim3(32, 32, 2), 256, 0, stream>>>(HB, PRb);
      k_ssd_c<<<dim3(NCH, 32, 2), 512, 0, stream>>>(BCtok, XT, DTt, HB, Alog_[d], Dp_[d], Y);
    } else {
      k_scan<<<dim3(4, 32, 2), 256, 0, stream>>>(XT, BCtok, DTt, DECt, Dp_[d], Y);
    }
    k_gate<<<8192, 256, 0, stream>>>(Y, ZX, normw_[d], U, flip);
    // d=0: bf16 out to Sb. d=1: accumulate bf16 Sb + fused u2 (silu(HPRE)) -> bf16 U2.
    if (d == 0) {
      k_gemm<<<dim3(64, 8), 256, 0, stream>>>(U, WtWo[d], nullptr, Sb, nullptr, nullptr,
                                              8192, 1024, 2048, 1024, 1);
    } else {
      k_gemm<<<dim3(64, 8), 256, 0, stream>>>(U, WtWo[d], nullptr, U2, HPRE, Sb,
                                              8192, 1024, 2048, 1024, 1 | 4 | 8 | 16);
    }
  }

  k_gemm<<<dim3(64, 4), 256, 0, stream>>>(U2, WtPost, nullptr, TMP2b, nullptr, nullptr,
                                          8192, 512, 1024, 512, 1);
  k_final<<<8192, 256, 0, stream>>>(TMP2b, post_b, post_g, post_bb, x, (float*)d_out);
}